// Round 2
// 6180.684 us; speedup vs baseline: 2.5554x; 2.5554x over previous
//
#include <hip/hip_runtime.h>
#include <hip/hip_bf16.h>

typedef __hip_bfloat16 bf16;

#define NBATCH 128
#define TT 128
#define VV 19
#define NT (NBATCH*TT)
#define EPSF 1e-5f

static __device__ __forceinline__ float b2f(bf16 v){ return __bfloat162float(v); }
static __device__ __forceinline__ bf16  f2b(float v){ return __float2bfloat16(v); }
// dual-dtype input load: mode=1 -> fp32, mode=0 -> bf16
static __device__ __forceinline__ float ldi(const void* p, size_t i, int mode){
  return mode ? ((const float*)p)[i] : b2f(((const bf16*)p)[i]);
}

// acc[0..18] += w * row[0..18]; row is 16B-aligned, 20 floats long (pad)
static __device__ __forceinline__ void fma19(float* acc, float w, const float* row){
  const float4* r = (const float4*)row;
  float4 a=r[0], b=r[1], c=r[2], d=r[3], e=r[4];
  acc[0]+=w*a.x;  acc[1]+=w*a.y;  acc[2]+=w*a.z;  acc[3]+=w*a.w;
  acc[4]+=w*b.x;  acc[5]+=w*b.y;  acc[6]+=w*b.z;  acc[7]+=w*b.w;
  acc[8]+=w*c.x;  acc[9]+=w*c.y;  acc[10]+=w*c.z; acc[11]+=w*c.w;
  acc[12]+=w*d.x; acc[13]+=w*d.y; acc[14]+=w*d.z; acc[15]+=w*d.w;
  acc[16]+=w*e.x; acc[17]+=w*e.y; acc[18]+=w*e.z;
}

// ---- detect input dtype: fp32 buffers read as bf16 have wild exponents ----
__global__ void k_detect(const unsigned short* __restrict__ p, int* __restrict__ flag){
  const int tid = threadIdx.x;
  __shared__ int cnt;
  if(tid==0) cnt = 0;
  __syncthreads();
  int local = 0;
  for(int i=tid; i<2048; i+=256){
    unsigned short h = p[i];
    int e = (h>>7) & 0xFF;                 // bf16 exponent field
    if(h != 0 && (e < 107 || e > 147)) local++;   // |v| outside ~[2^-20, 2^20]
  }
  atomicAdd(&cnt, local);
  __syncthreads();
  if(tid==0) *flag = (cnt > 300) ? 1 : 0;
}

// ---- canary: pre-fill output with 3.0 (overwritten by stage3 if pipeline completes) ----
__global__ void k_canary(void* __restrict__ out, int n, const int* __restrict__ flag){
  int i = blockIdx.x*256 + threadIdx.x;
  if(i >= n) return;
  if(*flag) ((float*)out)[i] = 3.0f;
  else      ((bf16*)out)[i]  = f2b(3.0f);
}

__global__ void k_zero(float* __restrict__ p, int n){
  int i = blockIdx.x*256 + threadIdx.x;
  if(i < n) p[i] = 0.f;
}

// ---- convert a weight buffer (bf16 or fp32) to fp32 workspace copy ----
__global__ void k_cvt(const void* __restrict__ src, float* __restrict__ dst, int n,
                      const int* __restrict__ flag){
  int i = blockIdx.x*256 + threadIdx.x;
  if(i < n) dst[i] = ldi(src, i, *flag);
}

// ---- fmv = tanh(fm)+1 ----
__global__ void k_tanhp1(const void* __restrict__ fm, float* __restrict__ out, int n,
                         const int* __restrict__ flag){
  int i = blockIdx.x*256 + threadIdx.x;
  int mode = *flag;
  if(i < n) out[i] = tanhf(ldi(fm, i, mode)) + 1.0f;
}

// ---- g = softmax( A @ B ) per (n,t) ----
__global__ __launch_bounds__(256)
void k_gspa(const void* __restrict__ x0,
            const void* __restrict__ w1, const void* __restrict__ b1,
            const void* __restrict__ w2, const void* __restrict__ b2,
            float* __restrict__ gout, const int* __restrict__ flag)
{
  const int s = blockIdx.x;
  const int n = s / TT, t = s % TT;
  const int tid = threadIdx.x;
  const int mode = *flag;
  __shared__ float xt[64][20];
  __shared__ float Am[VV][32];
  __shared__ float Bm[32][20];
  __shared__ float Sm[VV][20];
  for(int idx=tid; idx<64*VV; idx+=256){
    int c = idx/VV, u = idx - c*VV;
    xt[c][u] = ldi(x0, (((size_t)n*64 + c)*TT + t)*VV + u, mode);
  }
  __syncthreads();
  for(int idx=tid; idx<VV*32; idx+=256){
    int u = idx/32, k = idx & 31;
    float acc = ldi(b1, k, mode);
    for(int c=0;c<64;c++) acc += xt[c][u]*ldi(w1, k*64+c, mode);
    Am[u][k] = acc;
  }
  for(int idx=tid; idx<32*VV; idx+=256){
    int k = idx/VV, w = idx - k*VV;
    float acc = ldi(b2, k, mode);
    for(int c=0;c<64;c++) acc += xt[c][w]*ldi(w2, k*64+c, mode);
    Bm[k][w] = acc;
  }
  __syncthreads();
  for(int idx=tid; idx<VV*VV; idx+=256){
    int u = idx/VV, w = idx - u*VV;
    float acc = 0.f;
#pragma unroll
    for(int k=0;k<32;k++) acc += Am[u][k]*Bm[k][w];
    Sm[u][w] = acc;
  }
  __syncthreads();
  if(tid < VV){
    int u = tid;
    float mx = -1e30f;
    for(int w=0;w<VV;w++) mx = fmaxf(mx, Sm[u][w]);
    float sum = 0.f;
    for(int w=0;w<VV;w++){ float e = __expf(Sm[u][w]-mx); Sm[u][w]=e; sum+=e; }
    float r = 1.0f/sum;
    for(int w=0;w<VV;w++) Sm[u][w] *= r;
  }
  __syncthreads();
  float* gp = gout + (size_t)s*(VV*VV);
  for(int idx=tid; idx<VV*VV; idx+=256) gp[idx] = Sm[idx/VV][idx%VV];
}

// ---- Stage 1: ypre[i][d] = sum_j xs[i][j]*lw[j][d] ----
// PREV: input is previous block's y in zbuf layout, apply BN2d(A2p,B2p)+relu on load.
// Weights (lwf/lbf/dwf/dbf) are pre-converted fp32 workspace buffers.
template<int CIN_, int COUT_, bool DOWN, bool PREV>
__global__ __launch_bounds__(256,3)
void k_stage1(const void* __restrict__ xin,
              const float* __restrict__ A2p, const float* __restrict__ B2p,
              const float* __restrict__ fmv,
              const float* __restrict__ lwf, const float* __restrict__ lbf,
              bf16* __restrict__ zbuf,
              const float* __restrict__ dwf, const float* __restrict__ dbf,
              float* __restrict__ dpart, const int* __restrict__ flag)
{
  constexpr int NS = 256/COUT_;
  constexpr int JC = CIN_/NS;
  const int s = blockIdx.x;
  const int n = s / TT, t = s % TT;
  const int tid = threadIdx.x;
  __shared__ __align__(16) float xt[CIN_][20];
  __shared__ __align__(16) float xsT[CIN_][20];   // xsT[j][i]
  __shared__ float pbuf[(NS-1)*COUT_*VV];
  __shared__ float ds1[256], ds2[256];

  if constexpr (PREV){
    const bf16* zin = (const bf16*)xin + (size_t)s*(CIN_*VV);
    for(int idx=tid; idx<CIN_*VV; idx+=256){
      int c = idx/VV, u = idx - c*VV;
      xt[c][u] = fmaxf(b2f(zin[idx])*A2p[c] + B2p[c], 0.f);
    }
  } else {
    const int mode = *flag;
    for(int idx=tid; idx<CIN_*VV; idx+=256){
      int c = idx/VV, u = idx - c*VV;
      xt[c][u] = ldi(xin, (((size_t)n*CIN_ + c)*TT + t)*VV + u, mode);
    }
  }
  if(tid < CIN_) xt[tid][19] = 0.f;   // zero pad column (read by DOWN u=19 lane)
  __syncthreads();
  for(int idx=tid; idx<CIN_*VV; idx+=256){
    int j = idx/VV, i = idx - j*VV;
    xsT[j][i] = xt[j][(i+j)%VV] * fmv[i*CIN_ + j];
  }
  __syncthreads();

  const int d  = tid % COUT_;
  const int sp = tid / COUT_;
  float acc[VV];
#pragma unroll
  for(int i=0;i<VV;i++) acc[i]=0.f;
  for(int j=sp*JC; j<(sp+1)*JC; j++){
    fma19(acc, lwf[j*COUT_ + d], xsT[j]);
  }
  if(sp > 0){
#pragma unroll
    for(int i=0;i<VV;i++) pbuf[((sp-1)*COUT_+d)*VV + i] = acc[i];
  }
  __syncthreads();
  if(sp == 0){
    float lbv = lbf[d];
    bf16* zp = zbuf + (size_t)s*(VV*COUT_);
#pragma unroll
    for(int i=0;i<VV;i++){
      float v = acc[i] + lbv;
#pragma unroll
      for(int q=1;q<NS;q++) v += pbuf[((q-1)*COUT_+d)*VV + i];
      zp[i*COUT_ + d] = f2b(v);
    }
  }
  if constexpr (DOWN){
    // down-conv BN stats: r[u] = db + sum_c dw[oc][c]*xt[c][u]
    // weight row loaded once as float4 chunks, reused over this thread's u set.
    const int oc  = tid & 127;
    const int grp = tid >> 7;           // wave-uniform
    float r[10];
    const float dbv = dbf[oc];
#pragma unroll
    for(int k=0;k<10;k++) r[k] = dbv;
    const float4* wrow = (const float4*)(dwf + oc*CIN_);
#pragma unroll 4
    for(int c4=0; c4<CIN_/4; c4++){
      float4 w = wrow[c4];
      const float* x0r = xt[c4*4+0];
      const float* x1r = xt[c4*4+1];
      const float* x2r = xt[c4*4+2];
      const float* x3r = xt[c4*4+3];
#pragma unroll
      for(int k=0;k<10;k++){
        int u = grp + 2*k;              // u==19 reads zero pad, excluded below
        r[k] += w.x*x0r[u] + w.y*x1r[u] + w.z*x2r[u] + w.w*x3r[u];
      }
    }
    float a1=0.f, a2=0.f;
#pragma unroll
    for(int k=0;k<10;k++){
      if(grp + 2*k < VV){ a1 += r[k]; a2 += r[k]*r[k]; }
    }
    ds1[tid]=a1; ds2[tid]=a2;
    __syncthreads();
    if(tid < 128){
      float* bucket = dpart + (size_t)(s & 63)*256;
      atomicAdd(&bucket[tid],       ds1[tid] + ds1[tid+128]);
      atomicAdd(&bucket[128 + tid], ds2[tid] + ds2[tid+128]);
    }
  }
}

// ---- column stats of [NT][F] bf16 buffer ----
__global__ __launch_bounds__(256)
void k_colstats(const bf16* __restrict__ zb, int F,
                float* __restrict__ s1, float* __restrict__ s2)
{
  int f = blockIdx.x*256 + threadIdx.x;
  if(f >= F) return;
  const int RP = NT/64;
  const bf16* p = zb + (size_t)(blockIdx.y*RP)*F + f;
  float a=0.f, b=0.f;
  for(int r=0; r<RP; r++){ float v = b2f(p[(size_t)r*F]); a += v; b += v*v; }
  atomicAdd(&s1[f], a);
  atomicAdd(&s2[f], b);
}

// ---- BN1d finalize with shift-out folded into index mapping ----
template<int COUT_>
__global__ void k_fin1(const float* __restrict__ s1, const float* __restrict__ s2,
                       const void* __restrict__ bng, const void* __restrict__ bnb,
                       float* __restrict__ A1, float* __restrict__ B1,
                       const int* __restrict__ flag)
{
  const int F = VV*COUT_;
  int fp = blockIdx.x*256 + threadIdx.x;
  if(fp >= F) return;
  int mode = *flag;
  int ip = fp/COUT_, d = fp - ip*COUT_;
  int f = ((ip + d)%VV)*COUT_ + d;        // post-shift feature
  float m = s1[fp] * (1.0f/NT);
  float v = s2[fp] * (1.0f/NT) - m*m;
  float a = ldi(bng, f, mode) * rsqrtf(v + EPSF);
  A1[fp] = a;
  B1[fp] = ldi(bnb, f, mode) - m*a;
}

// ---- BN2d finalize (per channel over (sample,u)) ----
template<int COUT_>
__global__ void k_fin2(const float* __restrict__ s1, const float* __restrict__ s2,
                       const void* __restrict__ bnsg, const void* __restrict__ bnsb,
                       float* __restrict__ A2, float* __restrict__ B2,
                       const int* __restrict__ flag)
{
  int d = threadIdx.x;
  if(d >= COUT_) return;
  int mode = *flag;
  float a=0.f, b=0.f;
  for(int u=0;u<VV;u++){ a += s1[d*VV+u]; b += s2[d*VV+u]; }
  const float inv = 1.0f/((float)NT*VV);
  float m = a*inv, v = b*inv - m*m;
  float g_ = ldi(bnsg, d, mode) * rsqrtf(v + EPSF);
  A2[d] = g_;
  B2[d] = ldi(bnsb, d, mode) - m*g_;
}

// ---- reduce 64 buckets -> A2d/B2d for the down-path BN ----
__global__ void k_dfin(const float* __restrict__ dpart, const void* __restrict__ dbng,
                       const void* __restrict__ dbnb, float* __restrict__ A2d,
                       float* __restrict__ B2d, const int* __restrict__ flag){
  int c = threadIdx.x;           // 256 threads: c<128 -> sum, c>=128 -> sumsq
  int mode = *flag;
  float a = 0.f;
  for(int r=0;r<64;r++) a += dpart[(size_t)r*256 + c];
  __shared__ float red[256];
  red[c] = a;
  __syncthreads();
  if(c < 128){
    const float inv = 1.0f/((float)NT*VV);
    float m = red[c]*inv;
    float v = red[128+c]*inv - m*m;
    float g_ = ldi(dbng, c, mode) * rsqrtf(v + EPSF);
    A2d[c] = g_;
    B2d[c] = ldi(dbnb, c, mode) - m*g_;
  }
}

// ---- Stage 2: BN1d + residual + ReLU, graph matmul, output convs -> y (in-place in zy) ----
// Weights (wwf/w1wf/w1bf/dwf/dbf) are pre-converted fp32 workspace buffers.
template<int CIN_, int COUT_, bool DOWN, bool PREV>
__global__ __launch_bounds__(256,3)
void k_stage2(const void* __restrict__ xin,
              const float* __restrict__ A2p, const float* __restrict__ B2p,
              bf16* __restrict__ zy,
              const float* __restrict__ A1, const float* __restrict__ B1,
              const float* __restrict__ gmat,
              const float* __restrict__ wwf, const float* __restrict__ w1wf,
              const float* __restrict__ w1bf,
              const float* __restrict__ dwf, const float* __restrict__ dbf,
              const float* __restrict__ A2d, const float* __restrict__ B2d,
              const int* __restrict__ flag)
{
  constexpr int NS = 256/COUT_;
  constexpr int F  = VV*COUT_;
  constexpr int CC = COUT_/NS;
  const int s = blockIdx.x;
  const int n = s/TT, t = s % TT;
  const int tid = threadIdx.x;
  __shared__ __align__(16) float X2[COUT_][20];   // [channel][node]
  __shared__ __align__(16) float XG[COUT_][20];
  __shared__ __align__(16) float XT[CIN_][20];
  __shared__ float gt[VV][20];
  __shared__ float comb[(NS-1)*COUT_*VV];

  if constexpr (PREV){
    const bf16* zin = (const bf16*)xin + (size_t)s*(CIN_*VV);
    for(int idx=tid; idx<CIN_*VV; idx+=256){
      int c = idx/VV, u = idx - c*VV;
      XT[c][u] = fmaxf(b2f(zin[idx])*A2p[c] + B2p[c], 0.f);
    }
  } else {
    const int mode = *flag;
    for(int idx=tid; idx<CIN_*VV; idx+=256){
      int c = idx/VV, u = idx - c*VV;
      XT[c][u] = ldi(xin, (((size_t)n*CIN_ + c)*TT + t)*VV + u, mode);
    }
  }
  for(int idx=tid; idx<VV*VV; idx+=256)
    gt[idx/VV][idx%VV] = gmat[(size_t)s*(VV*VV) + idx];
  __syncthreads();

  bf16* zp = zy + (size_t)s*F;
  if constexpr (DOWN){
    // per-thread d is constant (COUT_=128, stride 256): hoist the weight row.
    const int d0 = tid & 127;
    const int g0 = tid >> 7;
    float rr[10];
    const float dbv = dbf[d0];
#pragma unroll
    for(int k=0;k<10;k++) rr[k] = dbv;
    int uarr[10];
#pragma unroll
    for(int k=0;k<10;k++) uarr[k] = (g0 + 2*k + d0) % VV;
    const float4* wrow = (const float4*)(dwf + d0*CIN_);
#pragma unroll 4
    for(int c4=0; c4<CIN_/4; c4++){
      float4 w = wrow[c4];
      const float* x0r = XT[c4*4+0];
      const float* x1r = XT[c4*4+1];
      const float* x2r = XT[c4*4+2];
      const float* x3r = XT[c4*4+3];
#pragma unroll
      for(int k=0;k<10;k++){
        int u = uarr[k];
        rr[k] += w.x*x0r[u] + w.y*x1r[u] + w.z*x2r[u] + w.w*x3r[u];
      }
    }
    // fixed-trip unrolled loop: rr[k]/uarr[k] stay compile-time-indexed (rule #20)
#pragma unroll
    for(int k=0;k<10;k++){
      int idx = tid + k*256;
      if(idx < F){
        int ip = idx/COUT_, d = idx - ip*COUT_;
        int u = uarr[k];
        float res = rr[k]*A2d[d] + B2d[d];
        float v = b2f(zp[idx])*A1[idx] + B1[idx] + res;
        X2[d][u] = fmaxf(v, 0.f);
      }
    }
  } else {
    for(int idx=tid; idx<F; idx+=256){
      int ip = idx/COUT_, d = idx - ip*COUT_;
      int u = (ip + d) % VV;
      float res = XT[d][u];
      float v = b2f(zp[idx])*A1[idx] + B1[idx] + res;
      X2[d][u] = fmaxf(v, 0.f);
    }
  }
  __syncthreads();
  for(int idx=tid; idx<F; idx+=256){
    int c = idx/VV, u = idx - c*VV;
    float acc = 0.f;
#pragma unroll
    for(int w=0; w<VV; w++) acc += gt[u][w]*X2[c][w];
    XG[c][u] = acc;
  }
  __syncthreads();
  const int d  = tid % COUT_;
  const int sp = tid / COUT_;
  float acc[VV];
#pragma unroll
  for(int i=0;i<VV;i++) acc[i]=0.f;
  for(int c=sp*CC; c<(sp+1)*CC; c++){
    fma19(acc, wwf[d*COUT_ + c],  XG[c]);
    fma19(acc, w1wf[d*COUT_ + c], X2[c]);
  }
  if(sp > 0){
#pragma unroll
    for(int i=0;i<VV;i++) comb[((sp-1)*COUT_+d)*VV + i] = acc[i];
  }
  __syncthreads();
  if(sp == 0){
    float bv = w1bf[d];
#pragma unroll
    for(int i=0;i<VV;i++){
      float v = acc[i] + bv;
#pragma unroll
      for(int q=1;q<NS;q++) v += comb[((q-1)*COUT_+d)*VV + i];
      zp[d*VV + i] = f2b(v);
    }
  }
}

// ---- Stage 3 (final only): BN2d + ReLU -> output [n][d][t][u]; NaN canary ----
template<int COUT_>
__global__ __launch_bounds__(256)
void k_stage3(const bf16* __restrict__ ybuf, const float* __restrict__ A2,
              const float* __restrict__ B2, void* __restrict__ out,
              const int* __restrict__ flag)
{
  const int s = blockIdx.x, n = s/TT, t = s % TT, tid = threadIdx.x;
  const int mode = *flag;
  constexpr int F = VV*COUT_;
  const bf16* yp = ybuf + (size_t)s*F;
  for(int idx=tid; idx<F; idx+=256){
    int d = idx/VV, u = idx - d*VV;
    float v0 = b2f(yp[idx])*A2[d] + B2[d];
    float v = fmaxf(v0, 0.f);
    if(!(v0 == v0) || fabsf(v0) > 1e30f) v = 1000.0f;   // NaN/Inf canary
    size_t o = (((size_t)n*COUT_ + d)*TT + t)*VV + u;
    if(mode) ((float*)out)[o] = v;
    else     ((bf16*)out)[o]  = f2b(v);
  }
}

extern "C" void kernel_launch(void* const* d_in, const int* in_sizes, int n_in,
                              void* d_out, int out_size, void* d_ws, size_t ws_size,
                              hipStream_t stream)
{
  const void* in[39];
  for(int i=0;i<39;i++) in[i] = d_in[i];

  char* ws = (char*)d_ws;
  size_t off = 0;
  auto alloc = [&](size_t bytes)->void*{
    void* p = ws + off;
    off = (off + bytes + 255) & ~(size_t)255;
    return p;
  };
  int*   flag = (int*)  alloc(4);
  float* gmat = (float*)alloc((size_t)NT*VV*VV*4);      // 23.7 MB
  bf16*  zA   = (bf16*) alloc((size_t)NT*2432*2);       // 79.7 MB
  bf16*  zB   = (bf16*) alloc((size_t)NT*2432*2);       // 79.7 MB
  float* dpart= (float*)alloc((size_t)64*256*4);        // 64 KB
  float* s1   = (float*)alloc(2432*4);
  float* s2   = (float*)alloc(2432*4);
  float* A1   = (float*)alloc(2432*4);
  float* B1   = (float*)alloc(2432*4);
  float* A2b1 = (float*)alloc(128*4);
  float* B2b1 = (float*)alloc(128*4);
  float* A2b2 = (float*)alloc(128*4);
  float* B2b2 = (float*)alloc(128*4);
  float* A2b3 = (float*)alloc(128*4);
  float* B2b3 = (float*)alloc(128*4);
  float* A2d  = (float*)alloc(128*4);
  float* B2d  = (float*)alloc(128*4);
  float* fmv1 = (float*)alloc(1216*4);
  float* fmv2 = (float*)alloc(1216*4);
  float* fmv3 = (float*)alloc(2432*4);
  // fp32 weight copies (remove dual-dtype ldi from hot inner loops)
  float* b1_lwf  = (float*)alloc(64*64*4);
  float* b1_lbf  = (float*)alloc(64*4);
  float* b1_wwf  = (float*)alloc(64*64*4);
  float* b1_w1wf = (float*)alloc(64*64*4);
  float* b1_w1bf = (float*)alloc(64*4);
  float* b2_lwf  = (float*)alloc(64*128*4);
  float* b2_lbf  = (float*)alloc(128*4);
  float* b2_wwf  = (float*)alloc(128*128*4);
  float* b2_w1wf = (float*)alloc(128*128*4);
  float* b2_w1bf = (float*)alloc(128*4);
  float* b2_dwf  = (float*)alloc(128*64*4);
  float* b2_dbf  = (float*)alloc(128*4);
  float* b3_lwf  = (float*)alloc(128*128*4);
  float* b3_lbf  = (float*)alloc(128*4);
  float* b3_wwf  = (float*)alloc(128*128*4);
  float* b3_w1wf = (float*)alloc(128*128*4);
  float* b3_w1bf = (float*)alloc(128*4);

  if(ws_size < off){
    // workspace too small sentinel: fill out with ~12.06 (bf16 0x4141 pattern)
    hipMemsetAsync(d_out, 0x41, (size_t)out_size*2, stream);
    return;
  }

  k_detect<<<1,256,0,stream>>>((const unsigned short*)in[0], flag);
  k_canary<<<(out_size+255)/256,256,0,stream>>>(d_out, out_size, flag);

  auto cvt = [&](const void* src, float* dst, int n){
    k_cvt<<<(n+255)/256,256,0,stream>>>(src, dst, n, flag);
  };
  cvt(in[5],  b1_lwf,  64*64);   cvt(in[6],  b1_lbf,  64);
  cvt(in[12], b1_wwf,  64*64);   cvt(in[13], b1_w1wf, 64*64);  cvt(in[14], b1_w1bf, 64);
  cvt(in[15], b2_lwf,  64*128);  cvt(in[16], b2_lbf,  128);
  cvt(in[22], b2_wwf,  128*128); cvt(in[23], b2_w1wf, 128*128);cvt(in[24], b2_w1bf, 128);
  cvt(in[25], b2_dwf,  128*64);  cvt(in[26], b2_dbf,  128);
  cvt(in[29], b3_lwf,  128*128); cvt(in[30], b3_lbf,  128);
  cvt(in[36], b3_wwf,  128*128); cvt(in[37], b3_w1wf, 128*128);cvt(in[38], b3_w1bf, 128);

  k_tanhp1<<<5,256,0,stream>>>(in[7],  fmv1, 1216, flag);
  k_tanhp1<<<5,256,0,stream>>>(in[17], fmv2, 1216, flag);
  k_tanhp1<<<10,256,0,stream>>>(in[31], fmv3, 2432, flag);
  k_gspa<<<NT,256,0,stream>>>(in[0], in[1], in[2], in[3], in[4], gmat, flag);

  // ---- Block 1 (64 -> 64, identity residual), input = x0, ypre/y in zA ----
  k_stage1<64,64,false,false><<<NT,256,0,stream>>>(in[0], nullptr, nullptr, fmv1,
                                                   b1_lwf, b1_lbf, zA,
                                                   nullptr, nullptr, nullptr, flag);
  k_zero<<<19,256,0,stream>>>(s1, 2*2432);   // s1,s2 contiguous
  k_colstats<<<dim3(5,64),256,0,stream>>>(zA, 1216, s1, s2);
  k_fin1<64><<<5,256,0,stream>>>(s1, s2, in[8], in[9], A1, B1, flag);
  k_stage2<64,64,false,false><<<NT,256,0,stream>>>(in[0], nullptr, nullptr, zA, A1, B1,
                                                   gmat, b1_wwf, b1_w1wf, b1_w1bf,
                                                   nullptr, nullptr, nullptr, nullptr, flag);
  k_zero<<<19,256,0,stream>>>(s1, 2*2432);
  k_colstats<<<dim3(5,64),256,0,stream>>>(zA, 1216, s1, s2);
  k_fin2<64><<<1,64,0,stream>>>(s1, s2, in[10], in[11], A2b1, B2b1, flag);

  // ---- Block 2 (64 -> 128, down path), input = BN2d(zA)+relu, ypre/y in zB ----
  k_zero<<<64,256,0,stream>>>(dpart, 64*256);
  k_stage1<64,128,true,true><<<NT,256,0,stream>>>(zA, A2b1, B2b1, fmv2,
                                                  b2_lwf, b2_lbf, zB,
                                                  b2_dwf, b2_dbf, dpart, flag);
  k_dfin<<<1,256,0,stream>>>(dpart, in[27], in[28], A2d, B2d, flag);
  k_zero<<<19,256,0,stream>>>(s1, 2*2432);
  k_colstats<<<dim3(10,64),256,0,stream>>>(zB, 2432, s1, s2);
  k_fin1<128><<<10,256,0,stream>>>(s1, s2, in[18], in[19], A1, B1, flag);
  k_stage2<64,128,true,true><<<NT,256,0,stream>>>(zA, A2b1, B2b1, zB, A1, B1,
                                                  gmat, b2_wwf, b2_w1wf, b2_w1bf,
                                                  b2_dwf, b2_dbf, A2d, B2d, flag);
  k_zero<<<19,256,0,stream>>>(s1, 2*2432);
  k_colstats<<<dim3(10,64),256,0,stream>>>(zB, 2432, s1, s2);
  k_fin2<128><<<1,128,0,stream>>>(s1, s2, in[20], in[21], A2b2, B2b2, flag);

  // ---- Block 3 (128 -> 128, identity), input = BN2d(zB)+relu, ypre/y in zA ----
  k_stage1<128,128,false,true><<<NT,256,0,stream>>>(zB, A2b2, B2b2, fmv3,
                                                    b3_lwf, b3_lbf, zA,
                                                    nullptr, nullptr, nullptr, flag);
  k_zero<<<19,256,0,stream>>>(s1, 2*2432);
  k_colstats<<<dim3(10,64),256,0,stream>>>(zA, 2432, s1, s2);
  k_fin1<128><<<10,256,0,stream>>>(s1, s2, in[32], in[33], A1, B1, flag);
  k_stage2<128,128,false,true><<<NT,256,0,stream>>>(zB, A2b2, B2b2, zA, A1, B1,
                                                    gmat, b3_wwf, b3_w1wf, b3_w1bf,
                                                    nullptr, nullptr, nullptr, nullptr, flag);
  k_zero<<<19,256,0,stream>>>(s1, 2*2432);
  k_colstats<<<dim3(10,64),256,0,stream>>>(zA, 2432, s1, s2);
  k_fin2<128><<<1,128,0,stream>>>(s1, s2, in[34], in[35], A2b3, B2b3, flag);
  k_stage3<128><<<NT,256,0,stream>>>(zA, A2b3, B2b3, d_out, flag);
}

// Round 3
// 2811.796 us; speedup vs baseline: 5.6171x; 2.1981x over previous
//
#include <hip/hip_runtime.h>
#include <hip/hip_bf16.h>

typedef __hip_bfloat16 bf16;

#define NBATCH 128
#define TT 128
#define VV 19
#define NT (NBATCH*TT)
#define EPSF 1e-5f

static __device__ __forceinline__ float b2f(bf16 v){ return __bfloat162float(v); }
static __device__ __forceinline__ bf16  f2b(float v){ return __float2bfloat16(v); }
// dual-dtype input load: mode=1 -> fp32, mode=0 -> bf16
static __device__ __forceinline__ float ldi(const void* p, size_t i, int mode){
  return mode ? ((const float*)p)[i] : b2f(((const bf16*)p)[i]);
}

// acc[0..18] += w * row[0..18]; row is 16B-aligned, 20 floats long (pad)
static __device__ __forceinline__ void fma19(float* acc, float w, const float* row){
  const float4* r = (const float4*)row;
  float4 a=r[0], b=r[1], c=r[2], d=r[3], e=r[4];
  acc[0]+=w*a.x;  acc[1]+=w*a.y;  acc[2]+=w*a.z;  acc[3]+=w*a.w;
  acc[4]+=w*b.x;  acc[5]+=w*b.y;  acc[6]+=w*b.z;  acc[7]+=w*b.w;
  acc[8]+=w*c.x;  acc[9]+=w*c.y;  acc[10]+=w*c.z; acc[11]+=w*c.w;
  acc[12]+=w*d.x; acc[13]+=w*d.y; acc[14]+=w*d.z; acc[15]+=w*d.w;
  acc[16]+=w*e.x; acc[17]+=w*e.y; acc[18]+=w*e.z;
}

// ---- detect input dtype: fp32 buffers read as bf16 have wild exponents ----
__global__ void k_detect(const unsigned short* __restrict__ p, int* __restrict__ flag){
  const int tid = threadIdx.x;
  __shared__ int cnt;
  if(tid==0) cnt = 0;
  __syncthreads();
  int local = 0;
  for(int i=tid; i<2048; i+=256){
    unsigned short h = p[i];
    int e = (h>>7) & 0xFF;                 // bf16 exponent field
    if(h != 0 && (e < 107 || e > 147)) local++;   // |v| outside ~[2^-20, 2^20]
  }
  atomicAdd(&cnt, local);
  __syncthreads();
  if(tid==0) *flag = (cnt > 300) ? 1 : 0;
}

// ---- canary: pre-fill output with 3.0 (overwritten by stage3 if pipeline completes) ----
__global__ void k_canary(void* __restrict__ out, int n, const int* __restrict__ flag){
  int i = blockIdx.x*256 + threadIdx.x;
  if(i >= n) return;
  if(*flag) ((float*)out)[i] = 3.0f;
  else      ((bf16*)out)[i]  = f2b(3.0f);
}

__global__ void k_zero(float* __restrict__ p, int n){
  int i = blockIdx.x*256 + threadIdx.x;
  if(i < n) p[i] = 0.f;
}

// ---- convert a weight buffer (bf16 or fp32) to fp32 workspace copy ----
__global__ void k_cvt(const void* __restrict__ src, float* __restrict__ dst, int n,
                      const int* __restrict__ flag){
  int i = blockIdx.x*256 + threadIdx.x;
  if(i < n) dst[i] = ldi(src, i, *flag);
}

// ---- transposed fp32 copy: dst[c*rows + r] = src[r*cols + c] ----
// makes per-lane-d weight reads coalesced in the hot loops
__global__ void k_cvtT(const void* __restrict__ src, float* __restrict__ dst,
                       int rows, int cols, const int* __restrict__ flag){
  int i = blockIdx.x*256 + threadIdx.x;
  if(i < rows*cols){
    int r = i / cols, c = i - r*cols;
    dst[c*rows + r] = ldi(src, i, *flag);
  }
}

// ---- fmv = tanh(fm)+1 ----
__global__ void k_tanhp1(const void* __restrict__ fm, float* __restrict__ out, int n,
                         const int* __restrict__ flag){
  int i = blockIdx.x*256 + threadIdx.x;
  int mode = *flag;
  if(i < n) out[i] = tanhf(ldi(fm, i, mode)) + 1.0f;
}

// ---- g = softmax( A @ B ) per (n,t); weights pre-transposed fp32 ----
__global__ __launch_bounds__(256)
void k_gspa(const void* __restrict__ x0,
            const float* __restrict__ w1T, const float* __restrict__ b1f,
            const float* __restrict__ w2T, const float* __restrict__ b2f,
            float* __restrict__ gout, const int* __restrict__ flag)
{
  const int s = blockIdx.x;
  const int n = s / TT, t = s % TT;
  const int tid = threadIdx.x;
  const int mode = *flag;
  __shared__ float xt[64][20];
  __shared__ float Am[VV][33];
  __shared__ float Bm[32][21];
  __shared__ float Sm[VV][21];
  for(int idx=tid; idx<64*VV; idx+=256){
    int c = idx/VV, u = idx - c*VV;
    xt[c][u] = ldi(x0, (((size_t)n*64 + c)*TT + t)*VV + u, mode);
  }
  __syncthreads();
  for(int idx=tid; idx<VV*32; idx+=256){
    int u = idx/32, k = idx & 31;
    float acc = b1f[k];
    for(int c=0;c<64;c++) acc += xt[c][u]*w1T[c*32+k];   // w1T coalesced in k
    Am[u][k] = acc;
  }
  for(int idx=tid; idx<32*VV; idx+=256){
    int k = idx/VV, w = idx - k*VV;
    float acc = b2f[k];
    for(int c=0;c<64;c++) acc += xt[c][w]*w2T[c*32+k];
    Bm[k][w] = acc;
  }
  __syncthreads();
  for(int idx=tid; idx<VV*VV; idx+=256){
    int u = idx/VV, w = idx - u*VV;
    float acc = 0.f;
#pragma unroll
    for(int k=0;k<32;k++) acc += Am[u][k]*Bm[k][w];
    Sm[u][w] = acc;
  }
  __syncthreads();
  if(tid < VV){
    int u = tid;
    float mx = -1e30f;
    for(int w=0;w<VV;w++) mx = fmaxf(mx, Sm[u][w]);
    float sum = 0.f;
    for(int w=0;w<VV;w++){ float e = __expf(Sm[u][w]-mx); Sm[u][w]=e; sum+=e; }
    float r = 1.0f/sum;
    for(int w=0;w<VV;w++) Sm[u][w] *= r;
  }
  __syncthreads();
  float* gp = gout + (size_t)s*(VV*VV);
  for(int idx=tid; idx<VV*VV; idx+=256) gp[idx] = Sm[idx/VV][idx%VV];
}

// ---- Stage 1: ypre[i][d] = sum_j xs[i][j]*lw[j][d] ----
// PREV: input is previous block's y in zbuf layout, apply BN2d(A2p,B2p)+relu on load.
// lwf/lbf fp32; dwT is the TRANSPOSED down conv weight [CIN_][COUT_].
template<int CIN_, int COUT_, bool DOWN, bool PREV>
__global__ __launch_bounds__(256,3)
void k_stage1(const void* __restrict__ xin,
              const float* __restrict__ A2p, const float* __restrict__ B2p,
              const float* __restrict__ fmv,
              const float* __restrict__ lwf, const float* __restrict__ lbf,
              bf16* __restrict__ zbuf,
              const float* __restrict__ dwT, const float* __restrict__ dbf,
              float* __restrict__ dpart, const int* __restrict__ flag)
{
  constexpr int NS = 256/COUT_;
  constexpr int JC = CIN_/NS;
  const int s = blockIdx.x;
  const int n = s / TT, t = s % TT;
  const int tid = threadIdx.x;
  __shared__ __align__(16) float xt[CIN_][20];
  __shared__ __align__(16) float xsT[CIN_][20];   // xsT[j][i]
  __shared__ float pbuf[(NS-1)*COUT_*VV];
  __shared__ float ds1[DOWN?256:1], ds2[DOWN?256:1];

  if constexpr (PREV){
    const bf16* zin = (const bf16*)xin + (size_t)s*(CIN_*VV);
    for(int idx=tid; idx<CIN_*VV; idx+=256){
      int c = idx/VV, u = idx - c*VV;
      xt[c][u] = fmaxf(b2f(zin[idx])*A2p[c] + B2p[c], 0.f);
    }
  } else {
    const int mode = *flag;
    for(int idx=tid; idx<CIN_*VV; idx+=256){
      int c = idx/VV, u = idx - c*VV;
      xt[c][u] = ldi(xin, (((size_t)n*CIN_ + c)*TT + t)*VV + u, mode);
    }
  }
  if(tid < CIN_) xt[tid][19] = 0.f;   // zero pad column (read by DOWN u=19 lane)
  __syncthreads();
  for(int idx=tid; idx<CIN_*VV; idx+=256){
    int j = idx/VV, i = idx - j*VV;
    xsT[j][i] = xt[j][(i+j)%VV] * fmv[i*CIN_ + j];
  }
  __syncthreads();

  const int d  = tid % COUT_;
  const int sp = tid / COUT_;
  float acc[VV];
#pragma unroll
  for(int i=0;i<VV;i++) acc[i]=0.f;
  for(int j=sp*JC; j<(sp+1)*JC; j++){
    fma19(acc, lwf[j*COUT_ + d], xsT[j]);   // coalesced (d per-lane, stride 1)
  }
  if(sp > 0){
#pragma unroll
    for(int i=0;i<VV;i++) pbuf[((sp-1)*COUT_+d)*VV + i] = acc[i];
  }
  __syncthreads();
  if(sp == 0){
    float lbv = lbf[d];
    bf16* zp = zbuf + (size_t)s*(VV*COUT_);
#pragma unroll
    for(int i=0;i<VV;i++){
      float v = acc[i] + lbv;
#pragma unroll
      for(int q=1;q<NS;q++) v += pbuf[((q-1)*COUT_+d)*VV + i];
      zp[i*COUT_ + d] = f2b(v);
    }
  }
  if constexpr (DOWN){
    // down-conv BN stats: r[u] = db + sum_c dwT[c][oc]*xt[c][u]
    // dwT read coalesced (oc per-lane); xt reads are wave-broadcast (u uniform).
    const int oc  = tid & 127;
    const int grp = tid >> 7;           // wave-uniform
    float r[10];
    const float dbv = dbf[oc];
#pragma unroll
    for(int k=0;k<10;k++) r[k] = dbv;
#pragma unroll 4
    for(int c=0;c<CIN_;c++){
      float wc = dwT[c*COUT_ + oc];
      const float* xr = xt[c];
#pragma unroll
      for(int k=0;k<10;k++) r[k] += wc * xr[grp + 2*k];  // u==19 reads zero pad
    }
    float a1=0.f, a2=0.f;
#pragma unroll
    for(int k=0;k<10;k++){
      if(grp + 2*k < VV){ a1 += r[k]; a2 += r[k]*r[k]; }
    }
    ds1[tid]=a1; ds2[tid]=a2;
    __syncthreads();
    if(tid < 128){
      float* bucket = dpart + (size_t)(s & 63)*256;
      atomicAdd(&bucket[tid],       ds1[tid] + ds1[tid+128]);
      atomicAdd(&bucket[128 + tid], ds2[tid] + ds2[tid+128]);
    }
  }
}

// ---- column stats of [NT][F] bf16 buffer ----
__global__ __launch_bounds__(256)
void k_colstats(const bf16* __restrict__ zb, int F,
                float* __restrict__ s1, float* __restrict__ s2)
{
  int f = blockIdx.x*256 + threadIdx.x;
  if(f >= F) return;
  const int RP = NT/64;
  const bf16* p = zb + (size_t)(blockIdx.y*RP)*F + f;
  float a=0.f, b=0.f;
  for(int r=0; r<RP; r++){ float v = b2f(p[(size_t)r*F]); a += v; b += v*v; }
  atomicAdd(&s1[f], a);
  atomicAdd(&s2[f], b);
}

// ---- BN1d finalize with shift-out folded into index mapping ----
template<int COUT_>
__global__ void k_fin1(const float* __restrict__ s1, const float* __restrict__ s2,
                       const void* __restrict__ bng, const void* __restrict__ bnb,
                       float* __restrict__ A1, float* __restrict__ B1,
                       const int* __restrict__ flag)
{
  const int F = VV*COUT_;
  int fp = blockIdx.x*256 + threadIdx.x;
  if(fp >= F) return;
  int mode = *flag;
  int ip = fp/COUT_, d = fp - ip*COUT_;
  int f = ((ip + d)%VV)*COUT_ + d;        // post-shift feature
  float m = s1[fp] * (1.0f/NT);
  float v = s2[fp] * (1.0f/NT) - m*m;
  float a = ldi(bng, f, mode) * rsqrtf(v + EPSF);
  A1[fp] = a;
  B1[fp] = ldi(bnb, f, mode) - m*a;
}

// ---- BN2d finalize (per channel over (sample,u)) ----
template<int COUT_>
__global__ void k_fin2(const float* __restrict__ s1, const float* __restrict__ s2,
                       const void* __restrict__ bnsg, const void* __restrict__ bnsb,
                       float* __restrict__ A2, float* __restrict__ B2,
                       const int* __restrict__ flag)
{
  int d = threadIdx.x;
  if(d >= COUT_) return;
  int mode = *flag;
  float a=0.f, b=0.f;
  for(int u=0;u<VV;u++){ a += s1[d*VV+u]; b += s2[d*VV+u]; }
  const float inv = 1.0f/((float)NT*VV);
  float m = a*inv, v = b*inv - m*m;
  float g_ = ldi(bnsg, d, mode) * rsqrtf(v + EPSF);
  A2[d] = g_;
  B2[d] = ldi(bnsb, d, mode) - m*g_;
}

// ---- reduce 64 buckets -> A2d/B2d for the down-path BN ----
__global__ void k_dfin(const float* __restrict__ dpart, const void* __restrict__ dbng,
                       const void* __restrict__ dbnb, float* __restrict__ A2d,
                       float* __restrict__ B2d, const int* __restrict__ flag){
  int c = threadIdx.x;           // 256 threads: c<128 -> sum, c>=128 -> sumsq
  int mode = *flag;
  float a = 0.f;
  for(int r=0;r<64;r++) a += dpart[(size_t)r*256 + c];
  __shared__ float red[256];
  red[c] = a;
  __syncthreads();
  if(c < 128){
    const float inv = 1.0f/((float)NT*VV);
    float m = red[c]*inv;
    float v = red[128+c]*inv - m*m;
    float g_ = ldi(dbng, c, mode) * rsqrtf(v + EPSF);
    A2d[c] = g_;
    B2d[c] = ldi(dbnb, c, mode) - m*g_;
  }
}

// ---- Stage 2: BN1d + residual + ReLU, graph matmul, output convs -> y (in-place in zy) ----
// wwT/w1T/dwT are TRANSPOSED fp32 weights: wT[c*COUT_ + d] (coalesced in per-lane d).
template<int CIN_, int COUT_, bool DOWN, bool PREV>
__global__ __launch_bounds__(256,3)
void k_stage2(const void* __restrict__ xin,
              const float* __restrict__ A2p, const float* __restrict__ B2p,
              bf16* __restrict__ zy,
              const float* __restrict__ A1, const float* __restrict__ B1,
              const float* __restrict__ gmat,
              const float* __restrict__ wwT, const float* __restrict__ w1T,
              const float* __restrict__ w1bf,
              const float* __restrict__ dwT, const float* __restrict__ dbf,
              const float* __restrict__ A2d, const float* __restrict__ B2d,
              const int* __restrict__ flag)
{
  constexpr int NS = 256/COUT_;
  constexpr int F  = VV*COUT_;
  constexpr int CC = COUT_/NS;
  const int s = blockIdx.x;
  const int n = s/TT, t = s % TT;
  const int tid = threadIdx.x;
  __shared__ __align__(16) float X2[COUT_][20];   // [channel][node]
  __shared__ __align__(16) float XG[COUT_][20];
  __shared__ __align__(16) float XT[CIN_][20];
  __shared__ float gt[VV][21];                    // 21: coprime with 32 banks
  __shared__ float comb[(NS-1)*COUT_*VV];

  if constexpr (PREV){
    const bf16* zin = (const bf16*)xin + (size_t)s*(CIN_*VV);
    for(int idx=tid; idx<CIN_*VV; idx+=256){
      int c = idx/VV, u = idx - c*VV;
      XT[c][u] = fmaxf(b2f(zin[idx])*A2p[c] + B2p[c], 0.f);
    }
  } else {
    const int mode = *flag;
    for(int idx=tid; idx<CIN_*VV; idx+=256){
      int c = idx/VV, u = idx - c*VV;
      XT[c][u] = ldi(xin, (((size_t)n*CIN_ + c)*TT + t)*VV + u, mode);
    }
  }
  for(int idx=tid; idx<VV*VV; idx+=256)
    gt[idx/VV][idx%VV] = gmat[(size_t)s*(VV*VV) + idx];
  __syncthreads();

  bf16* zp = zy + (size_t)s*F;
  if constexpr (DOWN){
    // per-thread d is constant (COUT_=128, stride 256): accumulate down-conv per u.
    const int d0 = tid & 127;
    const int g0 = tid >> 7;
    float rr[10];
    const float dbv = dbf[d0];
#pragma unroll
    for(int k=0;k<10;k++) rr[k] = dbv;
    int uarr[10];
#pragma unroll
    for(int k=0;k<10;k++) uarr[k] = (g0 + 2*k + d0) % VV;
#pragma unroll 4
    for(int c=0;c<CIN_;c++){
      float wc = dwT[c*COUT_ + d0];   // coalesced
      const float* xr = XT[c];
#pragma unroll
      for(int k=0;k<10;k++) rr[k] += wc * xr[uarr[k]];
    }
    // fixed-trip unrolled loop: rr[k]/uarr[k] stay compile-time-indexed (rule #20)
#pragma unroll
    for(int k=0;k<10;k++){
      int idx = tid + k*256;
      if(idx < F){
        int ip = idx/COUT_, d = idx - ip*COUT_;
        int u = uarr[k];
        float res = rr[k]*A2d[d] + B2d[d];
        float v = b2f(zp[idx])*A1[idx] + B1[idx] + res;
        X2[d][u] = fmaxf(v, 0.f);
      }
    }
  } else {
    for(int idx=tid; idx<F; idx+=256){
      int ip = idx/COUT_, d = idx - ip*COUT_;
      int u = (ip + d) % VV;
      float res = XT[d][u];
      float v = b2f(zp[idx])*A1[idx] + B1[idx] + res;
      X2[d][u] = fmaxf(v, 0.f);
    }
  }
  __syncthreads();
  for(int idx=tid; idx<F; idx+=256){
    int c = idx/VV, u = idx - c*VV;
    float acc = 0.f;
#pragma unroll
    for(int w=0; w<VV; w++) acc += gt[u][w]*X2[c][w];
    XG[c][u] = acc;
  }
  __syncthreads();
  const int d  = tid % COUT_;
  const int sp = tid / COUT_;
  float acc[VV];
#pragma unroll
  for(int i=0;i<VV;i++) acc[i]=0.f;
#pragma unroll 4
  for(int c=sp*CC; c<(sp+1)*CC; c++){
    fma19(acc, wwT[c*COUT_ + d],  XG[c]);   // coalesced weight loads
    fma19(acc, w1T[c*COUT_ + d],  X2[c]);   // + wave-broadcast LDS rows
  }
  if(sp > 0){
#pragma unroll
    for(int i=0;i<VV;i++) comb[((sp-1)*COUT_+d)*VV + i] = acc[i];
  }
  __syncthreads();
  if(sp == 0){
    float bv = w1bf[d];
#pragma unroll
    for(int i=0;i<VV;i++){
      float v = acc[i] + bv;
#pragma unroll
      for(int q=1;q<NS;q++) v += comb[((q-1)*COUT_+d)*VV + i];
      zp[d*VV + i] = f2b(v);
    }
  }
}

// ---- Stage 3 (final only): BN2d + ReLU -> output [n][d][t][u]; NaN canary ----
template<int COUT_>
__global__ __launch_bounds__(256)
void k_stage3(const bf16* __restrict__ ybuf, const float* __restrict__ A2,
              const float* __restrict__ B2, void* __restrict__ out,
              const int* __restrict__ flag)
{
  const int s = blockIdx.x, n = s/TT, t = s % TT, tid = threadIdx.x;
  const int mode = *flag;
  constexpr int F = VV*COUT_;
  const bf16* yp = ybuf + (size_t)s*F;
  for(int idx=tid; idx<F; idx+=256){
    int d = idx/VV, u = idx - d*VV;
    float v0 = b2f(yp[idx])*A2[d] + B2[d];
    float v = fmaxf(v0, 0.f);
    if(!(v0 == v0) || fabsf(v0) > 1e30f) v = 1000.0f;   // NaN/Inf canary
    size_t o = (((size_t)n*COUT_ + d)*TT + t)*VV + u;
    if(mode) ((float*)out)[o] = v;
    else     ((bf16*)out)[o]  = f2b(v);
  }
}

extern "C" void kernel_launch(void* const* d_in, const int* in_sizes, int n_in,
                              void* d_out, int out_size, void* d_ws, size_t ws_size,
                              hipStream_t stream)
{
  const void* in[39];
  for(int i=0;i<39;i++) in[i] = d_in[i];

  char* ws = (char*)d_ws;
  size_t off = 0;
  auto alloc = [&](size_t bytes)->void*{
    void* p = ws + off;
    off = (off + bytes + 255) & ~(size_t)255;
    return p;
  };
  int*   flag = (int*)  alloc(4);
  float* gmat = (float*)alloc((size_t)NT*VV*VV*4);      // 23.7 MB
  bf16*  zA   = (bf16*) alloc((size_t)NT*2432*2);       // 79.7 MB
  bf16*  zB   = (bf16*) alloc((size_t)NT*2432*2);       // 79.7 MB
  float* dpart= (float*)alloc((size_t)64*256*4);        // 64 KB
  float* s1   = (float*)alloc(2432*4);
  float* s2   = (float*)alloc(2432*4);
  float* A1   = (float*)alloc(2432*4);
  float* B1   = (float*)alloc(2432*4);
  float* A2b1 = (float*)alloc(128*4);
  float* B2b1 = (float*)alloc(128*4);
  float* A2b2 = (float*)alloc(128*4);
  float* B2b2 = (float*)alloc(128*4);
  float* A2b3 = (float*)alloc(128*4);
  float* B2b3 = (float*)alloc(128*4);
  float* A2d  = (float*)alloc(128*4);
  float* B2d  = (float*)alloc(128*4);
  float* fmv1 = (float*)alloc(1216*4);
  float* fmv2 = (float*)alloc(1216*4);
  float* fmv3 = (float*)alloc(2432*4);
  // fp32 weight copies; *T = transposed (wT[c*rows + d])
  float* b1_lwf  = (float*)alloc(64*64*4);
  float* b1_lbf  = (float*)alloc(64*4);
  float* b1_wwT  = (float*)alloc(64*64*4);
  float* b1_w1T  = (float*)alloc(64*64*4);
  float* b1_w1bf = (float*)alloc(64*4);
  float* b2_lwf  = (float*)alloc(64*128*4);
  float* b2_lbf  = (float*)alloc(128*4);
  float* b2_wwT  = (float*)alloc(128*128*4);
  float* b2_w1T  = (float*)alloc(128*128*4);
  float* b2_w1bf = (float*)alloc(128*4);
  float* b2_dwT  = (float*)alloc(128*64*4);
  float* b2_dbf  = (float*)alloc(128*4);
  float* b3_lwf  = (float*)alloc(128*128*4);
  float* b3_lbf  = (float*)alloc(128*4);
  float* b3_wwT  = (float*)alloc(128*128*4);
  float* b3_w1T  = (float*)alloc(128*128*4);
  float* b3_w1bf = (float*)alloc(128*4);
  float* g1wT    = (float*)alloc(32*64*4);
  float* g1bf    = (float*)alloc(32*4);
  float* g2wT    = (float*)alloc(32*64*4);
  float* g2bf    = (float*)alloc(32*4);

  if(ws_size < off){
    // workspace too small sentinel: fill out with ~12.06 (bf16 0x4141 pattern)
    hipMemsetAsync(d_out, 0x41, (size_t)out_size*2, stream);
    return;
  }

  k_detect<<<1,256,0,stream>>>((const unsigned short*)in[0], flag);
  k_canary<<<(out_size+255)/256,256,0,stream>>>(d_out, out_size, flag);

  auto cvt = [&](const void* src, float* dst, int n){
    k_cvt<<<(n+255)/256,256,0,stream>>>(src, dst, n, flag);
  };
  auto cvtT = [&](const void* src, float* dst, int rows, int cols){
    k_cvtT<<<(rows*cols+255)/256,256,0,stream>>>(src, dst, rows, cols, flag);
  };
  cvt (in[5],  b1_lwf,  64*64);      cvt(in[6],  b1_lbf,  64);
  cvtT(in[12], b1_wwT,  64, 64);     cvtT(in[13], b1_w1T, 64, 64);   cvt(in[14], b1_w1bf, 64);
  cvt (in[15], b2_lwf,  64*128);     cvt(in[16], b2_lbf,  128);
  cvtT(in[22], b2_wwT,  128, 128);   cvtT(in[23], b2_w1T, 128, 128); cvt(in[24], b2_w1bf, 128);
  cvtT(in[25], b2_dwT,  128, 64);    cvt(in[26], b2_dbf,  128);
  cvt (in[29], b3_lwf,  128*128);    cvt(in[30], b3_lbf,  128);
  cvtT(in[36], b3_wwT,  128, 128);   cvtT(in[37], b3_w1T, 128, 128); cvt(in[38], b3_w1bf, 128);
  cvtT(in[1],  g1wT,    32, 64);     cvt(in[2],  g1bf,    32);
  cvtT(in[3],  g2wT,    32, 64);     cvt(in[4],  g2bf,    32);

  k_tanhp1<<<5,256,0,stream>>>(in[7],  fmv1, 1216, flag);
  k_tanhp1<<<5,256,0,stream>>>(in[17], fmv2, 1216, flag);
  k_tanhp1<<<10,256,0,stream>>>(in[31], fmv3, 2432, flag);
  k_gspa<<<NT,256,0,stream>>>(in[0], g1wT, g1bf, g2wT, g2bf, gmat, flag);

  // ---- Block 1 (64 -> 64, identity residual), input = x0, ypre/y in zA ----
  k_stage1<64,64,false,false><<<NT,256,0,stream>>>(in[0], nullptr, nullptr, fmv1,
                                                   b1_lwf, b1_lbf, zA,
                                                   nullptr, nullptr, nullptr, flag);
  k_zero<<<19,256,0,stream>>>(s1, 2*2432);   // s1,s2 contiguous
  k_colstats<<<dim3(5,64),256,0,stream>>>(zA, 1216, s1, s2);
  k_fin1<64><<<5,256,0,stream>>>(s1, s2, in[8], in[9], A1, B1, flag);
  k_stage2<64,64,false,false><<<NT,256,0,stream>>>(in[0], nullptr, nullptr, zA, A1, B1,
                                                   gmat, b1_wwT, b1_w1T, b1_w1bf,
                                                   nullptr, nullptr, nullptr, nullptr, flag);
  k_zero<<<19,256,0,stream>>>(s1, 2*2432);
  k_colstats<<<dim3(5,64),256,0,stream>>>(zA, 1216, s1, s2);
  k_fin2<64><<<1,64,0,stream>>>(s1, s2, in[10], in[11], A2b1, B2b1, flag);

  // ---- Block 2 (64 -> 128, down path), input = BN2d(zA)+relu, ypre/y in zB ----
  k_zero<<<64,256,0,stream>>>(dpart, 64*256);
  k_stage1<64,128,true,true><<<NT,256,0,stream>>>(zA, A2b1, B2b1, fmv2,
                                                  b2_lwf, b2_lbf, zB,
                                                  b2_dwT, b2_dbf, dpart, flag);
  k_dfin<<<1,256,0,stream>>>(dpart, in[27], in[28], A2d, B2d, flag);
  k_zero<<<19,256,0,stream>>>(s1, 2*2432);
  k_colstats<<<dim3(10,64),256,0,stream>>>(zB, 2432, s1, s2);
  k_fin1<128><<<10,256,0,stream>>>(s1, s2, in[18], in[19], A1, B1, flag);
  k_stage2<64,128,true,true><<<NT,256,0,stream>>>(zA, A2b1, B2b1, zB, A1, B1,
                                                  gmat, b2_wwT, b2_w1T, b2_w1bf,
                                                  b2_dwT, b2_dbf, A2d, B2d, flag);
  k_zero<<<19,256,0,stream>>>(s1, 2*2432);
  k_colstats<<<dim3(10,64),256,0,stream>>>(zB, 2432, s1, s2);
  k_fin2<128><<<1,128,0,stream>>>(s1, s2, in[20], in[21], A2b2, B2b2, flag);

  // ---- Block 3 (128 -> 128, identity), input = BN2d(zB)+relu, ypre/y in zA ----
  k_stage1<128,128,false,true><<<NT,256,0,stream>>>(zB, A2b2, B2b2, fmv3,
                                                    b3_lwf, b3_lbf, zA,
                                                    nullptr, nullptr, nullptr, flag);
  k_zero<<<19,256,0,stream>>>(s1, 2*2432);
  k_colstats<<<dim3(10,64),256,0,stream>>>(zA, 2432, s1, s2);
  k_fin1<128><<<10,256,0,stream>>>(s1, s2, in[32], in[33], A1, B1, flag);
  k_stage2<128,128,false,true><<<NT,256,0,stream>>>(zB, A2b2, B2b2, zA, A1, B1,
                                                    gmat, b3_wwT, b3_w1T, b3_w1bf,
                                                    nullptr, nullptr, nullptr, nullptr, flag);
  k_zero<<<19,256,0,stream>>>(s1, 2*2432);
  k_colstats<<<dim3(10,64),256,0,stream>>>(zA, 2432, s1, s2);
  k_fin2<128><<<1,128,0,stream>>>(s1, s2, in[34], in[35], A2b3, B2b3, flag);
  k_stage3<128><<<NT,256,0,stream>>>(zA, A2b3, B2b3, d_out, flag);
}

// Round 4
// 2387.570 us; speedup vs baseline: 6.6151x; 1.1777x over previous
//
#include <hip/hip_runtime.h>
#include <hip/hip_bf16.h>

typedef __hip_bfloat16 bf16;

#define NBATCH 128
#define TT 128
#define VV 19
#define NT (NBATCH*TT)
#define EPSF 1e-5f

static __device__ __forceinline__ float b2f(bf16 v){ return __bfloat162float(v); }
static __device__ __forceinline__ bf16  f2b(float v){ return __float2bfloat16(v); }
// dual-dtype input load: mode=1 -> fp32, mode=0 -> bf16
static __device__ __forceinline__ float ldi(const void* p, size_t i, int mode){
  return mode ? ((const float*)p)[i] : b2f(((const bf16*)p)[i]);
}

// acc[0..18] += w * row[0..18]; row is 16B-aligned, 20 floats long (pad)
static __device__ __forceinline__ void fma19(float* acc, float w, const float* row){
  const float4* r = (const float4*)row;
  float4 a=r[0], b=r[1], c=r[2], d=r[3], e=r[4];
  acc[0]+=w*a.x;  acc[1]+=w*a.y;  acc[2]+=w*a.z;  acc[3]+=w*a.w;
  acc[4]+=w*b.x;  acc[5]+=w*b.y;  acc[6]+=w*b.z;  acc[7]+=w*b.w;
  acc[8]+=w*c.x;  acc[9]+=w*c.y;  acc[10]+=w*c.z; acc[11]+=w*c.w;
  acc[12]+=w*d.x; acc[13]+=w*d.y; acc[14]+=w*d.z; acc[15]+=w*d.w;
  acc[16]+=w*e.x; acc[17]+=w*e.y; acc[18]+=w*e.z;
}

// ---- detect input dtype: fp32 buffers read as bf16 have wild exponents ----
__global__ void k_detect(const unsigned short* __restrict__ p, int* __restrict__ flag){
  const int tid = threadIdx.x;
  __shared__ int cnt;
  if(tid==0) cnt = 0;
  __syncthreads();
  int local = 0;
  for(int i=tid; i<2048; i+=256){
    unsigned short h = p[i];
    int e = (h>>7) & 0xFF;                 // bf16 exponent field
    if(h != 0 && (e < 107 || e > 147)) local++;   // |v| outside ~[2^-20, 2^20]
  }
  atomicAdd(&cnt, local);
  __syncthreads();
  if(tid==0) *flag = (cnt > 300) ? 1 : 0;
}

// ---- canary: pre-fill output with 3.0 (overwritten by stage3 if pipeline completes) ----
__global__ void k_canary(void* __restrict__ out, int n, const int* __restrict__ flag){
  int i = blockIdx.x*256 + threadIdx.x;
  if(i >= n) return;
  if(*flag) ((float*)out)[i] = 3.0f;
  else      ((bf16*)out)[i]  = f2b(3.0f);
}

__global__ void k_zero(float* __restrict__ p, int n){
  int i = blockIdx.x*256 + threadIdx.x;
  if(i < n) p[i] = 0.f;
}

// ---- convert a weight buffer (bf16 or fp32) to fp32 workspace copy ----
__global__ void k_cvt(const void* __restrict__ src, float* __restrict__ dst, int n,
                      const int* __restrict__ flag){
  int i = blockIdx.x*256 + threadIdx.x;
  if(i < n) dst[i] = ldi(src, i, *flag);
}

// ---- transposed fp32 copy: dst[c*rows + r] = src[r*cols + c] ----
// makes per-lane-d weight reads coalesced in the hot loops
__global__ void k_cvtT(const void* __restrict__ src, float* __restrict__ dst,
                       int rows, int cols, const int* __restrict__ flag){
  int i = blockIdx.x*256 + threadIdx.x;
  if(i < rows*cols){
    int r = i / cols, c = i - r*cols;
    dst[c*rows + r] = ldi(src, i, *flag);
  }
}

// ---- fmv = tanh(fm)+1 ----
__global__ void k_tanhp1(const void* __restrict__ fm, float* __restrict__ out, int n,
                         const int* __restrict__ flag){
  int i = blockIdx.x*256 + threadIdx.x;
  int mode = *flag;
  if(i < n) out[i] = tanhf(ldi(fm, i, mode)) + 1.0f;
}

// ---- g = softmax( A @ B ) per (n,t); weights pre-transposed fp32 ----
__global__ __launch_bounds__(256)
void k_gspa(const void* __restrict__ x0,
            const float* __restrict__ w1T, const float* __restrict__ b1f,
            const float* __restrict__ w2T, const float* __restrict__ b2f,
            float* __restrict__ gout, const int* __restrict__ flag)
{
  const int s = blockIdx.x;
  const int n = s / TT, t = s % TT;
  const int tid = threadIdx.x;
  const int mode = *flag;
  __shared__ float xt[64][20];
  __shared__ float Am[VV][33];
  __shared__ float Bm[32][21];
  __shared__ float Sm[VV][21];
  for(int idx=tid; idx<64*VV; idx+=256){
    int c = idx/VV, u = idx - c*VV;
    xt[c][u] = ldi(x0, (((size_t)n*64 + c)*TT + t)*VV + u, mode);
  }
  __syncthreads();
  for(int idx=tid; idx<VV*32; idx+=256){
    int u = idx/32, k = idx & 31;
    float acc = b1f[k];
    for(int c=0;c<64;c++) acc += xt[c][u]*w1T[c*32+k];   // w1T coalesced in k
    Am[u][k] = acc;
  }
  for(int idx=tid; idx<32*VV; idx+=256){
    int k = idx/VV, w = idx - k*VV;
    float acc = b2f[k];
    for(int c=0;c<64;c++) acc += xt[c][w]*w2T[c*32+k];
    Bm[k][w] = acc;
  }
  __syncthreads();
  for(int idx=tid; idx<VV*VV; idx+=256){
    int u = idx/VV, w = idx - u*VV;
    float acc = 0.f;
#pragma unroll
    for(int k=0;k<32;k++) acc += Am[u][k]*Bm[k][w];
    Sm[u][w] = acc;
  }
  __syncthreads();
  if(tid < VV){
    int u = tid;
    float mx = -1e30f;
    for(int w=0;w<VV;w++) mx = fmaxf(mx, Sm[u][w]);
    float sum = 0.f;
    for(int w=0;w<VV;w++){ float e = __expf(Sm[u][w]-mx); Sm[u][w]=e; sum+=e; }
    float r = 1.0f/sum;
    for(int w=0;w<VV;w++) Sm[u][w] *= r;
  }
  __syncthreads();
  float* gp = gout + (size_t)s*(VV*VV);
  for(int idx=tid; idx<VV*VV; idx+=256) gp[idx] = Sm[idx/VV][idx%VV];
}

// ---- Stage 1: ypre[i][d] = sum_j xs[i][j]*lw[j][d] ----
// PREV: input is previous block's y in zbuf layout, apply BN2d(A2p,B2p)+relu on load.
// lwf/lbf fp32; dwT is the TRANSPOSED down conv weight [CIN_][COUT_].
template<int CIN_, int COUT_, bool DOWN, bool PREV>
__global__ __launch_bounds__(256,3)
void k_stage1(const void* __restrict__ xin,
              const float* __restrict__ A2p, const float* __restrict__ B2p,
              const float* __restrict__ fmv,
              const float* __restrict__ lwf, const float* __restrict__ lbf,
              bf16* __restrict__ zbuf,
              const float* __restrict__ dwT, const float* __restrict__ dbf,
              float* __restrict__ dpart, const int* __restrict__ flag)
{
  constexpr int NS = 256/COUT_;
  constexpr int JC = CIN_/NS;
  const int s = blockIdx.x;
  const int n = s / TT, t = s % TT;
  const int tid = threadIdx.x;
  __shared__ __align__(16) float xt[CIN_][20];
  __shared__ __align__(16) float xsT[CIN_][20];   // xsT[j][i]
  __shared__ float pbuf[(NS-1)*COUT_*VV];
  __shared__ float ds1[DOWN?256:1], ds2[DOWN?256:1];

  if constexpr (PREV){
    const bf16* zin = (const bf16*)xin + (size_t)s*(CIN_*VV);
    for(int idx=tid; idx<CIN_*VV; idx+=256){
      int c = idx/VV, u = idx - c*VV;
      xt[c][u] = fmaxf(b2f(zin[idx])*A2p[c] + B2p[c], 0.f);
    }
  } else {
    const int mode = *flag;
    for(int idx=tid; idx<CIN_*VV; idx+=256){
      int c = idx/VV, u = idx - c*VV;
      xt[c][u] = ldi(xin, (((size_t)n*CIN_ + c)*TT + t)*VV + u, mode);
    }
  }
  if(tid < CIN_) xt[tid][19] = 0.f;   // zero pad column (read by DOWN u=19 lane)
  __syncthreads();
  for(int idx=tid; idx<CIN_*VV; idx+=256){
    int j = idx/VV, i = idx - j*VV;
    xsT[j][i] = xt[j][(i+j)%VV] * fmv[i*CIN_ + j];
  }
  __syncthreads();

  const int d  = tid % COUT_;
  const int sp = tid / COUT_;
  float acc[VV];
#pragma unroll
  for(int i=0;i<VV;i++) acc[i]=0.f;
  for(int j=sp*JC; j<(sp+1)*JC; j++){
    fma19(acc, lwf[j*COUT_ + d], xsT[j]);   // coalesced (d per-lane, stride 1)
  }
  if(sp > 0){
#pragma unroll
    for(int i=0;i<VV;i++) pbuf[((sp-1)*COUT_+d)*VV + i] = acc[i];
  }
  __syncthreads();
  if(sp == 0){
    float lbv = lbf[d];
    bf16* zp = zbuf + (size_t)s*(VV*COUT_);
#pragma unroll
    for(int i=0;i<VV;i++){
      float v = acc[i] + lbv;
#pragma unroll
      for(int q=1;q<NS;q++) v += pbuf[((q-1)*COUT_+d)*VV + i];
      zp[i*COUT_ + d] = f2b(v);
    }
  }
  if constexpr (DOWN){
    // down-conv BN stats: r[u] = db + sum_c dwT[c][oc]*xt[c][u]
    // dwT read coalesced (oc per-lane); xt reads are wave-broadcast (u uniform).
    const int oc  = tid & 127;
    const int grp = tid >> 7;           // wave-uniform
    float r[10];
    const float dbv = dbf[oc];
#pragma unroll
    for(int k=0;k<10;k++) r[k] = dbv;
#pragma unroll 4
    for(int c=0;c<CIN_;c++){
      float wc = dwT[c*COUT_ + oc];
      const float* xr = xt[c];
#pragma unroll
      for(int k=0;k<10;k++) r[k] += wc * xr[grp + 2*k];  // u==19 reads zero pad
    }
    float a1=0.f, a2=0.f;
#pragma unroll
    for(int k=0;k<10;k++){
      if(grp + 2*k < VV){ a1 += r[k]; a2 += r[k]*r[k]; }
    }
    ds1[tid]=a1; ds2[tid]=a2;
    __syncthreads();
    if(tid < 128){
      float* bucket = dpart + (size_t)(s & 63)*256;
      atomicAdd(&bucket[tid],       ds1[tid] + ds1[tid+128]);
      atomicAdd(&bucket[128 + tid], ds2[tid] + ds2[tid+128]);
    }
  }
}

// ---- column stats of [NT][F] bf16 buffer ----
__global__ __launch_bounds__(256)
void k_colstats(const bf16* __restrict__ zb, int F,
                float* __restrict__ s1, float* __restrict__ s2)
{
  int f = blockIdx.x*256 + threadIdx.x;
  if(f >= F) return;
  const int RP = NT/64;
  const bf16* p = zb + (size_t)(blockIdx.y*RP)*F + f;
  float a=0.f, b=0.f;
  for(int r=0; r<RP; r++){ float v = b2f(p[(size_t)r*F]); a += v; b += v*v; }
  atomicAdd(&s1[f], a);
  atomicAdd(&s2[f], b);
}

// ---- BN1d finalize with shift-out folded into index mapping ----
template<int COUT_>
__global__ void k_fin1(const float* __restrict__ s1, const float* __restrict__ s2,
                       const void* __restrict__ bng, const void* __restrict__ bnb,
                       float* __restrict__ A1, float* __restrict__ B1,
                       const int* __restrict__ flag)
{
  const int F = VV*COUT_;
  int fp = blockIdx.x*256 + threadIdx.x;
  if(fp >= F) return;
  int mode = *flag;
  int ip = fp/COUT_, d = fp - ip*COUT_;
  int f = ((ip + d)%VV)*COUT_ + d;        // post-shift feature
  float m = s1[fp] * (1.0f/NT);
  float v = s2[fp] * (1.0f/NT) - m*m;
  float a = ldi(bng, f, mode) * rsqrtf(v + EPSF);
  A1[fp] = a;
  B1[fp] = ldi(bnb, f, mode) - m*a;
}

// ---- BN2d finalize (per channel over (sample,u)) ----
template<int COUT_>
__global__ void k_fin2(const float* __restrict__ s1, const float* __restrict__ s2,
                       const void* __restrict__ bnsg, const void* __restrict__ bnsb,
                       float* __restrict__ A2, float* __restrict__ B2,
                       const int* __restrict__ flag)
{
  int d = threadIdx.x;
  if(d >= COUT_) return;
  int mode = *flag;
  float a=0.f, b=0.f;
  for(int u=0;u<VV;u++){ a += s1[d*VV+u]; b += s2[d*VV+u]; }
  const float inv = 1.0f/((float)NT*VV);
  float m = a*inv, v = b*inv - m*m;
  float g_ = ldi(bnsg, d, mode) * rsqrtf(v + EPSF);
  A2[d] = g_;
  B2[d] = ldi(bnsb, d, mode) - m*g_;
}

// ---- reduce 64 buckets -> A2d/B2d for the down-path BN ----
__global__ void k_dfin(const float* __restrict__ dpart, const void* __restrict__ dbng,
                       const void* __restrict__ dbnb, float* __restrict__ A2d,
                       float* __restrict__ B2d, const int* __restrict__ flag){
  int c = threadIdx.x;           // 256 threads: c<128 -> sum, c>=128 -> sumsq
  int mode = *flag;
  float a = 0.f;
  for(int r=0;r<64;r++) a += dpart[(size_t)r*256 + c];
  __shared__ float red[256];
  red[c] = a;
  __syncthreads();
  if(c < 128){
    const float inv = 1.0f/((float)NT*VV);
    float m = red[c]*inv;
    float v = red[128+c]*inv - m*m;
    float g_ = ldi(dbng, c, mode) * rsqrtf(v + EPSF);
    A2d[c] = g_;
    B2d[c] = ldi(dbnb, c, mode) - m*g_;
  }
}

// ---- Stage 2: BN1d + residual + ReLU, then FUSED (ww*X2)*G^T + w1*X2 -> y ----
// Algebra: Y = ww*(X2*G^T) + w1*X2 = (ww*X2)*G^T + w1*X2 -> graph matmul applied
// per-thread in registers to the conv partials (linear, commutes with K-split).
// gt read straight from global gmat with block-uniform addresses (scalar loads).
template<int CIN_, int COUT_, bool DOWN, bool PREV>
__global__ __launch_bounds__(256,4)
void k_stage2(const void* __restrict__ xin,
              const float* __restrict__ A2p, const float* __restrict__ B2p,
              bf16* __restrict__ zy,
              const float* __restrict__ A1, const float* __restrict__ B1,
              const float* __restrict__ gmat,
              const float* __restrict__ wwT, const float* __restrict__ w1T,
              const float* __restrict__ w1bf,
              const float* __restrict__ dwT, const float* __restrict__ dbf,
              const float* __restrict__ A2d, const float* __restrict__ B2d,
              const int* __restrict__ flag)
{
  constexpr int NS = 256/COUT_;
  constexpr int F  = VV*COUT_;
  constexpr int CC = COUT_/NS;
  const int s = blockIdx.x;
  const int n = s/TT, t = s % TT;
  const int tid = threadIdx.x;
  __shared__ __align__(16) float X2[COUT_][20];   // [channel][node]
  __shared__ __align__(16) float XT[CIN_][20];
  __shared__ float comb[(NS-1)*COUT_*VV];

  if constexpr (PREV){
    const bf16* zin = (const bf16*)xin + (size_t)s*(CIN_*VV);
    for(int idx=tid; idx<CIN_*VV; idx+=256){
      int c = idx/VV, u = idx - c*VV;
      XT[c][u] = fmaxf(b2f(zin[idx])*A2p[c] + B2p[c], 0.f);
    }
  } else {
    const int mode = *flag;
    for(int idx=tid; idx<CIN_*VV; idx+=256){
      int c = idx/VV, u = idx - c*VV;
      XT[c][u] = ldi(xin, (((size_t)n*CIN_ + c)*TT + t)*VV + u, mode);
    }
  }
  __syncthreads();

  bf16* zp = zy + (size_t)s*F;
  if constexpr (DOWN){
    // per-thread d is constant (COUT_=128, stride 256): accumulate down-conv per u.
    const int d0 = tid & 127;
    const int g0 = tid >> 7;
    float rr[10];
    const float dbv = dbf[d0];
#pragma unroll
    for(int k=0;k<10;k++) rr[k] = dbv;
    int uarr[10];
#pragma unroll
    for(int k=0;k<10;k++) uarr[k] = (g0 + 2*k + d0) % VV;
#pragma unroll 4
    for(int c=0;c<CIN_;c++){
      float wc = dwT[c*COUT_ + d0];   // coalesced
      const float* xr = XT[c];
#pragma unroll
      for(int k=0;k<10;k++) rr[k] += wc * xr[uarr[k]];
    }
    // fixed-trip unrolled loop: rr[k]/uarr[k] stay compile-time-indexed (rule #20)
#pragma unroll
    for(int k=0;k<10;k++){
      int idx = tid + k*256;
      if(idx < F){
        int ip = idx/COUT_, d = idx - ip*COUT_;
        int u = uarr[k];
        float res = rr[k]*A2d[d] + B2d[d];
        float v = b2f(zp[idx])*A1[idx] + B1[idx] + res;
        X2[d][u] = fmaxf(v, 0.f);
      }
    }
  } else {
    for(int idx=tid; idx<F; idx+=256){
      int ip = idx/COUT_, d = idx - ip*COUT_;
      int u = (ip + d) % VV;
      float res = XT[d][u];
      float v = b2f(zp[idx])*A1[idx] + B1[idx] + res;
      X2[d][u] = fmaxf(v, 0.f);
    }
  }
  __syncthreads();

  const int d  = tid % COUT_;
  const int sp = tid / COUT_;
  float accw[VV], acc1[VV];
#pragma unroll
  for(int i=0;i<VV;i++){ accw[i]=0.f; acc1[i]=0.f; }
#pragma unroll 4
  for(int c=sp*CC; c<(sp+1)*CC; c++){
    const float* row = X2[c];               // single row feeds BOTH convs
    fma19(accw, wwT[c*COUT_ + d], row);     // coalesced weight loads
    fma19(acc1, w1T[c*COUT_ + d], row);
  }
  // graph apply on partials (registers only; gt via uniform-address scalar loads)
  const float* __restrict__ gp = gmat + (size_t)s*(VV*VV);
#pragma unroll
  for(int i=0;i<VV;i++){
    float o = acc1[i];
#pragma unroll
    for(int w=0;w<VV;w++) o += gp[i*VV+w]*accw[w];
    acc1[i] = o;
  }
  if(sp > 0){
#pragma unroll
    for(int i=0;i<VV;i++) comb[((sp-1)*COUT_+d)*VV + i] = acc1[i];
  }
  __syncthreads();
  if(sp == 0){
    float bv = w1bf[d];
#pragma unroll
    for(int i=0;i<VV;i++){
      float v = acc1[i] + bv;
#pragma unroll
      for(int q=1;q<NS;q++) v += comb[((q-1)*COUT_+d)*VV + i];
      zp[d*VV + i] = f2b(v);
    }
  }
}

// ---- Stage 3 (final only): BN2d + ReLU -> output [n][d][t][u]; NaN canary ----
template<int COUT_>
__global__ __launch_bounds__(256)
void k_stage3(const bf16* __restrict__ ybuf, const float* __restrict__ A2,
              const float* __restrict__ B2, void* __restrict__ out,
              const int* __restrict__ flag)
{
  const int s = blockIdx.x, n = s/TT, t = s % TT, tid = threadIdx.x;
  const int mode = *flag;
  constexpr int F = VV*COUT_;
  const bf16* yp = ybuf + (size_t)s*F;
  for(int idx=tid; idx<F; idx+=256){
    int d = idx/VV, u = idx - d*VV;
    float v0 = b2f(yp[idx])*A2[d] + B2[d];
    float v = fmaxf(v0, 0.f);
    if(!(v0 == v0) || fabsf(v0) > 1e30f) v = 1000.0f;   // NaN/Inf canary
    size_t o = (((size_t)n*COUT_ + d)*TT + t)*VV + u;
    if(mode) ((float*)out)[o] = v;
    else     ((bf16*)out)[o]  = f2b(v);
  }
}

extern "C" void kernel_launch(void* const* d_in, const int* in_sizes, int n_in,
                              void* d_out, int out_size, void* d_ws, size_t ws_size,
                              hipStream_t stream)
{
  const void* in[39];
  for(int i=0;i<39;i++) in[i] = d_in[i];

  char* ws = (char*)d_ws;
  size_t off = 0;
  auto alloc = [&](size_t bytes)->void*{
    void* p = ws + off;
    off = (off + bytes + 255) & ~(size_t)255;
    return p;
  };
  int*   flag = (int*)  alloc(4);
  float* gmat = (float*)alloc((size_t)NT*VV*VV*4);      // 23.7 MB
  bf16*  zA   = (bf16*) alloc((size_t)NT*2432*2);       // 79.7 MB
  bf16*  zB   = (bf16*) alloc((size_t)NT*2432*2);       // 79.7 MB
  float* dpart= (float*)alloc((size_t)64*256*4);        // 64 KB
  float* s1   = (float*)alloc(2432*4);
  float* s2   = (float*)alloc(2432*4);
  float* A1   = (float*)alloc(2432*4);
  float* B1   = (float*)alloc(2432*4);
  float* A2b1 = (float*)alloc(128*4);
  float* B2b1 = (float*)alloc(128*4);
  float* A2b2 = (float*)alloc(128*4);
  float* B2b2 = (float*)alloc(128*4);
  float* A2b3 = (float*)alloc(128*4);
  float* B2b3 = (float*)alloc(128*4);
  float* A2d  = (float*)alloc(128*4);
  float* B2d  = (float*)alloc(128*4);
  float* fmv1 = (float*)alloc(1216*4);
  float* fmv2 = (float*)alloc(1216*4);
  float* fmv3 = (float*)alloc(2432*4);
  // fp32 weight copies; *T = transposed (wT[c*rows + d])
  float* b1_lwf  = (float*)alloc(64*64*4);
  float* b1_lbf  = (float*)alloc(64*4);
  float* b1_wwT  = (float*)alloc(64*64*4);
  float* b1_w1T  = (float*)alloc(64*64*4);
  float* b1_w1bf = (float*)alloc(64*4);
  float* b2_lwf  = (float*)alloc(64*128*4);
  float* b2_lbf  = (float*)alloc(128*4);
  float* b2_wwT  = (float*)alloc(128*128*4);
  float* b2_w1T  = (float*)alloc(128*128*4);
  float* b2_w1bf = (float*)alloc(128*4);
  float* b2_dwT  = (float*)alloc(128*64*4);
  float* b2_dbf  = (float*)alloc(128*4);
  float* b3_lwf  = (float*)alloc(128*128*4);
  float* b3_lbf  = (float*)alloc(128*4);
  float* b3_wwT  = (float*)alloc(128*128*4);
  float* b3_w1T  = (float*)alloc(128*128*4);
  float* b3_w1bf = (float*)alloc(128*4);
  float* g1wT    = (float*)alloc(32*64*4);
  float* g1bf    = (float*)alloc(32*4);
  float* g2wT    = (float*)alloc(32*64*4);
  float* g2bf    = (float*)alloc(32*4);

  if(ws_size < off){
    // workspace too small sentinel: fill out with ~12.06 (bf16 0x4141 pattern)
    hipMemsetAsync(d_out, 0x41, (size_t)out_size*2, stream);
    return;
  }

  k_detect<<<1,256,0,stream>>>((const unsigned short*)in[0], flag);
  k_canary<<<(out_size+255)/256,256,0,stream>>>(d_out, out_size, flag);

  auto cvt = [&](const void* src, float* dst, int n){
    k_cvt<<<(n+255)/256,256,0,stream>>>(src, dst, n, flag);
  };
  auto cvtT = [&](const void* src, float* dst, int rows, int cols){
    k_cvtT<<<(rows*cols+255)/256,256,0,stream>>>(src, dst, rows, cols, flag);
  };
  cvt (in[5],  b1_lwf,  64*64);      cvt(in[6],  b1_lbf,  64);
  cvtT(in[12], b1_wwT,  64, 64);     cvtT(in[13], b1_w1T, 64, 64);   cvt(in[14], b1_w1bf, 64);
  cvt (in[15], b2_lwf,  64*128);     cvt(in[16], b2_lbf,  128);
  cvtT(in[22], b2_wwT,  128, 128);   cvtT(in[23], b2_w1T, 128, 128); cvt(in[24], b2_w1bf, 128);
  cvtT(in[25], b2_dwT,  128, 64);    cvt(in[26], b2_dbf,  128);
  cvt (in[29], b3_lwf,  128*128);    cvt(in[30], b3_lbf,  128);
  cvtT(in[36], b3_wwT,  128, 128);   cvtT(in[37], b3_w1T, 128, 128); cvt(in[38], b3_w1bf, 128);
  cvtT(in[1],  g1wT,    32, 64);     cvt(in[2],  g1bf,    32);
  cvtT(in[3],  g2wT,    32, 64);     cvt(in[4],  g2bf,    32);

  k_tanhp1<<<5,256,0,stream>>>(in[7],  fmv1, 1216, flag);
  k_tanhp1<<<5,256,0,stream>>>(in[17], fmv2, 1216, flag);
  k_tanhp1<<<10,256,0,stream>>>(in[31], fmv3, 2432, flag);
  k_gspa<<<NT,256,0,stream>>>(in[0], g1wT, g1bf, g2wT, g2bf, gmat, flag);

  // ---- Block 1 (64 -> 64, identity residual), input = x0, ypre/y in zA ----
  k_stage1<64,64,false,false><<<NT,256,0,stream>>>(in[0], nullptr, nullptr, fmv1,
                                                   b1_lwf, b1_lbf, zA,
                                                   nullptr, nullptr, nullptr, flag);
  k_zero<<<19,256,0,stream>>>(s1, 2*2432);   // s1,s2 contiguous
  k_colstats<<<dim3(5,64),256,0,stream>>>(zA, 1216, s1, s2);
  k_fin1<64><<<5,256,0,stream>>>(s1, s2, in[8], in[9], A1, B1, flag);
  k_stage2<64,64,false,false><<<NT,256,0,stream>>>(in[0], nullptr, nullptr, zA, A1, B1,
                                                   gmat, b1_wwT, b1_w1T, b1_w1bf,
                                                   nullptr, nullptr, nullptr, nullptr, flag);
  k_zero<<<19,256,0,stream>>>(s1, 2*2432);
  k_colstats<<<dim3(5,64),256,0,stream>>>(zA, 1216, s1, s2);
  k_fin2<64><<<1,64,0,stream>>>(s1, s2, in[10], in[11], A2b1, B2b1, flag);

  // ---- Block 2 (64 -> 128, down path), input = BN2d(zA)+relu, ypre/y in zB ----
  k_zero<<<64,256,0,stream>>>(dpart, 64*256);
  k_stage1<64,128,true,true><<<NT,256,0,stream>>>(zA, A2b1, B2b1, fmv2,
                                                  b2_lwf, b2_lbf, zB,
                                                  b2_dwT, b2_dbf, dpart, flag);
  k_dfin<<<1,256,0,stream>>>(dpart, in[27], in[28], A2d, B2d, flag);
  k_zero<<<19,256,0,stream>>>(s1, 2*2432);
  k_colstats<<<dim3(10,64),256,0,stream>>>(zB, 2432, s1, s2);
  k_fin1<128><<<10,256,0,stream>>>(s1, s2, in[18], in[19], A1, B1, flag);
  k_stage2<64,128,true,true><<<NT,256,0,stream>>>(zA, A2b1, B2b1, zB, A1, B1,
                                                  gmat, b2_wwT, b2_w1T, b2_w1bf,
                                                  b2_dwT, b2_dbf, A2d, B2d, flag);
  k_zero<<<19,256,0,stream>>>(s1, 2*2432);
  k_colstats<<<dim3(10,64),256,0,stream>>>(zB, 2432, s1, s2);
  k_fin2<128><<<1,128,0,stream>>>(s1, s2, in[20], in[21], A2b2, B2b2, flag);

  // ---- Block 3 (128 -> 128, identity), input = BN2d(zB)+relu, ypre/y in zA ----
  k_stage1<128,128,false,true><<<NT,256,0,stream>>>(zB, A2b2, B2b2, fmv3,
                                                    b3_lwf, b3_lbf, zA,
                                                    nullptr, nullptr, nullptr, flag);
  k_zero<<<19,256,0,stream>>>(s1, 2*2432);
  k_colstats<<<dim3(10,64),256,0,stream>>>(zA, 2432, s1, s2);
  k_fin1<128><<<10,256,0,stream>>>(s1, s2, in[32], in[33], A1, B1, flag);
  k_stage2<128,128,false,true><<<NT,256,0,stream>>>(zB, A2b2, B2b2, zA, A1, B1,
                                                    gmat, b3_wwT, b3_w1T, b3_w1bf,
                                                    nullptr, nullptr, nullptr, nullptr, flag);
  k_zero<<<19,256,0,stream>>>(s1, 2*2432);
  k_colstats<<<dim3(10,64),256,0,stream>>>(zA, 2432, s1, s2);
  k_fin2<128><<<1,128,0,stream>>>(s1, s2, in[34], in[35], A2b3, B2b3, flag);
  k_stage3<128><<<NT,256,0,stream>>>(zA, A2b3, B2b3, d_out, flag);
}

// Round 5
// 2383.700 us; speedup vs baseline: 6.6259x; 1.0016x over previous
//
#include <hip/hip_runtime.h>
#include <hip/hip_bf16.h>

typedef __hip_bfloat16 bf16;

#define NBATCH 128
#define TT 128
#define VV 19
#define NT (NBATCH*TT)
#define EPSF 1e-5f

static __device__ __forceinline__ float b2f(bf16 v){ return __bfloat162float(v); }
static __device__ __forceinline__ bf16  f2b(float v){ return __float2bfloat16(v); }
// dual-dtype input load: mode=1 -> fp32, mode=0 -> bf16
static __device__ __forceinline__ float ldi(const void* p, size_t i, int mode){
  return mode ? ((const float*)p)[i] : b2f(((const bf16*)p)[i]);
}

// acc[0..18] += w * row[0..18]; row is 16B-aligned, 20 floats long (pad)
static __device__ __forceinline__ void fma19(float* acc, float w, const float* row){
  const float4* r = (const float4*)row;
  float4 a=r[0], b=r[1], c=r[2], d=r[3], e=r[4];
  acc[0]+=w*a.x;  acc[1]+=w*a.y;  acc[2]+=w*a.z;  acc[3]+=w*a.w;
  acc[4]+=w*b.x;  acc[5]+=w*b.y;  acc[6]+=w*b.z;  acc[7]+=w*b.w;
  acc[8]+=w*c.x;  acc[9]+=w*c.y;  acc[10]+=w*c.z; acc[11]+=w*c.w;
  acc[12]+=w*d.x; acc[13]+=w*d.y; acc[14]+=w*d.z; acc[15]+=w*d.w;
  acc[16]+=w*e.x; acc[17]+=w*e.y; acc[18]+=w*e.z;
}

// ---- detect input dtype: fp32 buffers read as bf16 have wild exponents ----
__global__ void k_detect(const unsigned short* __restrict__ p, int* __restrict__ flag){
  const int tid = threadIdx.x;
  __shared__ int cnt;
  if(tid==0) cnt = 0;
  __syncthreads();
  int local = 0;
  for(int i=tid; i<2048; i+=256){
    unsigned short h = p[i];
    int e = (h>>7) & 0xFF;                 // bf16 exponent field
    if(h != 0 && (e < 107 || e > 147)) local++;   // |v| outside ~[2^-20, 2^20]
  }
  atomicAdd(&cnt, local);
  __syncthreads();
  if(tid==0) *flag = (cnt > 300) ? 1 : 0;
}

// ---- canary: pre-fill output with 3.0 (overwritten by stage3 if pipeline completes) ----
__global__ void k_canary(void* __restrict__ out, int n, const int* __restrict__ flag){
  int i = blockIdx.x*256 + threadIdx.x;
  if(i >= n) return;
  if(*flag) ((float*)out)[i] = 3.0f;
  else      ((bf16*)out)[i]  = f2b(3.0f);
}

__global__ void k_zero(float* __restrict__ p, int n){
  int i = blockIdx.x*256 + threadIdx.x;
  if(i < n) p[i] = 0.f;
}

// ---- convert a weight buffer (bf16 or fp32) to fp32 workspace copy ----
__global__ void k_cvt(const void* __restrict__ src, float* __restrict__ dst, int n,
                      const int* __restrict__ flag){
  int i = blockIdx.x*256 + threadIdx.x;
  if(i < n) dst[i] = ldi(src, i, *flag);
}

// ---- transposed fp32 copy: dst[c*rows + r] = src[r*cols + c] ----
// makes per-lane-d weight reads coalesced in the hot loops
__global__ void k_cvtT(const void* __restrict__ src, float* __restrict__ dst,
                       int rows, int cols, const int* __restrict__ flag){
  int i = blockIdx.x*256 + threadIdx.x;
  if(i < rows*cols){
    int r = i / cols, c = i - r*cols;
    dst[c*rows + r] = ldi(src, i, *flag);
  }
}

// ---- paired transposed copy: dst[c*rows + r] = {A[r,c], B[r,c]} (float2) ----
// one 8B coalesced load per c in the stage2 conv loop instead of two 4B streams
__global__ void k_cvtP(const void* __restrict__ srcA, const void* __restrict__ srcB,
                       float2* __restrict__ dst, int rows, int cols,
                       const int* __restrict__ flag){
  int i = blockIdx.x*256 + threadIdx.x;
  if(i < rows*cols){
    int r = i / cols, c = i - r*cols;
    int mode = *flag;
    dst[c*rows + r] = make_float2(ldi(srcA, i, mode), ldi(srcB, i, mode));
  }
}

// ---- fmv = tanh(fm)+1 ----
__global__ void k_tanhp1(const void* __restrict__ fm, float* __restrict__ out, int n,
                         const int* __restrict__ flag){
  int i = blockIdx.x*256 + threadIdx.x;
  int mode = *flag;
  if(i < n) out[i] = tanhf(ldi(fm, i, mode)) + 1.0f;
}

// ---- g = softmax( A @ B ) per (n,t); weights pre-transposed fp32 ----
__global__ __launch_bounds__(256)
void k_gspa(const void* __restrict__ x0,
            const float* __restrict__ w1T, const float* __restrict__ b1f,
            const float* __restrict__ w2T, const float* __restrict__ b2f,
            float* __restrict__ gout, const int* __restrict__ flag)
{
  const int s = blockIdx.x;
  const int n = s / TT, t = s % TT;
  const int tid = threadIdx.x;
  const int mode = *flag;
  __shared__ float xt[64][20];
  __shared__ float Am[VV][33];
  __shared__ float Bm[32][21];
  __shared__ float Sm[VV][21];
  for(int idx=tid; idx<64*VV; idx+=256){
    int c = idx/VV, u = idx - c*VV;
    xt[c][u] = ldi(x0, (((size_t)n*64 + c)*TT + t)*VV + u, mode);
  }
  __syncthreads();
  for(int idx=tid; idx<VV*32; idx+=256){
    int u = idx/32, k = idx & 31;
    float acc = b1f[k];
    for(int c=0;c<64;c++) acc += xt[c][u]*w1T[c*32+k];   // w1T coalesced in k
    Am[u][k] = acc;
  }
  for(int idx=tid; idx<32*VV; idx+=256){
    int k = idx/VV, w = idx - k*VV;
    float acc = b2f[k];
    for(int c=0;c<64;c++) acc += xt[c][w]*w2T[c*32+k];
    Bm[k][w] = acc;
  }
  __syncthreads();
  for(int idx=tid; idx<VV*VV; idx+=256){
    int u = idx/VV, w = idx - u*VV;
    float acc = 0.f;
#pragma unroll
    for(int k=0;k<32;k++) acc += Am[u][k]*Bm[k][w];
    Sm[u][w] = acc;
  }
  __syncthreads();
  if(tid < VV){
    int u = tid;
    float mx = -1e30f;
    for(int w=0;w<VV;w++) mx = fmaxf(mx, Sm[u][w]);
    float sum = 0.f;
    for(int w=0;w<VV;w++){ float e = __expf(Sm[u][w]-mx); Sm[u][w]=e; sum+=e; }
    float r = 1.0f/sum;
    for(int w=0;w<VV;w++) Sm[u][w] *= r;
  }
  __syncthreads();
  float* gp = gout + (size_t)s*(VV*VV);
  for(int idx=tid; idx<VV*VV; idx+=256) gp[idx] = Sm[idx/VV][idx%VV];
}

// ---- Stage 1: ypre[i][d] = sum_j xs[i][j]*lw[j][d] ----
// PREV: input is previous block's y in zbuf layout, apply BN2d(A2p,B2p)+relu on load.
// lwf/lbf fp32; dwT is the TRANSPOSED down conv weight [CIN_][COUT_].
// launch_bounds(256,6): VGPR cap 85 >> ~50 used; residency limited by LDS (5-7 blk/CU).
template<int CIN_, int COUT_, bool DOWN, bool PREV>
__global__ __launch_bounds__(256,6)
void k_stage1(const void* __restrict__ xin,
              const float* __restrict__ A2p, const float* __restrict__ B2p,
              const float* __restrict__ fmv,
              const float* __restrict__ lwf, const float* __restrict__ lbf,
              bf16* __restrict__ zbuf,
              const float* __restrict__ dwT, const float* __restrict__ dbf,
              float* __restrict__ dpart, const int* __restrict__ flag)
{
  constexpr int NS = 256/COUT_;
  constexpr int JC = CIN_/NS;
  const int s = blockIdx.x;
  const int n = s / TT, t = s % TT;
  const int tid = threadIdx.x;
  __shared__ __align__(16) float xt[CIN_][20];
  __shared__ __align__(16) float xsT[CIN_][20];   // xsT[j][i]
  __shared__ float pbuf[(NS-1)*COUT_*VV];
  __shared__ float ds1[DOWN?256:1], ds2[DOWN?256:1];

  if constexpr (PREV){
    const bf16* zin = (const bf16*)xin + (size_t)s*(CIN_*VV);
    for(int idx=tid; idx<CIN_*VV; idx+=256){
      int c = idx/VV, u = idx - c*VV;
      xt[c][u] = fmaxf(b2f(zin[idx])*A2p[c] + B2p[c], 0.f);
    }
  } else {
    const int mode = *flag;
    for(int idx=tid; idx<CIN_*VV; idx+=256){
      int c = idx/VV, u = idx - c*VV;
      xt[c][u] = ldi(xin, (((size_t)n*CIN_ + c)*TT + t)*VV + u, mode);
    }
  }
  if(tid < CIN_) xt[tid][19] = 0.f;   // zero pad column (read by DOWN u=19 lane)
  __syncthreads();
  for(int idx=tid; idx<CIN_*VV; idx+=256){
    int j = idx/VV, i = idx - j*VV;
    xsT[j][i] = xt[j][(i+j)%VV] * fmv[i*CIN_ + j];
  }
  __syncthreads();

  const int d  = tid % COUT_;
  const int sp = tid / COUT_;
  float acc[VV];
#pragma unroll
  for(int i=0;i<VV;i++) acc[i]=0.f;
  {
    const float* lp = lwf + sp*JC*COUT_ + d;     // pointer-bump stream
#pragma unroll 4
    for(int j=0;j<JC;j++){
      fma19(acc, *lp, xsT[sp*JC + j]);
      lp += COUT_;
    }
  }
  if(sp > 0){
#pragma unroll
    for(int i=0;i<VV;i++) pbuf[((sp-1)*COUT_+d)*VV + i] = acc[i];
  }
  __syncthreads();
  if(sp == 0){
    float lbv = lbf[d];
    bf16* zp = zbuf + (size_t)s*(VV*COUT_);
#pragma unroll
    for(int i=0;i<VV;i++){
      float v = acc[i] + lbv;
#pragma unroll
      for(int q=1;q<NS;q++) v += pbuf[((q-1)*COUT_+d)*VV + i];
      zp[i*COUT_ + d] = f2b(v);
    }
  }
  if constexpr (DOWN){
    // down-conv BN stats: r[u] = db + sum_c dwT[c][oc]*xt[c][u]
    // dwT read coalesced (oc per-lane); xt reads are wave-broadcast (u uniform).
    const int oc  = tid & 127;
    const int grp = tid >> 7;           // wave-uniform
    float r[10];
    const float dbv = dbf[oc];
#pragma unroll
    for(int k=0;k<10;k++) r[k] = dbv;
#pragma unroll 4
    for(int c=0;c<CIN_;c++){
      float wc = dwT[c*COUT_ + oc];
      const float* xr = xt[c];
#pragma unroll
      for(int k=0;k<10;k++) r[k] += wc * xr[grp + 2*k];  // u==19 reads zero pad
    }
    float a1=0.f, a2=0.f;
#pragma unroll
    for(int k=0;k<10;k++){
      if(grp + 2*k < VV){ a1 += r[k]; a2 += r[k]*r[k]; }
    }
    ds1[tid]=a1; ds2[tid]=a2;
    __syncthreads();
    if(tid < 128){
      float* bucket = dpart + (size_t)(s & 63)*256;
      atomicAdd(&bucket[tid],       ds1[tid] + ds1[tid+128]);
      atomicAdd(&bucket[128 + tid], ds2[tid] + ds2[tid+128]);
    }
  }
}

// ---- column stats of [NT][F] bf16 buffer ----
__global__ __launch_bounds__(256)
void k_colstats(const bf16* __restrict__ zb, int F,
                float* __restrict__ s1, float* __restrict__ s2)
{
  int f = blockIdx.x*256 + threadIdx.x;
  if(f >= F) return;
  const int RP = NT/64;
  const bf16* p = zb + (size_t)(blockIdx.y*RP)*F + f;
  float a=0.f, b=0.f;
  for(int r=0; r<RP; r++){ float v = b2f(p[(size_t)r*F]); a += v; b += v*v; }
  atomicAdd(&s1[f], a);
  atomicAdd(&s2[f], b);
}

// ---- BN1d finalize with shift-out folded into index mapping ----
template<int COUT_>
__global__ void k_fin1(const float* __restrict__ s1, const float* __restrict__ s2,
                       const void* __restrict__ bng, const void* __restrict__ bnb,
                       float* __restrict__ A1, float* __restrict__ B1,
                       const int* __restrict__ flag)
{
  const int F = VV*COUT_;
  int fp = blockIdx.x*256 + threadIdx.x;
  if(fp >= F) return;
  int mode = *flag;
  int ip = fp/COUT_, d = fp - ip*COUT_;
  int f = ((ip + d)%VV)*COUT_ + d;        // post-shift feature
  float m = s1[fp] * (1.0f/NT);
  float v = s2[fp] * (1.0f/NT) - m*m;
  float a = ldi(bng, f, mode) * rsqrtf(v + EPSF);
  A1[fp] = a;
  B1[fp] = ldi(bnb, f, mode) - m*a;
}

// ---- BN2d finalize (per channel over (sample,u)) ----
template<int COUT_>
__global__ void k_fin2(const float* __restrict__ s1, const float* __restrict__ s2,
                       const void* __restrict__ bnsg, const void* __restrict__ bnsb,
                       float* __restrict__ A2, float* __restrict__ B2,
                       const int* __restrict__ flag)
{
  int d = threadIdx.x;
  if(d >= COUT_) return;
  int mode = *flag;
  float a=0.f, b=0.f;
  for(int u=0;u<VV;u++){ a += s1[d*VV+u]; b += s2[d*VV+u]; }
  const float inv = 1.0f/((float)NT*VV);
  float m = a*inv, v = b*inv - m*m;
  float g_ = ldi(bnsg, d, mode) * rsqrtf(v + EPSF);
  A2[d] = g_;
  B2[d] = ldi(bnsb, d, mode) - m*g_;
}

// ---- reduce 64 buckets -> A2d/B2d for the down-path BN ----
__global__ void k_dfin(const float* __restrict__ dpart, const void* __restrict__ dbng,
                       const void* __restrict__ dbnb, float* __restrict__ A2d,
                       float* __restrict__ B2d, const int* __restrict__ flag){
  int c = threadIdx.x;           // 256 threads: c<128 -> sum, c>=128 -> sumsq
  int mode = *flag;
  float a = 0.f;
  for(int r=0;r<64;r++) a += dpart[(size_t)r*256 + c];
  __shared__ float red[256];
  red[c] = a;
  __syncthreads();
  if(c < 128){
    const float inv = 1.0f/((float)NT*VV);
    float m = red[c]*inv;
    float v = red[128+c]*inv - m*m;
    float g_ = ldi(dbng, c, mode) * rsqrtf(v + EPSF);
    A2d[c] = g_;
    B2d[c] = ldi(dbnb, c, mode) - m*g_;
  }
}

// ---- Stage 2: BN1d + residual + ReLU, then FUSED (ww*X2)*G^T + w1*X2 -> y ----
// Algebra: Y = ww*(X2*G^T) + w1*X2 = (ww*X2)*G^T + w1*X2 -> graph matmul applied
// per-thread in registers to the conv partials (linear, commutes with K-split).
// gt read straight from global gmat with block-uniform addresses (scalar loads).
// wpair = interleaved {ww, w1} float2 stream -> 1 coalesced 8B load per c.
template<int CIN_, int COUT_, bool DOWN, bool PREV>
__global__ __launch_bounds__(256,6)
void k_stage2(const void* __restrict__ xin,
              const float* __restrict__ A2p, const float* __restrict__ B2p,
              bf16* __restrict__ zy,
              const float* __restrict__ A1, const float* __restrict__ B1,
              const float* __restrict__ gmat,
              const float2* __restrict__ wpair,
              const float* __restrict__ w1bf,
              const float* __restrict__ dwT, const float* __restrict__ dbf,
              const float* __restrict__ A2d, const float* __restrict__ B2d,
              const int* __restrict__ flag)
{
  constexpr int NS = 256/COUT_;
  constexpr int F  = VV*COUT_;
  constexpr int CC = COUT_/NS;
  const int s = blockIdx.x;
  const int n = s/TT, t = s % TT;
  const int tid = threadIdx.x;
  __shared__ __align__(16) float X2[COUT_][20];   // [channel][node]
  __shared__ __align__(16) float XT[CIN_][20];
  __shared__ float comb[(NS-1)*COUT_*VV];

  if constexpr (PREV){
    const bf16* zin = (const bf16*)xin + (size_t)s*(CIN_*VV);
    for(int idx=tid; idx<CIN_*VV; idx+=256){
      int c = idx/VV, u = idx - c*VV;
      XT[c][u] = fmaxf(b2f(zin[idx])*A2p[c] + B2p[c], 0.f);
    }
  } else {
    const int mode = *flag;
    for(int idx=tid; idx<CIN_*VV; idx+=256){
      int c = idx/VV, u = idx - c*VV;
      XT[c][u] = ldi(xin, (((size_t)n*CIN_ + c)*TT + t)*VV + u, mode);
    }
  }
  __syncthreads();

  bf16* zp = zy + (size_t)s*F;
  if constexpr (DOWN){
    // per-thread d is constant (COUT_=128, stride 256): accumulate down-conv per u.
    const int d0 = tid & 127;
    const int g0 = tid >> 7;
    float rr[10];
    const float dbv = dbf[d0];
#pragma unroll
    for(int k=0;k<10;k++) rr[k] = dbv;
    int uarr[10];
#pragma unroll
    for(int k=0;k<10;k++) uarr[k] = (g0 + 2*k + d0) % VV;
#pragma unroll 4
    for(int c=0;c<CIN_;c++){
      float wc = dwT[c*COUT_ + d0];   // coalesced
      const float* xr = XT[c];
#pragma unroll
      for(int k=0;k<10;k++) rr[k] += wc * xr[uarr[k]];
    }
    // fixed-trip unrolled loop: rr[k]/uarr[k] stay compile-time-indexed (rule #20)
#pragma unroll
    for(int k=0;k<10;k++){
      int idx = tid + k*256;
      if(idx < F){
        int ip = idx/COUT_, d = idx - ip*COUT_;
        int u = uarr[k];
        float res = rr[k]*A2d[d] + B2d[d];
        float v = b2f(zp[idx])*A1[idx] + B1[idx] + res;
        X2[d][u] = fmaxf(v, 0.f);
      }
    }
  } else {
    for(int idx=tid; idx<F; idx+=256){
      int ip = idx/COUT_, d = idx - ip*COUT_;
      int u = (ip + d) % VV;
      float res = XT[d][u];
      float v = b2f(zp[idx])*A1[idx] + B1[idx] + res;
      X2[d][u] = fmaxf(v, 0.f);
    }
  }
  __syncthreads();

  const int d  = tid % COUT_;
  const int sp = tid / COUT_;
  float accw[VV], acc1[VV];
#pragma unroll
  for(int i=0;i<VV;i++){ accw[i]=0.f; acc1[i]=0.f; }
  {
    const float2* wp = wpair + sp*CC*COUT_ + d;   // single 8B stream, pointer-bump
#pragma unroll 4
    for(int c=0;c<CC;c++){
      float2 w = *wp; wp += COUT_;
      const float* row = X2[sp*CC + c];           // single row feeds BOTH convs
      fma19(accw, w.x, row);
      fma19(acc1, w.y, row);
    }
  }
  // graph apply on partials (registers only; gt via uniform-address scalar loads)
  const float* __restrict__ gp = gmat + (size_t)s*(VV*VV);
#pragma unroll
  for(int i=0;i<VV;i++){
    float o = acc1[i];
#pragma unroll
    for(int w=0;w<VV;w++) o += gp[i*VV+w]*accw[w];
    acc1[i] = o;
  }
  if(sp > 0){
#pragma unroll
    for(int i=0;i<VV;i++) comb[((sp-1)*COUT_+d)*VV + i] = acc1[i];
  }
  __syncthreads();
  if(sp == 0){
    float bv = w1bf[d];
#pragma unroll
    for(int i=0;i<VV;i++){
      float v = acc1[i] + bv;
#pragma unroll
      for(int q=1;q<NS;q++) v += comb[((q-1)*COUT_+d)*VV + i];
      zp[d*VV + i] = f2b(v);
    }
  }
}

// ---- Stage 3 (final only): BN2d + ReLU -> output [n][d][t][u]; NaN canary ----
template<int COUT_>
__global__ __launch_bounds__(256)
void k_stage3(const bf16* __restrict__ ybuf, const float* __restrict__ A2,
              const float* __restrict__ B2, void* __restrict__ out,
              const int* __restrict__ flag)
{
  const int s = blockIdx.x, n = s/TT, t = s % TT, tid = threadIdx.x;
  const int mode = *flag;
  constexpr int F = VV*COUT_;
  const bf16* yp = ybuf + (size_t)s*F;
  for(int idx=tid; idx<F; idx+=256){
    int d = idx/VV, u = idx - d*VV;
    float v0 = b2f(yp[idx])*A2[d] + B2[d];
    float v = fmaxf(v0, 0.f);
    if(!(v0 == v0) || fabsf(v0) > 1e30f) v = 1000.0f;   // NaN/Inf canary
    size_t o = (((size_t)n*COUT_ + d)*TT + t)*VV + u;
    if(mode) ((float*)out)[o] = v;
    else     ((bf16*)out)[o]  = f2b(v);
  }
}

extern "C" void kernel_launch(void* const* d_in, const int* in_sizes, int n_in,
                              void* d_out, int out_size, void* d_ws, size_t ws_size,
                              hipStream_t stream)
{
  const void* in[39];
  for(int i=0;i<39;i++) in[i] = d_in[i];

  char* ws = (char*)d_ws;
  size_t off = 0;
  auto alloc = [&](size_t bytes)->void*{
    void* p = ws + off;
    off = (off + bytes + 255) & ~(size_t)255;
    return p;
  };
  int*   flag = (int*)  alloc(4);
  float* gmat = (float*)alloc((size_t)NT*VV*VV*4);      // 23.7 MB
  bf16*  zA   = (bf16*) alloc((size_t)NT*2432*2);       // 79.7 MB
  bf16*  zB   = (bf16*) alloc((size_t)NT*2432*2);       // 79.7 MB
  float* dpart= (float*)alloc((size_t)64*256*4);        // 64 KB
  float* s1   = (float*)alloc(2432*4);
  float* s2   = (float*)alloc(2432*4);
  float* A1   = (float*)alloc(2432*4);
  float* B1   = (float*)alloc(2432*4);
  float* A2b1 = (float*)alloc(128*4);
  float* B2b1 = (float*)alloc(128*4);
  float* A2b2 = (float*)alloc(128*4);
  float* B2b2 = (float*)alloc(128*4);
  float* A2b3 = (float*)alloc(128*4);
  float* B2b3 = (float*)alloc(128*4);
  float* A2d  = (float*)alloc(128*4);
  float* B2d  = (float*)alloc(128*4);
  float* fmv1 = (float*)alloc(1216*4);
  float* fmv2 = (float*)alloc(1216*4);
  float* fmv3 = (float*)alloc(2432*4);
  // fp32 weight copies; *T = transposed (wT[c*rows + d]); *P = paired {ww,w1}
  float*  b1_lwf  = (float*)alloc(64*64*4);
  float*  b1_lbf  = (float*)alloc(64*4);
  float2* b1_wP   = (float2*)alloc(64*64*8);
  float*  b1_w1bf = (float*)alloc(64*4);
  float*  b2_lwf  = (float*)alloc(64*128*4);
  float*  b2_lbf  = (float*)alloc(128*4);
  float2* b2_wP   = (float2*)alloc(128*128*8);
  float*  b2_w1bf = (float*)alloc(128*4);
  float*  b2_dwT  = (float*)alloc(128*64*4);
  float*  b2_dbf  = (float*)alloc(128*4);
  float*  b3_lwf  = (float*)alloc(128*128*4);
  float*  b3_lbf  = (float*)alloc(128*4);
  float2* b3_wP   = (float2*)alloc(128*128*8);
  float*  b3_w1bf = (float*)alloc(128*4);
  float*  g1wT    = (float*)alloc(32*64*4);
  float*  g1bf    = (float*)alloc(32*4);
  float*  g2wT    = (float*)alloc(32*64*4);
  float*  g2bf    = (float*)alloc(32*4);

  if(ws_size < off){
    // workspace too small sentinel: fill out with ~12.06 (bf16 0x4141 pattern)
    hipMemsetAsync(d_out, 0x41, (size_t)out_size*2, stream);
    return;
  }

  k_detect<<<1,256,0,stream>>>((const unsigned short*)in[0], flag);
  k_canary<<<(out_size+255)/256,256,0,stream>>>(d_out, out_size, flag);

  auto cvt = [&](const void* src, float* dst, int n){
    k_cvt<<<(n+255)/256,256,0,stream>>>(src, dst, n, flag);
  };
  auto cvtT = [&](const void* src, float* dst, int rows, int cols){
    k_cvtT<<<(rows*cols+255)/256,256,0,stream>>>(src, dst, rows, cols, flag);
  };
  auto cvtP = [&](const void* srcA, const void* srcB, float2* dst, int rows, int cols){
    k_cvtP<<<(rows*cols+255)/256,256,0,stream>>>(srcA, srcB, dst, rows, cols, flag);
  };
  cvt (in[5],  b1_lwf,  64*64);      cvt(in[6],  b1_lbf,  64);
  cvtP(in[12], in[13], b1_wP, 64, 64);                            cvt(in[14], b1_w1bf, 64);
  cvt (in[15], b2_lwf,  64*128);     cvt(in[16], b2_lbf,  128);
  cvtP(in[22], in[23], b2_wP, 128, 128);                          cvt(in[24], b2_w1bf, 128);
  cvtT(in[25], b2_dwT,  128, 64);    cvt(in[26], b2_dbf,  128);
  cvt (in[29], b3_lwf,  128*128);    cvt(in[30], b3_lbf,  128);
  cvtP(in[36], in[37], b3_wP, 128, 128);                          cvt(in[38], b3_w1bf, 128);
  cvtT(in[1],  g1wT,    32, 64);     cvt(in[2],  g1bf,    32);
  cvtT(in[3],  g2wT,    32, 64);     cvt(in[4],  g2bf,    32);

  k_tanhp1<<<5,256,0,stream>>>(in[7],  fmv1, 1216, flag);
  k_tanhp1<<<5,256,0,stream>>>(in[17], fmv2, 1216, flag);
  k_tanhp1<<<10,256,0,stream>>>(in[31], fmv3, 2432, flag);
  k_gspa<<<NT,256,0,stream>>>(in[0], g1wT, g1bf, g2wT, g2bf, gmat, flag);

  // ---- Block 1 (64 -> 64, identity residual), input = x0, ypre/y in zA ----
  k_stage1<64,64,false,false><<<NT,256,0,stream>>>(in[0], nullptr, nullptr, fmv1,
                                                   b1_lwf, b1_lbf, zA,
                                                   nullptr, nullptr, nullptr, flag);
  k_zero<<<19,256,0,stream>>>(s1, 2*2432);   // s1,s2 contiguous
  k_colstats<<<dim3(5,64),256,0,stream>>>(zA, 1216, s1, s2);
  k_fin1<64><<<5,256,0,stream>>>(s1, s2, in[8], in[9], A1, B1, flag);
  k_stage2<64,64,false,false><<<NT,256,0,stream>>>(in[0], nullptr, nullptr, zA, A1, B1,
                                                   gmat, b1_wP, b1_w1bf,
                                                   nullptr, nullptr, nullptr, nullptr, flag);
  k_zero<<<19,256,0,stream>>>(s1, 2*2432);
  k_colstats<<<dim3(5,64),256,0,stream>>>(zA, 1216, s1, s2);
  k_fin2<64><<<1,64,0,stream>>>(s1, s2, in[10], in[11], A2b1, B2b1, flag);

  // ---- Block 2 (64 -> 128, down path), input = BN2d(zA)+relu, ypre/y in zB ----
  k_zero<<<64,256,0,stream>>>(dpart, 64*256);
  k_stage1<64,128,true,true><<<NT,256,0,stream>>>(zA, A2b1, B2b1, fmv2,
                                                  b2_lwf, b2_lbf, zB,
                                                  b2_dwT, b2_dbf, dpart, flag);
  k_dfin<<<1,256,0,stream>>>(dpart, in[27], in[28], A2d, B2d, flag);
  k_zero<<<19,256,0,stream>>>(s1, 2*2432);
  k_colstats<<<dim3(10,64),256,0,stream>>>(zB, 2432, s1, s2);
  k_fin1<128><<<10,256,0,stream>>>(s1, s2, in[18], in[19], A1, B1, flag);
  k_stage2<64,128,true,true><<<NT,256,0,stream>>>(zA, A2b1, B2b1, zB, A1, B1,
                                                  gmat, b2_wP, b2_w1bf,
                                                  b2_dwT, b2_dbf, A2d, B2d, flag);
  k_zero<<<19,256,0,stream>>>(s1, 2*2432);
  k_colstats<<<dim3(10,64),256,0,stream>>>(zB, 2432, s1, s2);
  k_fin2<128><<<1,128,0,stream>>>(s1, s2, in[20], in[21], A2b2, B2b2, flag);

  // ---- Block 3 (128 -> 128, identity), input = BN2d(zB)+relu, ypre/y in zA ----
  k_stage1<128,128,false,true><<<NT,256,0,stream>>>(zB, A2b2, B2b2, fmv3,
                                                    b3_lwf, b3_lbf, zA,
                                                    nullptr, nullptr, nullptr, flag);
  k_zero<<<19,256,0,stream>>>(s1, 2*2432);
  k_colstats<<<dim3(10,64),256,0,stream>>>(zA, 2432, s1, s2);
  k_fin1<128><<<10,256,0,stream>>>(s1, s2, in[32], in[33], A1, B1, flag);
  k_stage2<128,128,false,true><<<NT,256,0,stream>>>(zB, A2b2, B2b2, zA, A1, B1,
                                                    gmat, b3_wP, b3_w1bf,
                                                    nullptr, nullptr, nullptr, nullptr, flag);
  k_zero<<<19,256,0,stream>>>(s1, 2*2432);
  k_colstats<<<dim3(10,64),256,0,stream>>>(zA, 2432, s1, s2);
  k_fin2<128><<<1,128,0,stream>>>(s1, s2, in[34], in[35], A2b3, B2b3, flag);
  k_stage3<128><<<NT,256,0,stream>>>(zA, A2b3, B2b3, d_out, flag);
}

// Round 6
// 1967.348 us; speedup vs baseline: 8.0281x; 1.2116x over previous
//
#include <hip/hip_runtime.h>
#include <hip/hip_bf16.h>

typedef __hip_bfloat16 bf16;
typedef __bf16 bf16x8 __attribute__((ext_vector_type(8)));
typedef float  f32x4  __attribute__((ext_vector_type(4)));

#define NBATCH 128
#define TT 128
#define VV 19
#define NT (NBATCH*TT)
#define EPSF 1e-5f

static __device__ __forceinline__ float b2f(bf16 v){ return __bfloat162float(v); }
static __device__ __forceinline__ bf16  f2b(float v){ return __float2bfloat16(v); }
static __device__ __forceinline__ unsigned short f2u(float v){
  bf16 b = f2b(v); return *reinterpret_cast<unsigned short*>(&b);
}
// dual-dtype input load: mode=1 -> fp32, mode=0 -> bf16
static __device__ __forceinline__ float ldi(const void* p, size_t i, int mode){
  return mode ? ((const float*)p)[i] : b2f(((const bf16*)p)[i]);
}

// acc[0..18] += w * row[0..18]; row is 16B-aligned, 20 floats long (pad)
static __device__ __forceinline__ void fma19(float* acc, float w, const float* row){
  const float4* r = (const float4*)row;
  float4 a=r[0], b=r[1], c=r[2], d=r[3], e=r[4];
  acc[0]+=w*a.x;  acc[1]+=w*a.y;  acc[2]+=w*a.z;  acc[3]+=w*a.w;
  acc[4]+=w*b.x;  acc[5]+=w*b.y;  acc[6]+=w*b.z;  acc[7]+=w*b.w;
  acc[8]+=w*c.x;  acc[9]+=w*c.y;  acc[10]+=w*c.z; acc[11]+=w*c.w;
  acc[12]+=w*d.x; acc[13]+=w*d.y; acc[14]+=w*d.z; acc[15]+=w*d.w;
  acc[16]+=w*e.x; acc[17]+=w*e.y; acc[18]+=w*e.z;
}

// ---- detect input dtype: fp32 buffers read as bf16 have wild exponents ----
__global__ void k_detect(const unsigned short* __restrict__ p, int* __restrict__ flag){
  const int tid = threadIdx.x;
  __shared__ int cnt;
  if(tid==0) cnt = 0;
  __syncthreads();
  int local = 0;
  for(int i=tid; i<2048; i+=256){
    unsigned short h = p[i];
    int e = (h>>7) & 0xFF;
    if(h != 0 && (e < 107 || e > 147)) local++;
  }
  atomicAdd(&cnt, local);
  __syncthreads();
  if(tid==0) *flag = (cnt > 300) ? 1 : 0;
}

// ---- canary: pre-fill output with 3.0 ----
__global__ void k_canary(void* __restrict__ out, int n, const int* __restrict__ flag){
  int i = blockIdx.x*256 + threadIdx.x;
  if(i >= n) return;
  if(*flag) ((float*)out)[i] = 3.0f;
  else      ((bf16*)out)[i]  = f2b(3.0f);
}

__global__ void k_zero(float* __restrict__ p, int n){
  int i = blockIdx.x*256 + threadIdx.x;
  if(i < n) p[i] = 0.f;
}

// ---- convert a weight buffer to fp32 workspace copy ----
__global__ void k_cvt(const void* __restrict__ src, float* __restrict__ dst, int n,
                      const int* __restrict__ flag){
  int i = blockIdx.x*256 + threadIdx.x;
  if(i < n) dst[i] = ldi(src, i, *flag);
}

// ---- transposed fp32 copy: dst[c*rows + r] = src[r*cols + c] ----
__global__ void k_cvtT(const void* __restrict__ src, float* __restrict__ dst,
                       int rows, int cols, const int* __restrict__ flag){
  int i = blockIdx.x*256 + threadIdx.x;
  if(i < rows*cols){
    int r = i / cols, c = i - r*cols;
    dst[c*rows + r] = ldi(src, i, *flag);
  }
}

// ---- pack W[d][c] (ND x KD row-major) into MFMA B-fragment layout, bf16 ----
// B[k=c][n=d]; lane l: n = l&15, k = (l>>4)*8 + j.
// dst[((nt*KT + kt)*64 + l)*8 + j] = W[nt*16 + (l&15)][kt*32 + ((l>>4)<<3) + j]
__global__ void k_packB(const void* __restrict__ src, unsigned short* __restrict__ dst,
                        int ND, int KD, const int* __restrict__ flag){
  int o = blockIdx.x*256 + threadIdx.x;
  if(o >= ND*KD) return;
  int mode = *flag;
  int KT = KD >> 5;
  int j = o & 7, l = (o >> 3) & 63;
  int q = o >> 9;
  int kt = q % KT, nt = q / KT;
  int d = nt*16 + (l & 15);
  int c = kt*32 + ((l >> 4) << 3) + j;
  dst[o] = f2u(ldi(src, (size_t)d*KD + c, mode));
}

// ---- fmv = tanh(fm)+1 ----
__global__ void k_tanhp1(const void* __restrict__ fm, float* __restrict__ out, int n,
                         const int* __restrict__ flag){
  int i = blockIdx.x*256 + threadIdx.x;
  int mode = *flag;
  if(i < n) out[i] = tanhf(ldi(fm, i, mode)) + 1.0f;
}

// ---- g = softmax( A @ B ) per (n,t); weights pre-transposed fp32 ----
__global__ __launch_bounds__(256)
void k_gspa(const void* __restrict__ x0,
            const float* __restrict__ w1T, const float* __restrict__ b1f,
            const float* __restrict__ w2T, const float* __restrict__ b2f,
            float* __restrict__ gout, const int* __restrict__ flag)
{
  const int s = blockIdx.x;
  const int n = s / TT, t = s % TT;
  const int tid = threadIdx.x;
  const int mode = *flag;
  __shared__ float xt[64][20];
  __shared__ float Am[VV][33];
  __shared__ float Bm[32][21];
  __shared__ float Sm[VV][21];
  for(int idx=tid; idx<64*VV; idx+=256){
    int c = idx/VV, u = idx - c*VV;
    xt[c][u] = ldi(x0, (((size_t)n*64 + c)*TT + t)*VV + u, mode);
  }
  __syncthreads();
  for(int idx=tid; idx<VV*32; idx+=256){
    int u = idx/32, k = idx & 31;
    float acc = b1f[k];
    for(int c=0;c<64;c++) acc += xt[c][u]*w1T[c*32+k];
    Am[u][k] = acc;
  }
  for(int idx=tid; idx<32*VV; idx+=256){
    int k = idx/VV, w = idx - k*VV;
    float acc = b2f[k];
    for(int c=0;c<64;c++) acc += xt[c][w]*w2T[c*32+k];
    Bm[k][w] = acc;
  }
  __syncthreads();
  for(int idx=tid; idx<VV*VV; idx+=256){
    int u = idx/VV, w = idx - u*VV;
    float acc = 0.f;
#pragma unroll
    for(int k=0;k<32;k++) acc += Am[u][k]*Bm[k][w];
    Sm[u][w] = acc;
  }
  __syncthreads();
  if(tid < VV){
    int u = tid;
    float mx = -1e30f;
    for(int w=0;w<VV;w++) mx = fmaxf(mx, Sm[u][w]);
    float sum = 0.f;
    for(int w=0;w<VV;w++){ float e = __expf(Sm[u][w]-mx); Sm[u][w]=e; sum+=e; }
    float r = 1.0f/sum;
    for(int w=0;w<VV;w++) Sm[u][w] *= r;
  }
  __syncthreads();
  float* gp = gout + (size_t)s*(VV*VV);
  for(int idx=tid; idx<VV*VV; idx+=256) gp[idx] = Sm[idx/VV][idx%VV];
}

// ---- Stage 1 (unchanged scalar path) ----
template<int CIN_, int COUT_, bool DOWN, bool PREV>
__global__ __launch_bounds__(256,6)
void k_stage1(const void* __restrict__ xin,
              const float* __restrict__ A2p, const float* __restrict__ B2p,
              const float* __restrict__ fmv,
              const float* __restrict__ lwf, const float* __restrict__ lbf,
              bf16* __restrict__ zbuf,
              const float* __restrict__ dwT, const float* __restrict__ dbf,
              float* __restrict__ dpart, const int* __restrict__ flag)
{
  constexpr int NS = 256/COUT_;
  constexpr int JC = CIN_/NS;
  const int s = blockIdx.x;
  const int n = s / TT, t = s % TT;
  const int tid = threadIdx.x;
  __shared__ __align__(16) float xt[CIN_][20];
  __shared__ __align__(16) float xsT[CIN_][20];
  __shared__ float pbuf[(NS-1)*COUT_*VV];
  __shared__ float ds1[DOWN?256:1], ds2[DOWN?256:1];

  if constexpr (PREV){
    const bf16* zin = (const bf16*)xin + (size_t)s*(CIN_*VV);
    for(int idx=tid; idx<CIN_*VV; idx+=256){
      int c = idx/VV, u = idx - c*VV;
      xt[c][u] = fmaxf(b2f(zin[idx])*A2p[c] + B2p[c], 0.f);
    }
  } else {
    const int mode = *flag;
    for(int idx=tid; idx<CIN_*VV; idx+=256){
      int c = idx/VV, u = idx - c*VV;
      xt[c][u] = ldi(xin, (((size_t)n*CIN_ + c)*TT + t)*VV + u, mode);
    }
  }
  if(tid < CIN_) xt[tid][19] = 0.f;
  __syncthreads();
  for(int idx=tid; idx<CIN_*VV; idx+=256){
    int j = idx/VV, i = idx - j*VV;
    xsT[j][i] = xt[j][(i+j)%VV] * fmv[i*CIN_ + j];
  }
  __syncthreads();

  const int d  = tid % COUT_;
  const int sp = tid / COUT_;
  float acc[VV];
#pragma unroll
  for(int i=0;i<VV;i++) acc[i]=0.f;
  {
    const float* lp = lwf + sp*JC*COUT_ + d;
#pragma unroll 4
    for(int j=0;j<JC;j++){
      fma19(acc, *lp, xsT[sp*JC + j]);
      lp += COUT_;
    }
  }
  if(sp > 0){
#pragma unroll
    for(int i=0;i<VV;i++) pbuf[((sp-1)*COUT_+d)*VV + i] = acc[i];
  }
  __syncthreads();
  if(sp == 0){
    float lbv = lbf[d];
    bf16* zp = zbuf + (size_t)s*(VV*COUT_);
#pragma unroll
    for(int i=0;i<VV;i++){
      float v = acc[i] + lbv;
#pragma unroll
      for(int q=1;q<NS;q++) v += pbuf[((q-1)*COUT_+d)*VV + i];
      zp[i*COUT_ + d] = f2b(v);
    }
  }
  if constexpr (DOWN){
    const int oc  = tid & 127;
    const int grp = tid >> 7;
    float r[10];
    const float dbv = dbf[oc];
#pragma unroll
    for(int k=0;k<10;k++) r[k] = dbv;
#pragma unroll 4
    for(int c=0;c<CIN_;c++){
      float wc = dwT[c*COUT_ + oc];
      const float* xr = xt[c];
#pragma unroll
      for(int k=0;k<10;k++) r[k] += wc * xr[grp + 2*k];
    }
    float a1=0.f, a2=0.f;
#pragma unroll
    for(int k=0;k<10;k++){
      if(grp + 2*k < VV){ a1 += r[k]; a2 += r[k]*r[k]; }
    }
    ds1[tid]=a1; ds2[tid]=a2;
    __syncthreads();
    if(tid < 128){
      float* bucket = dpart + (size_t)(s & 63)*256;
      atomicAdd(&bucket[tid],       ds1[tid] + ds1[tid+128]);
      atomicAdd(&bucket[128 + tid], ds2[tid] + ds2[tid+128]);
    }
  }
}

// ---- column stats of [NT][F] bf16 buffer ----
__global__ __launch_bounds__(256)
void k_colstats(const bf16* __restrict__ zb, int F,
                float* __restrict__ s1, float* __restrict__ s2)
{
  int f = blockIdx.x*256 + threadIdx.x;
  if(f >= F) return;
  const int RPC = NT/64;
  const bf16* p = zb + (size_t)(blockIdx.y*RPC)*F + f;
  float a=0.f, b=0.f;
  for(int r=0; r<RPC; r++){ float v = b2f(p[(size_t)r*F]); a += v; b += v*v; }
  atomicAdd(&s1[f], a);
  atomicAdd(&s2[f], b);
}

// ---- BN1d finalize ----
template<int COUT_>
__global__ void k_fin1(const float* __restrict__ s1, const float* __restrict__ s2,
                       const void* __restrict__ bng, const void* __restrict__ bnb,
                       float* __restrict__ A1, float* __restrict__ B1,
                       const int* __restrict__ flag)
{
  const int F = VV*COUT_;
  int fp = blockIdx.x*256 + threadIdx.x;
  if(fp >= F) return;
  int mode = *flag;
  int ip = fp/COUT_, d = fp - ip*COUT_;
  int f = ((ip + d)%VV)*COUT_ + d;
  float m = s1[fp] * (1.0f/NT);
  float v = s2[fp] * (1.0f/NT) - m*m;
  float a = ldi(bng, f, mode) * rsqrtf(v + EPSF);
  A1[fp] = a;
  B1[fp] = ldi(bnb, f, mode) - m*a;
}

// ---- BN2d finalize ----
template<int COUT_>
__global__ void k_fin2(const float* __restrict__ s1, const float* __restrict__ s2,
                       const void* __restrict__ bnsg, const void* __restrict__ bnsb,
                       float* __restrict__ A2, float* __restrict__ B2,
                       const int* __restrict__ flag)
{
  int d = threadIdx.x;
  if(d >= COUT_) return;
  int mode = *flag;
  float a=0.f, b=0.f;
  for(int u=0;u<VV;u++){ a += s1[d*VV+u]; b += s2[d*VV+u]; }
  const float inv = 1.0f/((float)NT*VV);
  float m = a*inv, v = b*inv - m*m;
  float g_ = ldi(bnsg, d, mode) * rsqrtf(v + EPSF);
  A2[d] = g_;
  B2[d] = ldi(bnsb, d, mode) - m*g_;
}

// ---- reduce 64 buckets -> A2d/B2d ----
__global__ void k_dfin(const float* __restrict__ dpart, const void* __restrict__ dbng,
                       const void* __restrict__ dbnb, float* __restrict__ A2d,
                       float* __restrict__ B2d, const int* __restrict__ flag){
  int c = threadIdx.x;
  int mode = *flag;
  float a = 0.f;
  for(int r=0;r<64;r++) a += dpart[(size_t)r*256 + c];
  __shared__ float red[256];
  red[c] = a;
  __syncthreads();
  if(c < 128){
    const float inv = 1.0f/((float)NT*VV);
    float m = red[c]*inv;
    float v = red[128+c]*inv - m*m;
    float g_ = ldi(dbng, c, mode) * rsqrtf(v + EPSF);
    A2d[c] = g_;
    B2d[c] = ldi(dbnb, c, mode) - m*g_;
  }
}

// ---- Stage 2 (MFMA): BN1d+res+ReLU -> X2T(bf16,LDS,swizzled); convs via
// mfma_f32_16x16x32_bf16 with A = X2T[i][c], B = packed weights; fused graph
// apply on the fp32 accumulators; LDS-staged coalesced bf16 output.
// Fragment layouts: A lane l: m=l&15, k=(l>>4)*8+j. B lane l: n=l&15, k=(l>>4)*8+j.
// D lane l: row=(l>>4)*4+r, col=l&15.  => D[i][d], A m-index = i, B n-index = d.
template<int CIN_, int COUT_, bool DOWN, bool PREV>
__global__ __launch_bounds__(256,3)
void k_stage2(const void* __restrict__ xin,
              const float* __restrict__ A2p, const float* __restrict__ B2p,
              bf16* __restrict__ zy,
              const float* __restrict__ A1, const float* __restrict__ B1,
              const float* __restrict__ gmat,
              const unsigned short* __restrict__ wpk,
              const unsigned short* __restrict__ w1pk,
              const float* __restrict__ w1bf,
              const unsigned short* __restrict__ dwpk,
              const float* __restrict__ dbf,
              const float* __restrict__ A2d, const float* __restrict__ B2d,
              const int* __restrict__ flag)
{
  constexpr int F  = VV*COUT_;
  constexpr int KT = COUT_/32;        // K-steps (K = channel count of X2)
  constexpr int NL = COUT_/64;        // d-tiles per wave (128->2, 64->1)
  constexpr int RP = COUT_ + 4;       // scr row pitch (bank-conflict-free)
  const int s = blockIdx.x;
  const int n = s/TT, t = s % TT;
  const int tid = threadIdx.x;
  const int lane = tid & 63, wid = tid >> 6;

  __shared__ __align__(16) unsigned short x2t[32*COUT_];     // bf16, swizzled
  __shared__ __align__(16) float scrA[VV*RP];                // Dres then Yw
  __shared__ __align__(16) float scrB[VV*RP];                // Y1
  __shared__ unsigned short zst[F];
  __shared__ float gt[VV][21];
  __shared__ __align__(16) unsigned short xtt[DOWN ? 32*64 : 16]; // bf16 XT^T
  __shared__ __align__(16) float XT[DOWN ? 1 : CIN_][20];

  for(int idx=tid; idx<VV*VV; idx+=256)
    gt[idx/VV][idx%VV] = gmat[(size_t)s*(VV*VV) + idx];

  if constexpr (DOWN){
    const bf16* zin = (const bf16*)xin + (size_t)s*(CIN_*VV);
    for(int idx=tid; idx<CIN_*VV; idx+=256){
      int c = idx/VV, u = idx - c*VV;
      float v = fmaxf(b2f(zin[idx])*A2p[c] + B2p[c], 0.f);
      int bo = ((u*64 + c)*2) ^ ((u&7)<<4);
      *(unsigned short*)((char*)xtt + bo) = f2u(v);
    }
  } else if constexpr (PREV){
    const bf16* zin = (const bf16*)xin + (size_t)s*(CIN_*VV);
    for(int idx=tid; idx<CIN_*VV; idx+=256){
      int c = idx/VV, u = idx - c*VV;
      XT[c][u] = fmaxf(b2f(zin[idx])*A2p[c] + B2p[c], 0.f);
    }
  } else {
    const int mode = *flag;
    for(int idx=tid; idx<CIN_*VV; idx+=256){
      int c = idx/VV, u = idx - c*VV;
      XT[c][u] = ldi(xin, (((size_t)n*CIN_ + c)*TT + t)*VV + u, mode);
    }
  }
  __syncthreads();

  if constexpr (DOWN){
    // down-conv via MFMA: Dres[u][d] = sum_c dw[d][c]*XT[c][u]; K=64, N=128, M=u
    f32x4 z4 = {0.f,0.f,0.f,0.f};
    f32x4 dacc[2][2] = {{z4,z4},{z4,z4}};
    const bf16x8* dwp = reinterpret_cast<const bf16x8*>(dwpk);
#pragma unroll
    for(int kt=0; kt<2; ++kt){
      bf16x8 af[2];
#pragma unroll
      for(int mt=0; mt<2; ++mt){
        int u = mt*16 + (lane&15);
        int bo = ((u*64 + kt*32 + ((lane>>4)<<3))*2) ^ ((u&7)<<4);
        af[mt] = *reinterpret_cast<const bf16x8*>((const char*)xtt + bo);
      }
#pragma unroll
      for(int nl=0; nl<2; ++nl){
        bf16x8 bd = dwp[((wid*2+nl)*2 + kt)*64 + lane];
#pragma unroll
        for(int mt=0; mt<2; ++mt)
          dacc[mt][nl] = __builtin_amdgcn_mfma_f32_16x16x32_bf16(af[mt], bd, dacc[mt][nl], 0,0,0);
      }
    }
#pragma unroll
    for(int mt=0; mt<2; ++mt)
#pragma unroll
    for(int nl=0; nl<2; ++nl)
#pragma unroll
    for(int r=0; r<4; ++r){
      int u = mt*16 + ((lane>>4)<<2) + r;
      if(u < VV){
        int d = (wid*2+nl)*16 + (lane&15);
        scrA[u*RP + d] = dacc[mt][nl][r];
      }
    }
    __syncthreads();
  }

  // ---- staging: BN1d + residual + ReLU -> X2T bf16 (swizzled) ----
  bf16* zp = zy + (size_t)s*F;
  for(int idx=tid; idx<F; idx+=256){
    int ip = idx/COUT_, d = idx - ip*COUT_;
    int u = (ip + d) % VV;
    float res;
    if constexpr (DOWN) res = (scrA[u*RP + d] + dbf[d])*A2d[d] + B2d[d];
    else                res = XT[d][u];
    float v = fmaxf(b2f(zp[idx])*A1[idx] + B1[idx] + res, 0.f);
    int bo = ((u*COUT_ + d)*2) ^ ((u&7)<<4);
    *(unsigned short*)((char*)x2t + bo) = f2u(v);
  }
  __syncthreads();

  // ---- main convs via MFMA: Yw/Y1[i][d] ----
  {
    f32x4 z4 = {0.f,0.f,0.f,0.f};
    f32x4 accw[2][NL], acc1[2][NL];
#pragma unroll
    for(int mt=0; mt<2; ++mt)
#pragma unroll
    for(int nl=0; nl<NL; ++nl){ accw[mt][nl] = z4; acc1[mt][nl] = z4; }
    const bf16x8* wp  = reinterpret_cast<const bf16x8*>(wpk);
    const bf16x8* w1p = reinterpret_cast<const bf16x8*>(w1pk);
#pragma unroll
    for(int kt=0; kt<KT; ++kt){
      bf16x8 af[2];
#pragma unroll
      for(int mt=0; mt<2; ++mt){
        int i = mt*16 + (lane&15);
        int bo = ((i*COUT_ + kt*32 + ((lane>>4)<<3))*2) ^ ((i&7)<<4);
        af[mt] = *reinterpret_cast<const bf16x8*>((const char*)x2t + bo);
      }
#pragma unroll
      for(int nl=0; nl<NL; ++nl){
        int ntg = wid*NL + nl;
        bf16x8 bw = wp [(ntg*KT + kt)*64 + lane];
        bf16x8 b1 = w1p[(ntg*KT + kt)*64 + lane];
#pragma unroll
        for(int mt=0; mt<2; ++mt){
          accw[mt][nl] = __builtin_amdgcn_mfma_f32_16x16x32_bf16(af[mt], bw, accw[mt][nl], 0,0,0);
          acc1[mt][nl] = __builtin_amdgcn_mfma_f32_16x16x32_bf16(af[mt], b1, acc1[mt][nl], 0,0,0);
        }
      }
    }
#pragma unroll
    for(int mt=0; mt<2; ++mt)
#pragma unroll
    for(int nl=0; nl<NL; ++nl)
#pragma unroll
    for(int r=0; r<4; ++r){
      int i = mt*16 + ((lane>>4)<<2) + r;
      if(i < VV){
        int d = (wid*NL+nl)*16 + (lane&15);
        scrA[i*RP + d] = accw[mt][nl][r];
        scrB[i*RP + d] = acc1[mt][nl][r];
      }
    }
  }
  __syncthreads();

  // ---- graph apply + bias -> zst (LDS) ----
  {
    constexpr int NSF = 256/COUT_;
    constexpr int IB  = (VV + NSF - 1)/NSF;
    const int d = tid % COUT_;
    const int h = tid / COUT_;
    float rw[VV];
#pragma unroll
    for(int w=0; w<VV; ++w) rw[w] = scrA[w*RP + d];
    const float bias = w1bf[d];
    const int i0 = h*IB, i1 = (i0+IB < VV) ? i0+IB : VV;
    for(int i=i0; i<i1; ++i){
      float o = scrB[i*RP + d] + bias;
#pragma unroll
      for(int w=0; w<VV; ++w) o += gt[i][w]*rw[w];
      zst[d*VV + i] = f2u(o);
    }
  }
  __syncthreads();
  // ---- coalesced bf16 write-back ----
  for(int idx=tid; idx<F; idx+=256)
    ((unsigned short*)zp)[idx] = zst[idx];
}

// ---- Stage 3: BN2d + ReLU -> output; NaN canary ----
template<int COUT_>
__global__ __launch_bounds__(256)
void k_stage3(const bf16* __restrict__ ybuf, const float* __restrict__ A2,
              const float* __restrict__ B2, void* __restrict__ out,
              const int* __restrict__ flag)
{
  const int s = blockIdx.x, n = s/TT, t = s % TT, tid = threadIdx.x;
  const int mode = *flag;
  constexpr int F = VV*COUT_;
  const bf16* yp = ybuf + (size_t)s*F;
  for(int idx=tid; idx<F; idx+=256){
    int d = idx/VV, u = idx - d*VV;
    float v0 = b2f(yp[idx])*A2[d] + B2[d];
    float v = fmaxf(v0, 0.f);
    if(!(v0 == v0) || fabsf(v0) > 1e30f) v = 1000.0f;
    size_t o = (((size_t)n*COUT_ + d)*TT + t)*VV + u;
    if(mode) ((float*)out)[o] = v;
    else     ((bf16*)out)[o]  = f2b(v);
  }
}

extern "C" void kernel_launch(void* const* d_in, const int* in_sizes, int n_in,
                              void* d_out, int out_size, void* d_ws, size_t ws_size,
                              hipStream_t stream)
{
  const void* in[39];
  for(int i=0;i<39;i++) in[i] = d_in[i];

  char* ws = (char*)d_ws;
  size_t off = 0;
  auto alloc = [&](size_t bytes)->void*{
    void* p = ws + off;
    off = (off + bytes + 255) & ~(size_t)255;
    return p;
  };
  int*   flag = (int*)  alloc(4);
  float* gmat = (float*)alloc((size_t)NT*VV*VV*4);
  bf16*  zA   = (bf16*) alloc((size_t)NT*2432*2);
  bf16*  zB   = (bf16*) alloc((size_t)NT*2432*2);
  float* dpart= (float*)alloc((size_t)64*256*4);
  float* s1   = (float*)alloc(2432*4);
  float* s2   = (float*)alloc(2432*4);
  float* A1   = (float*)alloc(2432*4);
  float* B1   = (float*)alloc(2432*4);
  float* A2b1 = (float*)alloc(128*4);
  float* B2b1 = (float*)alloc(128*4);
  float* A2b2 = (float*)alloc(128*4);
  float* B2b2 = (float*)alloc(128*4);
  float* A2b3 = (float*)alloc(128*4);
  float* B2b3 = (float*)alloc(128*4);
  float* A2d  = (float*)alloc(128*4);
  float* B2d  = (float*)alloc(128*4);
  float* fmv1 = (float*)alloc(1216*4);
  float* fmv2 = (float*)alloc(1216*4);
  float* fmv3 = (float*)alloc(2432*4);
  // stage1 fp32 weights
  float*  b1_lwf  = (float*)alloc(64*64*4);
  float*  b1_lbf  = (float*)alloc(64*4);
  float*  b2_lwf  = (float*)alloc(64*128*4);
  float*  b2_lbf  = (float*)alloc(128*4);
  float*  b2_dwT  = (float*)alloc(128*64*4);
  float*  b2_dbf  = (float*)alloc(128*4);
  float*  b3_lwf  = (float*)alloc(128*128*4);
  float*  b3_lbf  = (float*)alloc(128*4);
  // stage2 MFMA packed bf16 weights + biases
  unsigned short* b1_wwP = (unsigned short*)alloc(64*64*2);
  unsigned short* b1_w1P = (unsigned short*)alloc(64*64*2);
  float*  b1_w1bf = (float*)alloc(64*4);
  unsigned short* b2_wwP = (unsigned short*)alloc(128*128*2);
  unsigned short* b2_w1P = (unsigned short*)alloc(128*128*2);
  float*  b2_w1bf = (float*)alloc(128*4);
  unsigned short* b2_dwP = (unsigned short*)alloc(128*64*2);
  unsigned short* b3_wwP = (unsigned short*)alloc(128*128*2);
  unsigned short* b3_w1P = (unsigned short*)alloc(128*128*2);
  float*  b3_w1bf = (float*)alloc(128*4);
  float*  g1wT    = (float*)alloc(32*64*4);
  float*  g1bf    = (float*)alloc(32*4);
  float*  g2wT    = (float*)alloc(32*64*4);
  float*  g2bf    = (float*)alloc(32*4);

  if(ws_size < off){
    hipMemsetAsync(d_out, 0x41, (size_t)out_size*2, stream);
    return;
  }

  k_detect<<<1,256,0,stream>>>((const unsigned short*)in[0], flag);
  k_canary<<<(out_size+255)/256,256,0,stream>>>(d_out, out_size, flag);

  auto cvt = [&](const void* src, float* dst, int n){
    k_cvt<<<(n+255)/256,256,0,stream>>>(src, dst, n, flag);
  };
  auto cvtT = [&](const void* src, float* dst, int rows, int cols){
    k_cvtT<<<(rows*cols+255)/256,256,0,stream>>>(src, dst, rows, cols, flag);
  };
  auto packB = [&](const void* src, unsigned short* dst, int ND, int KD){
    k_packB<<<(ND*KD+255)/256,256,0,stream>>>(src, dst, ND, KD, flag);
  };
  cvt (in[5],  b1_lwf,  64*64);      cvt(in[6],  b1_lbf,  64);
  packB(in[12], b1_wwP, 64, 64);     packB(in[13], b1_w1P, 64, 64);
  cvt (in[14], b1_w1bf, 64);
  cvt (in[15], b2_lwf,  64*128);     cvt(in[16], b2_lbf,  128);
  packB(in[22], b2_wwP, 128, 128);   packB(in[23], b2_w1P, 128, 128);
  cvt (in[24], b2_w1bf, 128);
  cvtT(in[25], b2_dwT,  128, 64);    packB(in[25], b2_dwP, 128, 64);
  cvt (in[26], b2_dbf,  128);
  cvt (in[29], b3_lwf,  128*128);    cvt(in[30], b3_lbf,  128);
  packB(in[36], b3_wwP, 128, 128);   packB(in[37], b3_w1P, 128, 128);
  cvt (in[38], b3_w1bf, 128);
  cvtT(in[1],  g1wT,    32, 64);     cvt(in[2],  g1bf,    32);
  cvtT(in[3],  g2wT,    32, 64);     cvt(in[4],  g2bf,    32);

  k_tanhp1<<<5,256,0,stream>>>(in[7],  fmv1, 1216, flag);
  k_tanhp1<<<5,256,0,stream>>>(in[17], fmv2, 1216, flag);
  k_tanhp1<<<10,256,0,stream>>>(in[31], fmv3, 2432, flag);
  k_gspa<<<NT,256,0,stream>>>(in[0], g1wT, g1bf, g2wT, g2bf, gmat, flag);

  // ---- Block 1 (64 -> 64, identity residual) ----
  k_stage1<64,64,false,false><<<NT,256,0,stream>>>(in[0], nullptr, nullptr, fmv1,
                                                   b1_lwf, b1_lbf, zA,
                                                   nullptr, nullptr, nullptr, flag);
  k_zero<<<19,256,0,stream>>>(s1, 2*2432);
  k_colstats<<<dim3(5,64),256,0,stream>>>(zA, 1216, s1, s2);
  k_fin1<64><<<5,256,0,stream>>>(s1, s2, in[8], in[9], A1, B1, flag);
  k_stage2<64,64,false,false><<<NT,256,0,stream>>>(in[0], nullptr, nullptr, zA, A1, B1,
                                                   gmat, b1_wwP, b1_w1P, b1_w1bf,
                                                   nullptr, nullptr, nullptr, nullptr, flag);
  k_zero<<<19,256,0,stream>>>(s1, 2*2432);
  k_colstats<<<dim3(5,64),256,0,stream>>>(zA, 1216, s1, s2);
  k_fin2<64><<<1,64,0,stream>>>(s1, s2, in[10], in[11], A2b1, B2b1, flag);

  // ---- Block 2 (64 -> 128, down path) ----
  k_zero<<<64,256,0,stream>>>(dpart, 64*256);
  k_stage1<64,128,true,true><<<NT,256,0,stream>>>(zA, A2b1, B2b1, fmv2,
                                                  b2_lwf, b2_lbf, zB,
                                                  b2_dwT, b2_dbf, dpart, flag);
  k_dfin<<<1,256,0,stream>>>(dpart, in[27], in[28], A2d, B2d, flag);
  k_zero<<<19,256,0,stream>>>(s1, 2*2432);
  k_colstats<<<dim3(10,64),256,0,stream>>>(zB, 2432, s1, s2);
  k_fin1<128><<<10,256,0,stream>>>(s1, s2, in[18], in[19], A1, B1, flag);
  k_stage2<64,128,true,true><<<NT,256,0,stream>>>(zA, A2b1, B2b1, zB, A1, B1,
                                                  gmat, b2_wwP, b2_w1P, b2_w1bf,
                                                  b2_dwP, b2_dbf, A2d, B2d, flag);
  k_zero<<<19,256,0,stream>>>(s1, 2*2432);
  k_colstats<<<dim3(10,64),256,0,stream>>>(zB, 2432, s1, s2);
  k_fin2<128><<<1,128,0,stream>>>(s1, s2, in[20], in[21], A2b2, B2b2, flag);

  // ---- Block 3 (128 -> 128, identity) ----
  k_stage1<128,128,false,true><<<NT,256,0,stream>>>(zB, A2b2, B2b2, fmv3,
                                                    b3_lwf, b3_lbf, zA,
                                                    nullptr, nullptr, nullptr, flag);
  k_zero<<<19,256,0,stream>>>(s1, 2*2432);
  k_colstats<<<dim3(10,64),256,0,stream>>>(zA, 2432, s1, s2);
  k_fin1<128><<<10,256,0,stream>>>(s1, s2, in[32], in[33], A1, B1, flag);
  k_stage2<128,128,false,true><<<NT,256,0,stream>>>(zB, A2b2, B2b2, zA, A1, B1,
                                                    gmat, b3_wwP, b3_w1P, b3_w1bf,
                                                    nullptr, nullptr, nullptr, nullptr, flag);
  k_zero<<<19,256,0,stream>>>(s1, 2*2432);
  k_colstats<<<dim3(10,64),256,0,stream>>>(zA, 2432, s1, s2);
  k_fin2<128><<<1,128,0,stream>>>(s1, s2, in[34], in[35], A2b3, B2b3, flag);
  k_stage3<128><<<NT,256,0,stream>>>(zA, A2b3, B2b3, d_out, flag);
}

// Round 7
// 1573.420 us; speedup vs baseline: 10.0381x; 1.2504x over previous
//
#include <hip/hip_runtime.h>
#include <hip/hip_bf16.h>

typedef __hip_bfloat16 bf16;
typedef __bf16 bf16x8 __attribute__((ext_vector_type(8)));
typedef float  f32x4  __attribute__((ext_vector_type(4)));

#define NBATCH 128
#define TT 128
#define VV 19
#define NT (NBATCH*TT)
#define EPSF 1e-5f

static __device__ __forceinline__ float b2f(bf16 v){ return __bfloat162float(v); }
static __device__ __forceinline__ bf16  f2b(float v){ return __float2bfloat16(v); }
static __device__ __forceinline__ unsigned short f2u(float v){
  bf16 b = f2b(v); return *reinterpret_cast<unsigned short*>(&b);
}
// dual-dtype input load: mode=1 -> fp32, mode=0 -> bf16
static __device__ __forceinline__ float ldi(const void* p, size_t i, int mode){
  return mode ? ((const float*)p)[i] : b2f(((const bf16*)p)[i]);
}

// ---- detect input dtype: fp32 buffers read as bf16 have wild exponents ----
__global__ void k_detect(const unsigned short* __restrict__ p, int* __restrict__ flag){
  const int tid = threadIdx.x;
  __shared__ int cnt;
  if(tid==0) cnt = 0;
  __syncthreads();
  int local = 0;
  for(int i=tid; i<2048; i+=256){
    unsigned short h = p[i];
    int e = (h>>7) & 0xFF;
    if(h != 0 && (e < 107 || e > 147)) local++;
  }
  atomicAdd(&cnt, local);
  __syncthreads();
  if(tid==0) *flag = (cnt > 300) ? 1 : 0;
}

// ---- canary: pre-fill output with 3.0 ----
__global__ void k_canary(void* __restrict__ out, int n, const int* __restrict__ flag){
  int i = blockIdx.x*256 + threadIdx.x;
  if(i >= n) return;
  if(*flag) ((float*)out)[i] = 3.0f;
  else      ((bf16*)out)[i]  = f2b(3.0f);
}

__global__ void k_zero(float* __restrict__ p, int n){
  int i = blockIdx.x*256 + threadIdx.x;
  if(i < n) p[i] = 0.f;
}

// ---- convert a weight buffer to fp32 workspace copy ----
__global__ void k_cvt(const void* __restrict__ src, float* __restrict__ dst, int n,
                      const int* __restrict__ flag){
  int i = blockIdx.x*256 + threadIdx.x;
  if(i < n) dst[i] = ldi(src, i, *flag);
}

// ---- transposed fp32 copy: dst[c*rows + r] = src[r*cols + c] ----
__global__ void k_cvtT(const void* __restrict__ src, float* __restrict__ dst,
                       int rows, int cols, const int* __restrict__ flag){
  int i = blockIdx.x*256 + threadIdx.x;
  if(i < rows*cols){
    int r = i / cols, c = i - r*cols;
    dst[c*rows + r] = ldi(src, i, *flag);
  }
}

// ---- pack weight into MFMA B-fragment layout, bf16 ----
// B[k][n]; lane l: n = l&15, k = (l>>4)*8 + j.
// trans=0: src is W[n][k] row-major (ND x KD). trans=1: src is W[k][n] (KD x ND).
__global__ void k_packB(const void* __restrict__ src, unsigned short* __restrict__ dst,
                        int ND, int KD, int trans, const int* __restrict__ flag){
  int o = blockIdx.x*256 + threadIdx.x;
  if(o >= ND*KD) return;
  int mode = *flag;
  int KT = KD >> 5;
  int j = o & 7, l = (o >> 3) & 63;
  int q = o >> 9;
  int kt = q % KT, nt = q / KT;
  int d = nt*16 + (l & 15);
  int c = kt*32 + ((l >> 4) << 3) + j;
  size_t si = trans ? ((size_t)c*ND + d) : ((size_t)d*KD + c);
  dst[o] = f2u(ldi(src, si, mode));
}

// ---- fmv = tanh(fm)+1 ----
__global__ void k_tanhp1(const void* __restrict__ fm, float* __restrict__ out, int n,
                         const int* __restrict__ flag){
  int i = blockIdx.x*256 + threadIdx.x;
  int mode = *flag;
  if(i < n) out[i] = tanhf(ldi(fm, i, mode)) + 1.0f;
}

// ---- g = softmax( A @ B ) per (n,t); weights pre-transposed fp32 ----
__global__ __launch_bounds__(256)
void k_gspa(const void* __restrict__ x0,
            const float* __restrict__ w1T, const float* __restrict__ b1f,
            const float* __restrict__ w2T, const float* __restrict__ b2f,
            float* __restrict__ gout, const int* __restrict__ flag)
{
  const int s = blockIdx.x;
  const int n = s / TT, t = s % TT;
  const int tid = threadIdx.x;
  const int mode = *flag;
  __shared__ float xt[64][20];
  __shared__ float Am[VV][33];
  __shared__ float Bm[32][21];
  __shared__ float Sm[VV][21];
  for(int idx=tid; idx<64*VV; idx+=256){
    int c = idx/VV, u = idx - c*VV;
    xt[c][u] = ldi(x0, (((size_t)n*64 + c)*TT + t)*VV + u, mode);
  }
  __syncthreads();
  for(int idx=tid; idx<VV*32; idx+=256){
    int u = idx/32, k = idx & 31;
    float acc = b1f[k];
    for(int c=0;c<64;c++) acc += xt[c][u]*w1T[c*32+k];
    Am[u][k] = acc;
  }
  for(int idx=tid; idx<32*VV; idx+=256){
    int k = idx/VV, w = idx - k*VV;
    float acc = b2f[k];
    for(int c=0;c<64;c++) acc += xt[c][w]*w2T[c*32+k];
    Bm[k][w] = acc;
  }
  __syncthreads();
  for(int idx=tid; idx<VV*VV; idx+=256){
    int u = idx/VV, w = idx - u*VV;
    float acc = 0.f;
#pragma unroll
    for(int k=0;k<32;k++) acc += Am[u][k]*Bm[k][w];
    Sm[u][w] = acc;
  }
  __syncthreads();
  if(tid < VV){
    int u = tid;
    float mx = -1e30f;
    for(int w=0;w<VV;w++) mx = fmaxf(mx, Sm[u][w]);
    float sum = 0.f;
    for(int w=0;w<VV;w++){ float e = __expf(Sm[u][w]-mx); Sm[u][w]=e; sum+=e; }
    float r = 1.0f/sum;
    for(int w=0;w<VV;w++) Sm[u][w] *= r;
  }
  __syncthreads();
  float* gp = gout + (size_t)s*(VV*VV);
  for(int idx=tid; idx<VV*VV; idx+=256) gp[idx] = Sm[idx/VV][idx%VV];
}

// ---- Stage 1 (MFMA): xs staged as bf16 A-layout [i][j] (swizzled); ypre via
// mfma_f32_16x16x32_bf16 over full K per wave (no partial combine); DOWN stats
// via the dw MFMA (bit-identical to stage2's residual recompute); LDS-staged
// coalesced bf16 write-back.
template<int CIN_, int COUT_, bool DOWN, bool PREV>
__global__ __launch_bounds__(256,4)
void k_stage1(const void* __restrict__ xin,
              const float* __restrict__ A2p, const float* __restrict__ B2p,
              const float* __restrict__ fmv,
              const unsigned short* __restrict__ lwpk, const float* __restrict__ lbf,
              bf16* __restrict__ zbuf,
              const unsigned short* __restrict__ dwpk, const float* __restrict__ dbf,
              float* __restrict__ dpart, const int* __restrict__ flag)
{
  constexpr int F  = VV*COUT_;
  constexpr int KT = CIN_/32;
  constexpr int NL = COUT_/64;
  constexpr int RP = COUT_ + 4;
  const int s = blockIdx.x;
  const int n = s / TT, t = s % TT;
  const int tid = threadIdx.x;
  const int lane = tid & 63, wid = tid >> 6;

  __shared__ __align__(16) float xt[CIN_][20];
  __shared__ __align__(16) unsigned short xA[32*CIN_];   // bf16 xs, swizzled
  __shared__ unsigned short zst[F];
  __shared__ __align__(16) unsigned short xD[DOWN ? 32*64 : 16];
  __shared__ __align__(16) float scrD[DOWN ? VV*RP : 4];

  if constexpr (PREV){
    const bf16* zin = (const bf16*)xin + (size_t)s*(CIN_*VV);
    for(int idx=tid; idx<CIN_*VV; idx+=256){
      int c = idx/VV, u = idx - c*VV;
      float v = fmaxf(b2f(zin[idx])*A2p[c] + B2p[c], 0.f);
      xt[c][u] = v;
      if constexpr (DOWN){
        int bo = ((u*64 + c)*2) ^ ((u&7)<<4);
        *(unsigned short*)((char*)xD + bo) = f2u(v);
      }
    }
  } else {
    const int mode = *flag;
    for(int idx=tid; idx<CIN_*VV; idx+=256){
      int c = idx/VV, u = idx - c*VV;
      xt[c][u] = ldi(xin, (((size_t)n*CIN_ + c)*TT + t)*VV + u, mode);
    }
  }
  __syncthreads();
  // shift-gather + feature mask -> xs[i][j] bf16 (A-fragment layout, swizzled)
  for(int idx=tid; idx<CIN_*VV; idx+=256){
    int j = idx/VV, i = idx - j*VV;
    float v = xt[j][(i+j)%VV] * fmv[i*CIN_ + j];
    int bo = ((i*CIN_ + j)*2) ^ ((i&7)<<4);
    *(unsigned short*)((char*)xA + bo) = f2u(v);
  }
  __syncthreads();

  // ---- main MFMA: ypre[i][d] ----
  {
    f32x4 z4 = {0.f,0.f,0.f,0.f};
    f32x4 acc[2][NL];
#pragma unroll
    for(int mt=0; mt<2; ++mt)
#pragma unroll
    for(int nl=0; nl<NL; ++nl) acc[mt][nl] = z4;
    const bf16x8* lwp = reinterpret_cast<const bf16x8*>(lwpk);
#pragma unroll
    for(int kt=0; kt<KT; ++kt){
      bf16x8 af[2];
#pragma unroll
      for(int mt=0; mt<2; ++mt){
        int i = mt*16 + (lane&15);
        int bo = ((i*CIN_ + kt*32 + ((lane>>4)<<3))*2) ^ ((i&7)<<4);
        af[mt] = *reinterpret_cast<const bf16x8*>((const char*)xA + bo);
      }
#pragma unroll
      for(int nl=0; nl<NL; ++nl){
        int ntg = wid*NL + nl;
        bf16x8 bw = lwp[(ntg*KT + kt)*64 + lane];
#pragma unroll
        for(int mt=0; mt<2; ++mt)
          acc[mt][nl] = __builtin_amdgcn_mfma_f32_16x16x32_bf16(af[mt], bw, acc[mt][nl], 0,0,0);
      }
    }
    float lb_[NL];
#pragma unroll
    for(int nl=0; nl<NL; ++nl) lb_[nl] = lbf[(wid*NL+nl)*16 + (lane&15)];
#pragma unroll
    for(int mt=0; mt<2; ++mt)
#pragma unroll
    for(int nl=0; nl<NL; ++nl)
#pragma unroll
    for(int r=0; r<4; ++r){
      int i = mt*16 + ((lane>>4)<<2) + r;
      if(i < VV){
        int d = (wid*NL+nl)*16 + (lane&15);
        zst[i*COUT_ + d] = f2u(acc[mt][nl][r] + lb_[nl]);
      }
    }
  }

  if constexpr (DOWN){
    // down-conv MFMA: Dres[u][d] = sum_c dw[d][c]*xt[c][u]
    f32x4 z4 = {0.f,0.f,0.f,0.f};
    f32x4 dacc[2][2] = {{z4,z4},{z4,z4}};
    const bf16x8* dwp = reinterpret_cast<const bf16x8*>(dwpk);
#pragma unroll
    for(int kt=0; kt<2; ++kt){
      bf16x8 af[2];
#pragma unroll
      for(int mt=0; mt<2; ++mt){
        int u = mt*16 + (lane&15);
        int bo = ((u*64 + kt*32 + ((lane>>4)<<3))*2) ^ ((u&7)<<4);
        af[mt] = *reinterpret_cast<const bf16x8*>((const char*)xD + bo);
      }
#pragma unroll
      for(int nl=0; nl<2; ++nl){
        bf16x8 bd = dwp[((wid*2+nl)*2 + kt)*64 + lane];
#pragma unroll
        for(int mt=0; mt<2; ++mt)
          dacc[mt][nl] = __builtin_amdgcn_mfma_f32_16x16x32_bf16(af[mt], bd, dacc[mt][nl], 0,0,0);
      }
    }
#pragma unroll
    for(int mt=0; mt<2; ++mt)
#pragma unroll
    for(int nl=0; nl<2; ++nl)
#pragma unroll
    for(int r=0; r<4; ++r){
      int u = mt*16 + ((lane>>4)<<2) + r;
      if(u < VV){
        int d = (wid*2+nl)*16 + (lane&15);
        scrD[u*RP + d] = dacc[mt][nl][r];
      }
    }
  }
  __syncthreads();

  // ---- coalesced bf16 write-back ----
  bf16* zp = zbuf + (size_t)s*F;
  for(int idx=tid; idx<F; idx+=256)
    ((unsigned short*)zp)[idx] = zst[idx];

  if constexpr (DOWN){
    if(tid < 128){
      int d = tid;
      float db_ = dbf[d], a1 = 0.f, a2 = 0.f;
#pragma unroll
      for(int u=0; u<VV; ++u){
        float r = scrD[u*RP + d] + db_;
        a1 += r; a2 += r*r;
      }
      float* bucket = dpart + (size_t)(s & 63)*256;
      atomicAdd(&bucket[d],       a1);
      atomicAdd(&bucket[128 + d], a2);
    }
  }
}

// ---- column stats of [NT][F] bf16 buffer ----
__global__ __launch_bounds__(256)
void k_colstats(const bf16* __restrict__ zb, int F,
                float* __restrict__ s1, float* __restrict__ s2)
{
  int f = blockIdx.x*256 + threadIdx.x;
  if(f >= F) return;
  const int RPC = NT/64;
  const bf16* p = zb + (size_t)(blockIdx.y*RPC)*F + f;
  float a=0.f, b=0.f;
  for(int r=0; r<RPC; r++){ float v = b2f(p[(size_t)r*F]); a += v; b += v*v; }
  atomicAdd(&s1[f], a);
  atomicAdd(&s2[f], b);
}

// ---- BN1d finalize ----
template<int COUT_>
__global__ void k_fin1(const float* __restrict__ s1, const float* __restrict__ s2,
                       const void* __restrict__ bng, const void* __restrict__ bnb,
                       float* __restrict__ A1, float* __restrict__ B1,
                       const int* __restrict__ flag)
{
  const int F = VV*COUT_;
  int fp = blockIdx.x*256 + threadIdx.x;
  if(fp >= F) return;
  int mode = *flag;
  int ip = fp/COUT_, d = fp - ip*COUT_;
  int f = ((ip + d)%VV)*COUT_ + d;
  float m = s1[fp] * (1.0f/NT);
  float v = s2[fp] * (1.0f/NT) - m*m;
  float a = ldi(bng, f, mode) * rsqrtf(v + EPSF);
  A1[fp] = a;
  B1[fp] = ldi(bnb, f, mode) - m*a;
}

// ---- BN2d finalize ----
template<int COUT_>
__global__ void k_fin2(const float* __restrict__ s1, const float* __restrict__ s2,
                       const void* __restrict__ bnsg, const void* __restrict__ bnsb,
                       float* __restrict__ A2, float* __restrict__ B2,
                       const int* __restrict__ flag)
{
  int d = threadIdx.x;
  if(d >= COUT_) return;
  int mode = *flag;
  float a=0.f, b=0.f;
  for(int u=0;u<VV;u++){ a += s1[d*VV+u]; b += s2[d*VV+u]; }
  const float inv = 1.0f/((float)NT*VV);
  float m = a*inv, v = b*inv - m*m;
  float g_ = ldi(bnsg, d, mode) * rsqrtf(v + EPSF);
  A2[d] = g_;
  B2[d] = ldi(bnsb, d, mode) - m*g_;
}

// ---- reduce 64 buckets -> A2d/B2d ----
__global__ void k_dfin(const float* __restrict__ dpart, const void* __restrict__ dbng,
                       const void* __restrict__ dbnb, float* __restrict__ A2d,
                       float* __restrict__ B2d, const int* __restrict__ flag){
  int c = threadIdx.x;
  int mode = *flag;
  float a = 0.f;
  for(int r=0;r<64;r++) a += dpart[(size_t)r*256 + c];
  __shared__ float red[256];
  red[c] = a;
  __syncthreads();
  if(c < 128){
    const float inv = 1.0f/((float)NT*VV);
    float m = red[c]*inv;
    float v = red[128+c]*inv - m*m;
    float g_ = ldi(dbng, c, mode) * rsqrtf(v + EPSF);
    A2d[c] = g_;
    B2d[c] = ldi(dbnb, c, mode) - m*g_;
  }
}

// ---- Stage 2 (MFMA) ----
template<int CIN_, int COUT_, bool DOWN, bool PREV>
__global__ __launch_bounds__(256,3)
void k_stage2(const void* __restrict__ xin,
              const float* __restrict__ A2p, const float* __restrict__ B2p,
              bf16* __restrict__ zy,
              const float* __restrict__ A1, const float* __restrict__ B1,
              const float* __restrict__ gmat,
              const unsigned short* __restrict__ wpk,
              const unsigned short* __restrict__ w1pk,
              const float* __restrict__ w1bf,
              const unsigned short* __restrict__ dwpk,
              const float* __restrict__ dbf,
              const float* __restrict__ A2d, const float* __restrict__ B2d,
              const int* __restrict__ flag)
{
  constexpr int F  = VV*COUT_;
  constexpr int KT = COUT_/32;
  constexpr int NL = COUT_/64;
  constexpr int RP = COUT_ + 4;
  const int s = blockIdx.x;
  const int n = s/TT, t = s % TT;
  const int tid = threadIdx.x;
  const int lane = tid & 63, wid = tid >> 6;

  __shared__ __align__(16) unsigned short x2t[32*COUT_];
  __shared__ __align__(16) float scrA[VV*RP];
  __shared__ __align__(16) float scrB[VV*RP];
  __shared__ unsigned short zst[F];
  __shared__ float gt[VV][21];
  __shared__ __align__(16) unsigned short xtt[DOWN ? 32*64 : 16];
  __shared__ __align__(16) float XT[DOWN ? 1 : CIN_][20];

  for(int idx=tid; idx<VV*VV; idx+=256)
    gt[idx/VV][idx%VV] = gmat[(size_t)s*(VV*VV) + idx];

  if constexpr (DOWN){
    const bf16* zin = (const bf16*)xin + (size_t)s*(CIN_*VV);
    for(int idx=tid; idx<CIN_*VV; idx+=256){
      int c = idx/VV, u = idx - c*VV;
      float v = fmaxf(b2f(zin[idx])*A2p[c] + B2p[c], 0.f);
      int bo = ((u*64 + c)*2) ^ ((u&7)<<4);
      *(unsigned short*)((char*)xtt + bo) = f2u(v);
    }
  } else if constexpr (PREV){
    const bf16* zin = (const bf16*)xin + (size_t)s*(CIN_*VV);
    for(int idx=tid; idx<CIN_*VV; idx+=256){
      int c = idx/VV, u = idx - c*VV;
      XT[c][u] = fmaxf(b2f(zin[idx])*A2p[c] + B2p[c], 0.f);
    }
  } else {
    const int mode = *flag;
    for(int idx=tid; idx<CIN_*VV; idx+=256){
      int c = idx/VV, u = idx - c*VV;
      XT[c][u] = ldi(xin, (((size_t)n*CIN_ + c)*TT + t)*VV + u, mode);
    }
  }
  __syncthreads();

  if constexpr (DOWN){
    f32x4 z4 = {0.f,0.f,0.f,0.f};
    f32x4 dacc[2][2] = {{z4,z4},{z4,z4}};
    const bf16x8* dwp = reinterpret_cast<const bf16x8*>(dwpk);
#pragma unroll
    for(int kt=0; kt<2; ++kt){
      bf16x8 af[2];
#pragma unroll
      for(int mt=0; mt<2; ++mt){
        int u = mt*16 + (lane&15);
        int bo = ((u*64 + kt*32 + ((lane>>4)<<3))*2) ^ ((u&7)<<4);
        af[mt] = *reinterpret_cast<const bf16x8*>((const char*)xtt + bo);
      }
#pragma unroll
      for(int nl=0; nl<2; ++nl){
        bf16x8 bd = dwp[((wid*2+nl)*2 + kt)*64 + lane];
#pragma unroll
        for(int mt=0; mt<2; ++mt)
          dacc[mt][nl] = __builtin_amdgcn_mfma_f32_16x16x32_bf16(af[mt], bd, dacc[mt][nl], 0,0,0);
      }
    }
#pragma unroll
    for(int mt=0; mt<2; ++mt)
#pragma unroll
    for(int nl=0; nl<2; ++nl)
#pragma unroll
    for(int r=0; r<4; ++r){
      int u = mt*16 + ((lane>>4)<<2) + r;
      if(u < VV){
        int d = (wid*2+nl)*16 + (lane&15);
        scrA[u*RP + d] = dacc[mt][nl][r];
      }
    }
    __syncthreads();
  }

  // ---- staging: BN1d + residual + ReLU -> X2T bf16 (swizzled) ----
  bf16* zp = zy + (size_t)s*F;
  for(int idx=tid; idx<F; idx+=256){
    int ip = idx/COUT_, d = idx - ip*COUT_;
    int u = (ip + d) % VV;
    float res;
    if constexpr (DOWN) res = (scrA[u*RP + d] + dbf[d])*A2d[d] + B2d[d];
    else                res = XT[d][u];
    float v = fmaxf(b2f(zp[idx])*A1[idx] + B1[idx] + res, 0.f);
    int bo = ((u*COUT_ + d)*2) ^ ((u&7)<<4);
    *(unsigned short*)((char*)x2t + bo) = f2u(v);
  }
  __syncthreads();

  // ---- main convs via MFMA: Yw/Y1[i][d] ----
  {
    f32x4 z4 = {0.f,0.f,0.f,0.f};
    f32x4 accw[2][NL], acc1[2][NL];
#pragma unroll
    for(int mt=0; mt<2; ++mt)
#pragma unroll
    for(int nl=0; nl<NL; ++nl){ accw[mt][nl] = z4; acc1[mt][nl] = z4; }
    const bf16x8* wp  = reinterpret_cast<const bf16x8*>(wpk);
    const bf16x8* w1p = reinterpret_cast<const bf16x8*>(w1pk);
#pragma unroll
    for(int kt=0; kt<KT; ++kt){
      bf16x8 af[2];
#pragma unroll
      for(int mt=0; mt<2; ++mt){
        int i = mt*16 + (lane&15);
        int bo = ((i*COUT_ + kt*32 + ((lane>>4)<<3))*2) ^ ((i&7)<<4);
        af[mt] = *reinterpret_cast<const bf16x8*>((const char*)x2t + bo);
      }
#pragma unroll
      for(int nl=0; nl<NL; ++nl){
        int ntg = wid*NL + nl;
        bf16x8 bw = wp [(ntg*KT + kt)*64 + lane];
        bf16x8 b1 = w1p[(ntg*KT + kt)*64 + lane];
#pragma unroll
        for(int mt=0; mt<2; ++mt){
          accw[mt][nl] = __builtin_amdgcn_mfma_f32_16x16x32_bf16(af[mt], bw, accw[mt][nl], 0,0,0);
          acc1[mt][nl] = __builtin_amdgcn_mfma_f32_16x16x32_bf16(af[mt], b1, acc1[mt][nl], 0,0,0);
        }
      }
    }
#pragma unroll
    for(int mt=0; mt<2; ++mt)
#pragma unroll
    for(int nl=0; nl<NL; ++nl)
#pragma unroll
    for(int r=0; r<4; ++r){
      int i = mt*16 + ((lane>>4)<<2) + r;
      if(i < VV){
        int d = (wid*NL+nl)*16 + (lane&15);
        scrA[i*RP + d] = accw[mt][nl][r];
        scrB[i*RP + d] = acc1[mt][nl][r];
      }
    }
  }
  __syncthreads();

  // ---- graph apply + bias -> zst (LDS) ----
  {
    constexpr int NSF = 256/COUT_;
    constexpr int IB  = (VV + NSF - 1)/NSF;
    const int d = tid % COUT_;
    const int h = tid / COUT_;
    float rw[VV];
#pragma unroll
    for(int w=0; w<VV; ++w) rw[w] = scrA[w*RP + d];
    const float bias = w1bf[d];
    const int i0 = h*IB, i1 = (i0+IB < VV) ? i0+IB : VV;
    for(int i=i0; i<i1; ++i){
      float o = scrB[i*RP + d] + bias;
#pragma unroll
      for(int w=0; w<VV; ++w) o += gt[i][w]*rw[w];
      zst[d*VV + i] = f2u(o);
    }
  }
  __syncthreads();
  for(int idx=tid; idx<F; idx+=256)
    ((unsigned short*)zp)[idx] = zst[idx];
}

// ---- Stage 3: BN2d + ReLU -> output; NaN canary ----
template<int COUT_>
__global__ __launch_bounds__(256)
void k_stage3(const bf16* __restrict__ ybuf, const float* __restrict__ A2,
              const float* __restrict__ B2, void* __restrict__ out,
              const int* __restrict__ flag)
{
  const int s = blockIdx.x, n = s/TT, t = s % TT, tid = threadIdx.x;
  const int mode = *flag;
  constexpr int F = VV*COUT_;
  const bf16* yp = ybuf + (size_t)s*F;
  for(int idx=tid; idx<F; idx+=256){
    int d = idx/VV, u = idx - d*VV;
    float v0 = b2f(yp[idx])*A2[d] + B2[d];
    float v = fmaxf(v0, 0.f);
    if(!(v0 == v0) || fabsf(v0) > 1e30f) v = 1000.0f;
    size_t o = (((size_t)n*COUT_ + d)*TT + t)*VV + u;
    if(mode) ((float*)out)[o] = v;
    else     ((bf16*)out)[o]  = f2b(v);
  }
}

extern "C" void kernel_launch(void* const* d_in, const int* in_sizes, int n_in,
                              void* d_out, int out_size, void* d_ws, size_t ws_size,
                              hipStream_t stream)
{
  const void* in[39];
  for(int i=0;i<39;i++) in[i] = d_in[i];

  char* ws = (char*)d_ws;
  size_t off = 0;
  auto alloc = [&](size_t bytes)->void*{
    void* p = ws + off;
    off = (off + bytes + 255) & ~(size_t)255;
    return p;
  };
  int*   flag = (int*)  alloc(4);
  float* gmat = (float*)alloc((size_t)NT*VV*VV*4);
  bf16*  zA   = (bf16*) alloc((size_t)NT*2432*2);
  bf16*  zB   = (bf16*) alloc((size_t)NT*2432*2);
  float* dpart= (float*)alloc((size_t)64*256*4);
  float* s1   = (float*)alloc(2432*4);
  float* s2   = (float*)alloc(2432*4);
  float* A1   = (float*)alloc(2432*4);
  float* B1   = (float*)alloc(2432*4);
  float* A2b1 = (float*)alloc(128*4);
  float* B2b1 = (float*)alloc(128*4);
  float* A2b2 = (float*)alloc(128*4);
  float* B2b2 = (float*)alloc(128*4);
  float* A2b3 = (float*)alloc(128*4);
  float* B2b3 = (float*)alloc(128*4);
  float* A2d  = (float*)alloc(128*4);
  float* B2d  = (float*)alloc(128*4);
  float* fmv1 = (float*)alloc(1216*4);
  float* fmv2 = (float*)alloc(1216*4);
  float* fmv3 = (float*)alloc(2432*4);
  // packed bf16 MFMA weights + fp32 biases
  unsigned short* b1_lwP = (unsigned short*)alloc(64*64*2);
  float*  b1_lbf  = (float*)alloc(64*4);
  unsigned short* b1_wwP = (unsigned short*)alloc(64*64*2);
  unsigned short* b1_w1P = (unsigned short*)alloc(64*64*2);
  float*  b1_w1bf = (float*)alloc(64*4);
  unsigned short* b2_lwP = (unsigned short*)alloc(64*128*2);
  float*  b2_lbf  = (float*)alloc(128*4);
  unsigned short* b2_wwP = (unsigned short*)alloc(128*128*2);
  unsigned short* b2_w1P = (unsigned short*)alloc(128*128*2);
  float*  b2_w1bf = (float*)alloc(128*4);
  unsigned short* b2_dwP = (unsigned short*)alloc(128*64*2);
  float*  b2_dbf  = (float*)alloc(128*4);
  unsigned short* b3_lwP = (unsigned short*)alloc(128*128*2);
  float*  b3_lbf  = (float*)alloc(128*4);
  unsigned short* b3_wwP = (unsigned short*)alloc(128*128*2);
  unsigned short* b3_w1P = (unsigned short*)alloc(128*128*2);
  float*  b3_w1bf = (float*)alloc(128*4);
  float*  g1wT    = (float*)alloc(32*64*4);
  float*  g1bf    = (float*)alloc(32*4);
  float*  g2wT    = (float*)alloc(32*64*4);
  float*  g2bf    = (float*)alloc(32*4);

  if(ws_size < off){
    hipMemsetAsync(d_out, 0x41, (size_t)out_size*2, stream);
    return;
  }

  k_detect<<<1,256,0,stream>>>((const unsigned short*)in[0], flag);
  k_canary<<<(out_size+255)/256,256,0,stream>>>(d_out, out_size, flag);

  auto cvt = [&](const void* src, float* dst, int n){
    k_cvt<<<(n+255)/256,256,0,stream>>>(src, dst, n, flag);
  };
  auto cvtT = [&](const void* src, float* dst, int rows, int cols){
    k_cvtT<<<(rows*cols+255)/256,256,0,stream>>>(src, dst, rows, cols, flag);
  };
  auto packB = [&](const void* src, unsigned short* dst, int ND, int KD, int trans){
    k_packB<<<(ND*KD+255)/256,256,0,stream>>>(src, dst, ND, KD, trans, flag);
  };
  // lw buffers are K-major [CIN][COUT] -> trans=1; ww/w1w/dw are [N][K] -> trans=0
  packB(in[5],  b1_lwP, 64, 64, 1);     cvt(in[6],  b1_lbf,  64);
  packB(in[12], b1_wwP, 64, 64, 0);     packB(in[13], b1_w1P, 64, 64, 0);
  cvt (in[14], b1_w1bf, 64);
  packB(in[15], b2_lwP, 128, 64, 1);    cvt(in[16], b2_lbf,  128);
  packB(in[22], b2_wwP, 128, 128, 0);   packB(in[23], b2_w1P, 128, 128, 0);
  cvt (in[24], b2_w1bf, 128);
  packB(in[25], b2_dwP, 128, 64, 0);    cvt(in[26], b2_dbf,  128);
  packB(in[29], b3_lwP, 128, 128, 1);   cvt(in[30], b3_lbf,  128);
  packB(in[36], b3_wwP, 128, 128, 0);   packB(in[37], b3_w1P, 128, 128, 0);
  cvt (in[38], b3_w1bf, 128);
  cvtT(in[1],  g1wT,    32, 64);        cvt(in[2],  g1bf,    32);
  cvtT(in[3],  g2wT,    32, 64);        cvt(in[4],  g2bf,    32);

  k_tanhp1<<<5,256,0,stream>>>(in[7],  fmv1, 1216, flag);
  k_tanhp1<<<5,256,0,stream>>>(in[17], fmv2, 1216, flag);
  k_tanhp1<<<10,256,0,stream>>>(in[31], fmv3, 2432, flag);
  k_gspa<<<NT,256,0,stream>>>(in[0], g1wT, g1bf, g2wT, g2bf, gmat, flag);

  // ---- Block 1 (64 -> 64, identity residual) ----
  k_stage1<64,64,false,false><<<NT,256,0,stream>>>(in[0], nullptr, nullptr, fmv1,
                                                   b1_lwP, b1_lbf, zA,
                                                   nullptr, nullptr, nullptr, flag);
  k_zero<<<19,256,0,stream>>>(s1, 2*2432);
  k_colstats<<<dim3(5,64),256,0,stream>>>(zA, 1216, s1, s2);
  k_fin1<64><<<5,256,0,stream>>>(s1, s2, in[8], in[9], A1, B1, flag);
  k_stage2<64,64,false,false><<<NT,256,0,stream>>>(in[0], nullptr, nullptr, zA, A1, B1,
                                                   gmat, b1_wwP, b1_w1P, b1_w1bf,
                                                   nullptr, nullptr, nullptr, nullptr, flag);
  k_zero<<<19,256,0,stream>>>(s1, 2*2432);
  k_colstats<<<dim3(5,64),256,0,stream>>>(zA, 1216, s1, s2);
  k_fin2<64><<<1,64,0,stream>>>(s1, s2, in[10], in[11], A2b1, B2b1, flag);

  // ---- Block 2 (64 -> 128, down path) ----
  k_zero<<<64,256,0,stream>>>(dpart, 64*256);
  k_stage1<64,128,true,true><<<NT,256,0,stream>>>(zA, A2b1, B2b1, fmv2,
                                                  b2_lwP, b2_lbf, zB,
                                                  b2_dwP, b2_dbf, dpart, flag);
  k_dfin<<<1,256,0,stream>>>(dpart, in[27], in[28], A2d, B2d, flag);
  k_zero<<<19,256,0,stream>>>(s1, 2*2432);
  k_colstats<<<dim3(10,64),256,0,stream>>>(zB, 2432, s1, s2);
  k_fin1<128><<<10,256,0,stream>>>(s1, s2, in[18], in[19], A1, B1, flag);
  k_stage2<64,128,true,true><<<NT,256,0,stream>>>(zA, A2b1, B2b1, zB, A1, B1,
                                                  gmat, b2_wwP, b2_w1P, b2_w1bf,
                                                  b2_dwP, b2_dbf, A2d, B2d, flag);
  k_zero<<<19,256,0,stream>>>(s1, 2*2432);
  k_colstats<<<dim3(10,64),256,0,stream>>>(zB, 2432, s1, s2);
  k_fin2<128><<<1,128,0,stream>>>(s1, s2, in[20], in[21], A2b2, B2b2, flag);

  // ---- Block 3 (128 -> 128, identity) ----
  k_stage1<128,128,false,true><<<NT,256,0,stream>>>(zB, A2b2, B2b2, fmv3,
                                                    b3_lwP, b3_lbf, zA,
                                                    nullptr, nullptr, nullptr, flag);
  k_zero<<<19,256,0,stream>>>(s1, 2*2432);
  k_colstats<<<dim3(10,64),256,0,stream>>>(zA, 2432, s1, s2);
  k_fin1<128><<<10,256,0,stream>>>(s1, s2, in[32], in[33], A1, B1, flag);
  k_stage2<128,128,false,true><<<NT,256,0,stream>>>(zB, A2b2, B2b2, zA, A1, B1,
                                                    gmat, b3_wwP, b3_w1P, b3_w1bf,
                                                    nullptr, nullptr, nullptr, nullptr, flag);
  k_zero<<<19,256,0,stream>>>(s1, 2*2432);
  k_colstats<<<dim3(10,64),256,0,stream>>>(zA, 2432, s1, s2);
  k_fin2<128><<<1,128,0,stream>>>(s1, s2, in[34], in[35], A2b3, B2b3, flag);
  k_stage3<128><<<NT,256,0,stream>>>(zA, A2b3, B2b3, d_out, flag);
}

// Round 8
// 1466.272 us; speedup vs baseline: 10.7716x; 1.0731x over previous
//
#include <hip/hip_runtime.h>
#include <hip/hip_bf16.h>

typedef __hip_bfloat16 bf16;
typedef __bf16 bf16x8 __attribute__((ext_vector_type(8)));
typedef float  f32x4  __attribute__((ext_vector_type(4)));

#define NBATCH 128
#define TT 128
#define VV 19
#define NT (NBATCH*TT)
#define EPSF 1e-5f

static __device__ __forceinline__ float b2f(bf16 v){ return __bfloat162float(v); }
static __device__ __forceinline__ bf16  f2b(float v){ return __float2bfloat16(v); }
static __device__ __forceinline__ unsigned short f2u(float v){
  bf16 b = f2b(v); return *reinterpret_cast<unsigned short*>(&b);
}
// dual-dtype input load: mode=1 -> fp32, mode=0 -> bf16
static __device__ __forceinline__ float ldi(const void* p, size_t i, int mode){
  return mode ? ((const float*)p)[i] : b2f(((const bf16*)p)[i]);
}

// ---- detect input dtype: fp32 buffers read as bf16 have wild exponents ----
__global__ void k_detect(const unsigned short* __restrict__ p, int* __restrict__ flag){
  const int tid = threadIdx.x;
  __shared__ int cnt;
  if(tid==0) cnt = 0;
  __syncthreads();
  int local = 0;
  for(int i=tid; i<2048; i+=256){
    unsigned short h = p[i];
    int e = (h>>7) & 0xFF;
    if(h != 0 && (e < 107 || e > 147)) local++;
  }
  atomicAdd(&cnt, local);
  __syncthreads();
  if(tid==0) *flag = (cnt > 300) ? 1 : 0;
}

// ---- canary: pre-fill output with 3.0 ----
__global__ void k_canary(void* __restrict__ out, int n, const int* __restrict__ flag){
  int i = blockIdx.x*256 + threadIdx.x;
  if(i >= n) return;
  if(*flag) ((float*)out)[i] = 3.0f;
  else      ((bf16*)out)[i]  = f2b(3.0f);
}

__global__ void k_zero(float* __restrict__ p, int n){
  int i = blockIdx.x*256 + threadIdx.x;
  if(i < n) p[i] = 0.f;
}

// ---- convert a weight buffer to fp32 workspace copy ----
__global__ void k_cvt(const void* __restrict__ src, float* __restrict__ dst, int n,
                      const int* __restrict__ flag){
  int i = blockIdx.x*256 + threadIdx.x;
  if(i < n) dst[i] = ldi(src, i, *flag);
}

// ---- transposed fp32 copy: dst[c*rows + r] = src[r*cols + c] ----
__global__ void k_cvtT(const void* __restrict__ src, float* __restrict__ dst,
                       int rows, int cols, const int* __restrict__ flag){
  int i = blockIdx.x*256 + threadIdx.x;
  if(i < rows*cols){
    int r = i / cols, c = i - r*cols;
    dst[c*rows + r] = ldi(src, i, *flag);
  }
}

// ---- pack weight into MFMA B-fragment layout, bf16 ----
// B[k][n]; lane l: n = l&15, k = (l>>4)*8 + j.
// trans=0: src is W[n][k] row-major (ND x KD). trans=1: src is W[k][n] (KD x ND).
__global__ void k_packB(const void* __restrict__ src, unsigned short* __restrict__ dst,
                        int ND, int KD, int trans, const int* __restrict__ flag){
  int o = blockIdx.x*256 + threadIdx.x;
  if(o >= ND*KD) return;
  int mode = *flag;
  int KT = KD >> 5;
  int j = o & 7, l = (o >> 3) & 63;
  int q = o >> 9;
  int kt = q % KT, nt = q / KT;
  int d = nt*16 + (l & 15);
  int c = kt*32 + ((l >> 4) << 3) + j;
  size_t si = trans ? ((size_t)c*ND + d) : ((size_t)d*KD + c);
  dst[o] = f2u(ldi(src, si, mode));
}

// ---- fmv = tanh(fm)+1 ----
__global__ void k_tanhp1(const void* __restrict__ fm, float* __restrict__ out, int n,
                         const int* __restrict__ flag){
  int i = blockIdx.x*256 + threadIdx.x;
  int mode = *flag;
  if(i < n) out[i] = tanhf(ldi(fm, i, mode)) + 1.0f;
}

// ---- g = softmax( A @ B ) per (n,t); weights pre-transposed fp32 ----
__global__ __launch_bounds__(256)
void k_gspa(const void* __restrict__ x0,
            const float* __restrict__ w1T, const float* __restrict__ b1f,
            const float* __restrict__ w2T, const float* __restrict__ b2f,
            float* __restrict__ gout, const int* __restrict__ flag)
{
  const int s = blockIdx.x;
  const int n = s / TT, t = s % TT;
  const int tid = threadIdx.x;
  const int mode = *flag;
  __shared__ float xt[64][20];
  __shared__ float Am[VV][33];
  __shared__ float Bm[32][21];
  __shared__ float Sm[VV][21];
  for(int idx=tid; idx<64*VV; idx+=256){
    int c = idx/VV, u = idx - c*VV;
    xt[c][u] = ldi(x0, (((size_t)n*64 + c)*TT + t)*VV + u, mode);
  }
  __syncthreads();
  for(int idx=tid; idx<VV*32; idx+=256){
    int u = idx/32, k = idx & 31;
    float acc = b1f[k];
    for(int c=0;c<64;c++) acc += xt[c][u]*w1T[c*32+k];
    Am[u][k] = acc;
  }
  for(int idx=tid; idx<32*VV; idx+=256){
    int k = idx/VV, w = idx - k*VV;
    float acc = b2f[k];
    for(int c=0;c<64;c++) acc += xt[c][w]*w2T[c*32+k];
    Bm[k][w] = acc;
  }
  __syncthreads();
  for(int idx=tid; idx<VV*VV; idx+=256){
    int u = idx/VV, w = idx - u*VV;
    float acc = 0.f;
#pragma unroll
    for(int k=0;k<32;k++) acc += Am[u][k]*Bm[k][w];
    Sm[u][w] = acc;
  }
  __syncthreads();
  if(tid < VV){
    int u = tid;
    float mx = -1e30f;
    for(int w=0;w<VV;w++) mx = fmaxf(mx, Sm[u][w]);
    float sum = 0.f;
    for(int w=0;w<VV;w++){ float e = __expf(Sm[u][w]-mx); Sm[u][w]=e; sum+=e; }
    float r = 1.0f/sum;
    for(int w=0;w<VV;w++) Sm[u][w] *= r;
  }
  __syncthreads();
  float* gp = gout + (size_t)s*(VV*VV);
  for(int idx=tid; idx<VV*VV; idx+=256) gp[idx] = Sm[idx/VV][idx%VV];
}

// ---- Stage 1 (MFMA, LDS-aliased): xt (phases A-B) aliases zst (phase C) ----
template<int CIN_, int COUT_, bool DOWN, bool PREV>
__global__ __launch_bounds__(256,5)
void k_stage1(const void* __restrict__ xin,
              const float* __restrict__ A2p, const float* __restrict__ B2p,
              const float* __restrict__ fmv,
              const unsigned short* __restrict__ lwpk, const float* __restrict__ lbf,
              bf16* __restrict__ zbuf,
              const unsigned short* __restrict__ dwpk, const float* __restrict__ dbf,
              float* __restrict__ dpart, const int* __restrict__ flag)
{
  constexpr int F  = VV*COUT_;
  constexpr int KT = CIN_/32;
  constexpr int NL = COUT_/64;
  constexpr int RP = COUT_ + 4;
  constexpr int SZ_XT  = CIN_*20*4;
  constexpr int SZ_ZST = F*2;
  constexpr int BUFX = (SZ_XT > SZ_ZST ? SZ_XT : SZ_ZST);
  const int s = blockIdx.x;
  const int n = s / TT, t = s % TT;
  const int tid = threadIdx.x;
  const int lane = tid & 63, wid = tid >> 6;

  __shared__ __align__(16) char smem1[BUFX];
  float (*xt)[20] = (float(*)[20])smem1;                     // phases A-B
  unsigned short* zst = (unsigned short*)smem1;              // phase C
  __shared__ __align__(16) unsigned short xA[32*CIN_];       // bf16 xs, swizzled
  __shared__ __align__(16) unsigned short xD[DOWN ? 32*64 : 16];
  __shared__ __align__(16) float scrD[DOWN ? VV*RP : 4];

  if constexpr (PREV){
    const bf16* zin = (const bf16*)xin + (size_t)s*(CIN_*VV);
    for(int idx=tid; idx<CIN_*VV; idx+=256){
      int c = idx/VV, u = idx - c*VV;
      float v = fmaxf(b2f(zin[idx])*A2p[c] + B2p[c], 0.f);
      xt[c][u] = v;
      if constexpr (DOWN){
        int bo = ((u*64 + c)*2) ^ ((u&7)<<4);
        *(unsigned short*)((char*)xD + bo) = f2u(v);
      }
    }
  } else {
    const int mode = *flag;
    for(int idx=tid; idx<CIN_*VV; idx+=256){
      int c = idx/VV, u = idx - c*VV;
      xt[c][u] = ldi(xin, (((size_t)n*CIN_ + c)*TT + t)*VV + u, mode);
    }
  }
  __syncthreads();
  // shift-gather + feature mask -> xs[i][j] bf16 (A-fragment layout, swizzled)
  for(int idx=tid; idx<CIN_*VV; idx+=256){
    int j = idx/VV, i = idx - j*VV;
    float v = xt[j][(i+j)%VV] * fmv[i*CIN_ + j];
    int bo = ((i*CIN_ + j)*2) ^ ((i&7)<<4);
    *(unsigned short*)((char*)xA + bo) = f2u(v);
  }
  __syncthreads();          // last xt read above; zst (alias) written below

  // ---- main MFMA: ypre[i][d] ----
  {
    f32x4 z4 = {0.f,0.f,0.f,0.f};
    f32x4 acc[2][NL];
#pragma unroll
    for(int mt=0; mt<2; ++mt)
#pragma unroll
    for(int nl=0; nl<NL; ++nl) acc[mt][nl] = z4;
    const bf16x8* lwp = reinterpret_cast<const bf16x8*>(lwpk);
#pragma unroll
    for(int kt=0; kt<KT; ++kt){
      bf16x8 af[2];
#pragma unroll
      for(int mt=0; mt<2; ++mt){
        int i = mt*16 + (lane&15);
        int bo = ((i*CIN_ + kt*32 + ((lane>>4)<<3))*2) ^ ((i&7)<<4);
        af[mt] = *reinterpret_cast<const bf16x8*>((const char*)xA + bo);
      }
#pragma unroll
      for(int nl=0; nl<NL; ++nl){
        int ntg = wid*NL + nl;
        bf16x8 bw = lwp[(ntg*KT + kt)*64 + lane];
#pragma unroll
        for(int mt=0; mt<2; ++mt)
          acc[mt][nl] = __builtin_amdgcn_mfma_f32_16x16x32_bf16(af[mt], bw, acc[mt][nl], 0,0,0);
      }
    }
    float lb_[NL];
#pragma unroll
    for(int nl=0; nl<NL; ++nl) lb_[nl] = lbf[(wid*NL+nl)*16 + (lane&15)];
#pragma unroll
    for(int mt=0; mt<2; ++mt)
#pragma unroll
    for(int nl=0; nl<NL; ++nl)
#pragma unroll
    for(int r=0; r<4; ++r){
      int i = mt*16 + ((lane>>4)<<2) + r;
      if(i < VV){
        int d = (wid*NL+nl)*16 + (lane&15);
        zst[i*COUT_ + d] = f2u(acc[mt][nl][r] + lb_[nl]);
      }
    }
  }

  if constexpr (DOWN){
    // down-conv MFMA: Dres[u][d] = sum_c dw[d][c]*xt[c][u]
    f32x4 z4 = {0.f,0.f,0.f,0.f};
    f32x4 dacc[2][2] = {{z4,z4},{z4,z4}};
    const bf16x8* dwp = reinterpret_cast<const bf16x8*>(dwpk);
#pragma unroll
    for(int kt=0; kt<2; ++kt){
      bf16x8 af[2];
#pragma unroll
      for(int mt=0; mt<2; ++mt){
        int u = mt*16 + (lane&15);
        int bo = ((u*64 + kt*32 + ((lane>>4)<<3))*2) ^ ((u&7)<<4);
        af[mt] = *reinterpret_cast<const bf16x8*>((const char*)xD + bo);
      }
#pragma unroll
      for(int nl=0; nl<2; ++nl){
        bf16x8 bd = dwp[((wid*2+nl)*2 + kt)*64 + lane];
#pragma unroll
        for(int mt=0; mt<2; ++mt)
          dacc[mt][nl] = __builtin_amdgcn_mfma_f32_16x16x32_bf16(af[mt], bd, dacc[mt][nl], 0,0,0);
      }
    }
#pragma unroll
    for(int mt=0; mt<2; ++mt)
#pragma unroll
    for(int nl=0; nl<2; ++nl)
#pragma unroll
    for(int r=0; r<4; ++r){
      int u = mt*16 + ((lane>>4)<<2) + r;
      if(u < VV){
        int d = (wid*2+nl)*16 + (lane&15);
        scrD[u*RP + d] = dacc[mt][nl][r];
      }
    }
  }
  __syncthreads();

  // ---- coalesced bf16 write-back ----
  bf16* zp = zbuf + (size_t)s*F;
  for(int idx=tid; idx<F; idx+=256)
    ((unsigned short*)zp)[idx] = zst[idx];

  if constexpr (DOWN){
    if(tid < 128){
      int d = tid;
      float db_ = dbf[d], a1 = 0.f, a2 = 0.f;
#pragma unroll
      for(int u=0; u<VV; ++u){
        float r = scrD[u*RP + d] + db_;
        a1 += r; a2 += r*r;
      }
      float* bucket = dpart + (size_t)(s & 63)*256;
      atomicAdd(&bucket[d],       a1);
      atomicAdd(&bucket[128 + d], a2);
    }
  }
}

// ---- column stats of [NT][F] bf16 buffer ----
__global__ __launch_bounds__(256)
void k_colstats(const bf16* __restrict__ zb, int F,
                float* __restrict__ s1, float* __restrict__ s2)
{
  int f = blockIdx.x*256 + threadIdx.x;
  if(f >= F) return;
  const int RPC = NT/64;
  const bf16* p = zb + (size_t)(blockIdx.y*RPC)*F + f;
  float a=0.f, b=0.f;
  for(int r=0; r<RPC; r++){ float v = b2f(p[(size_t)r*F]); a += v; b += v*v; }
  atomicAdd(&s1[f], a);
  atomicAdd(&s2[f], b);
}

// ---- BN1d finalize ----
template<int COUT_>
__global__ void k_fin1(const float* __restrict__ s1, const float* __restrict__ s2,
                       const void* __restrict__ bng, const void* __restrict__ bnb,
                       float* __restrict__ A1, float* __restrict__ B1,
                       const int* __restrict__ flag)
{
  const int F = VV*COUT_;
  int fp = blockIdx.x*256 + threadIdx.x;
  if(fp >= F) return;
  int mode = *flag;
  int ip = fp/COUT_, d = fp - ip*COUT_;
  int f = ((ip + d)%VV)*COUT_ + d;
  float m = s1[fp] * (1.0f/NT);
  float v = s2[fp] * (1.0f/NT) - m*m;
  float a = ldi(bng, f, mode) * rsqrtf(v + EPSF);
  A1[fp] = a;
  B1[fp] = ldi(bnb, f, mode) - m*a;
}

// ---- BN2d finalize ----
template<int COUT_>
__global__ void k_fin2(const float* __restrict__ s1, const float* __restrict__ s2,
                       const void* __restrict__ bnsg, const void* __restrict__ bnsb,
                       float* __restrict__ A2, float* __restrict__ B2,
                       const int* __restrict__ flag)
{
  int d = threadIdx.x;
  if(d >= COUT_) return;
  int mode = *flag;
  float a=0.f, b=0.f;
  for(int u=0;u<VV;u++){ a += s1[d*VV+u]; b += s2[d*VV+u]; }
  const float inv = 1.0f/((float)NT*VV);
  float m = a*inv, v = b*inv - m*m;
  float g_ = ldi(bnsg, d, mode) * rsqrtf(v + EPSF);
  A2[d] = g_;
  B2[d] = ldi(bnsb, d, mode) - m*g_;
}

// ---- reduce 64 buckets -> A2d/B2d ----
__global__ void k_dfin(const float* __restrict__ dpart, const void* __restrict__ dbng,
                       const void* __restrict__ dbnb, float* __restrict__ A2d,
                       float* __restrict__ B2d, const int* __restrict__ flag){
  int c = threadIdx.x;
  int mode = *flag;
  float a = 0.f;
  for(int r=0;r<64;r++) a += dpart[(size_t)r*256 + c];
  __shared__ float red[256];
  red[c] = a;
  __syncthreads();
  if(c < 128){
    const float inv = 1.0f/((float)NT*VV);
    float m = red[c]*inv;
    float v = red[128+c]*inv - m*m;
    float g_ = ldi(dbng, c, mode) * rsqrtf(v + EPSF);
    A2d[c] = g_;
    B2d[c] = ldi(dbnb, c, mode) - m*g_;
  }
}

// ---- Stage 2 (MFMA, LDS-aliased):
//  bufA: XT (A-B, non-DOWN) / scrA (Dres B-C for DOWN; Yw D-E)
//  bufB: xtt (A-B, DOWN)    / scrB (Y1 D-E)
//  bufC: x2t (C-D)          / zst (E)
// every alias pair is separated by an existing __syncthreads().
template<int CIN_, int COUT_, bool DOWN, bool PREV>
__global__ __launch_bounds__(256,5)
void k_stage2(const void* __restrict__ xin,
              const float* __restrict__ A2p, const float* __restrict__ B2p,
              bf16* __restrict__ zy,
              const float* __restrict__ A1, const float* __restrict__ B1,
              const float* __restrict__ gmat,
              const unsigned short* __restrict__ wpk,
              const unsigned short* __restrict__ w1pk,
              const float* __restrict__ w1bf,
              const unsigned short* __restrict__ dwpk,
              const float* __restrict__ dbf,
              const float* __restrict__ A2d, const float* __restrict__ B2d,
              const int* __restrict__ flag)
{
  constexpr int F  = VV*COUT_;
  constexpr int KT = COUT_/32;
  constexpr int NL = COUT_/64;
  constexpr int RP = COUT_ + 4;
  constexpr int SZ_XT  = DOWN ? 0 : CIN_*20*4;
  constexpr int SZ_XTT = DOWN ? 32*64*2 : 0;
  constexpr int SZ_SCR = VV*RP*4;
  constexpr int BUFA = (SZ_XT  > SZ_SCR ? SZ_XT  : SZ_SCR);
  constexpr int BUFB = (SZ_XTT > SZ_SCR ? SZ_XTT : SZ_SCR);
  constexpr int SZ_X2T = 32*COUT_*2;
  constexpr int SZ_ZST = F*2;
  constexpr int BUFC = (SZ_X2T > SZ_ZST ? SZ_X2T : SZ_ZST);
  const int s = blockIdx.x;
  const int n = s/TT, t = s % TT;
  const int tid = threadIdx.x;
  const int lane = tid & 63, wid = tid >> 6;

  __shared__ __align__(16) char smem[BUFA+BUFB+BUFC];
  float (*XT)[20]      = (float(*)[20])smem;
  float* scrA          = (float*)smem;
  unsigned short* xtt  = (unsigned short*)(smem+BUFA);
  float* scrB          = (float*)(smem+BUFA);
  unsigned short* x2t  = (unsigned short*)(smem+BUFA+BUFB);
  unsigned short* zst  = (unsigned short*)(smem+BUFA+BUFB);
  __shared__ float gt[VV][21];

  for(int idx=tid; idx<VV*VV; idx+=256)
    gt[idx/VV][idx%VV] = gmat[(size_t)s*(VV*VV) + idx];

  if constexpr (DOWN){
    const bf16* zin = (const bf16*)xin + (size_t)s*(CIN_*VV);
    for(int idx=tid; idx<CIN_*VV; idx+=256){
      int c = idx/VV, u = idx - c*VV;
      float v = fmaxf(b2f(zin[idx])*A2p[c] + B2p[c], 0.f);
      int bo = ((u*64 + c)*2) ^ ((u&7)<<4);
      *(unsigned short*)((char*)xtt + bo) = f2u(v);
    }
  } else if constexpr (PREV){
    const bf16* zin = (const bf16*)xin + (size_t)s*(CIN_*VV);
    for(int idx=tid; idx<CIN_*VV; idx+=256){
      int c = idx/VV, u = idx - c*VV;
      XT[c][u] = fmaxf(b2f(zin[idx])*A2p[c] + B2p[c], 0.f);
    }
  } else {
    const int mode = *flag;
    for(int idx=tid; idx<CIN_*VV; idx+=256){
      int c = idx/VV, u = idx - c*VV;
      XT[c][u] = ldi(xin, (((size_t)n*CIN_ + c)*TT + t)*VV + u, mode);
    }
  }
  __syncthreads();

  if constexpr (DOWN){
    f32x4 z4 = {0.f,0.f,0.f,0.f};
    f32x4 dacc[2][2] = {{z4,z4},{z4,z4}};
    const bf16x8* dwp = reinterpret_cast<const bf16x8*>(dwpk);
#pragma unroll
    for(int kt=0; kt<2; ++kt){
      bf16x8 af[2];
#pragma unroll
      for(int mt=0; mt<2; ++mt){
        int u = mt*16 + (lane&15);
        int bo = ((u*64 + kt*32 + ((lane>>4)<<3))*2) ^ ((u&7)<<4);
        af[mt] = *reinterpret_cast<const bf16x8*>((const char*)xtt + bo);
      }
#pragma unroll
      for(int nl=0; nl<2; ++nl){
        bf16x8 bd = dwp[((wid*2+nl)*2 + kt)*64 + lane];
#pragma unroll
        for(int mt=0; mt<2; ++mt)
          dacc[mt][nl] = __builtin_amdgcn_mfma_f32_16x16x32_bf16(af[mt], bd, dacc[mt][nl], 0,0,0);
      }
    }
    __syncthreads();   // xtt reads done before scrA (bufA) write; scrA read next phase
#pragma unroll
    for(int mt=0; mt<2; ++mt)
#pragma unroll
    for(int nl=0; nl<2; ++nl)
#pragma unroll
    for(int r=0; r<4; ++r){
      int u = mt*16 + ((lane>>4)<<2) + r;
      if(u < VV){
        int d = (wid*2+nl)*16 + (lane&15);
        scrA[u*RP + d] = dacc[mt][nl][r];
      }
    }
    __syncthreads();
  }

  // ---- staging: BN1d + residual + ReLU -> X2T bf16 (swizzled) ----
  bf16* zp = zy + (size_t)s*F;
  for(int idx=tid; idx<F; idx+=256){
    int ip = idx/COUT_, d = idx - ip*COUT_;
    int u = (ip + d) % VV;
    float res;
    if constexpr (DOWN) res = (scrA[u*RP + d] + dbf[d])*A2d[d] + B2d[d];
    else                res = XT[d][u];
    float v = fmaxf(b2f(zp[idx])*A1[idx] + B1[idx] + res, 0.f);
    int bo = ((u*COUT_ + d)*2) ^ ((u&7)<<4);
    *(unsigned short*)((char*)x2t + bo) = f2u(v);
  }
  __syncthreads();   // XT/scrA reads done; scrA/scrB writes follow MFMA

  // ---- main convs via MFMA: Yw/Y1[i][d] ----
  {
    f32x4 z4 = {0.f,0.f,0.f,0.f};
    f32x4 accw[2][NL], acc1[2][NL];
#pragma unroll
    for(int mt=0; mt<2; ++mt)
#pragma unroll
    for(int nl=0; nl<NL; ++nl){ accw[mt][nl] = z4; acc1[mt][nl] = z4; }
    const bf16x8* wp  = reinterpret_cast<const bf16x8*>(wpk);
    const bf16x8* w1p = reinterpret_cast<const bf16x8*>(w1pk);
#pragma unroll
    for(int kt=0; kt<KT; ++kt){
      bf16x8 af[2];
#pragma unroll
      for(int mt=0; mt<2; ++mt){
        int i = mt*16 + (lane&15);
        int bo = ((i*COUT_ + kt*32 + ((lane>>4)<<3))*2) ^ ((i&7)<<4);
        af[mt] = *reinterpret_cast<const bf16x8*>((const char*)x2t + bo);
      }
#pragma unroll
      for(int nl=0; nl<NL; ++nl){
        int ntg = wid*NL + nl;
        bf16x8 bw = wp [(ntg*KT + kt)*64 + lane];
        bf16x8 b1 = w1p[(ntg*KT + kt)*64 + lane];
#pragma unroll
        for(int mt=0; mt<2; ++mt){
          accw[mt][nl] = __builtin_amdgcn_mfma_f32_16x16x32_bf16(af[mt], bw, accw[mt][nl], 0,0,0);
          acc1[mt][nl] = __builtin_amdgcn_mfma_f32_16x16x32_bf16(af[mt], b1, acc1[mt][nl], 0,0,0);
        }
      }
    }
#pragma unroll
    for(int mt=0; mt<2; ++mt)
#pragma unroll
    for(int nl=0; nl<NL; ++nl)
#pragma unroll
    for(int r=0; r<4; ++r){
      int i = mt*16 + ((lane>>4)<<2) + r;
      if(i < VV){
        int d = (wid*NL+nl)*16 + (lane&15);
        scrA[i*RP + d] = accw[mt][nl][r];
        scrB[i*RP + d] = acc1[mt][nl][r];
      }
    }
  }
  __syncthreads();   // x2t reads done; zst (alias) written next

  // ---- graph apply + bias -> zst (LDS) ----
  {
    constexpr int NSF = 256/COUT_;
    constexpr int IB  = (VV + NSF - 1)/NSF;
    const int d = tid % COUT_;
    const int h = tid / COUT_;
    float rw[VV];
#pragma unroll
    for(int w=0; w<VV; ++w) rw[w] = scrA[w*RP + d];
    const float bias = w1bf[d];
    const int i0 = h*IB, i1 = (i0+IB < VV) ? i0+IB : VV;
    for(int i=i0; i<i1; ++i){
      float o = scrB[i*RP + d] + bias;
#pragma unroll
      for(int w=0; w<VV; ++w) o += gt[i][w]*rw[w];
      zst[d*VV + i] = f2u(o);
    }
  }
  __syncthreads();
  for(int idx=tid; idx<F; idx+=256)
    ((unsigned short*)zp)[idx] = zst[idx];
}

// ---- Stage 3: BN2d + ReLU -> output; NaN canary ----
template<int COUT_>
__global__ __launch_bounds__(256)
void k_stage3(const bf16* __restrict__ ybuf, const float* __restrict__ A2,
              const float* __restrict__ B2, void* __restrict__ out,
              const int* __restrict__ flag)
{
  const int s = blockIdx.x, n = s/TT, t = s % TT, tid = threadIdx.x;
  const int mode = *flag;
  constexpr int F = VV*COUT_;
  const bf16* yp = ybuf + (size_t)s*F;
  for(int idx=tid; idx<F; idx+=256){
    int d = idx/VV, u = idx - d*VV;
    float v0 = b2f(yp[idx])*A2[d] + B2[d];
    float v = fmaxf(v0, 0.f);
    if(!(v0 == v0) || fabsf(v0) > 1e30f) v = 1000.0f;
    size_t o = (((size_t)n*COUT_ + d)*TT + t)*VV + u;
    if(mode) ((float*)out)[o] = v;
    else     ((bf16*)out)[o]  = f2b(v);
  }
}

extern "C" void kernel_launch(void* const* d_in, const int* in_sizes, int n_in,
                              void* d_out, int out_size, void* d_ws, size_t ws_size,
                              hipStream_t stream)
{
  const void* in[39];
  for(int i=0;i<39;i++) in[i] = d_in[i];

  char* ws = (char*)d_ws;
  size_t off = 0;
  auto alloc = [&](size_t bytes)->void*{
    void* p = ws + off;
    off = (off + bytes + 255) & ~(size_t)255;
    return p;
  };
  int*   flag = (int*)  alloc(4);
  float* gmat = (float*)alloc((size_t)NT*VV*VV*4);
  bf16*  zA   = (bf16*) alloc((size_t)NT*2432*2);
  bf16*  zB   = (bf16*) alloc((size_t)NT*2432*2);
  float* dpart= (float*)alloc((size_t)64*256*4);
  float* s1   = (float*)alloc(2432*4);
  float* s2   = (float*)alloc(2432*4);
  float* A1   = (float*)alloc(2432*4);
  float* B1   = (float*)alloc(2432*4);
  float* A2b1 = (float*)alloc(128*4);
  float* B2b1 = (float*)alloc(128*4);
  float* A2b2 = (float*)alloc(128*4);
  float* B2b2 = (float*)alloc(128*4);
  float* A2b3 = (float*)alloc(128*4);
  float* B2b3 = (float*)alloc(128*4);
  float* A2d  = (float*)alloc(128*4);
  float* B2d  = (float*)alloc(128*4);
  float* fmv1 = (float*)alloc(1216*4);
  float* fmv2 = (float*)alloc(1216*4);
  float* fmv3 = (float*)alloc(2432*4);
  // packed bf16 MFMA weights + fp32 biases
  unsigned short* b1_lwP = (unsigned short*)alloc(64*64*2);
  float*  b1_lbf  = (float*)alloc(64*4);
  unsigned short* b1_wwP = (unsigned short*)alloc(64*64*2);
  unsigned short* b1_w1P = (unsigned short*)alloc(64*64*2);
  float*  b1_w1bf = (float*)alloc(64*4);
  unsigned short* b2_lwP = (unsigned short*)alloc(64*128*2);
  float*  b2_lbf  = (float*)alloc(128*4);
  unsigned short* b2_wwP = (unsigned short*)alloc(128*128*2);
  unsigned short* b2_w1P = (unsigned short*)alloc(128*128*2);
  float*  b2_w1bf = (float*)alloc(128*4);
  unsigned short* b2_dwP = (unsigned short*)alloc(128*64*2);
  float*  b2_dbf  = (float*)alloc(128*4);
  unsigned short* b3_lwP = (unsigned short*)alloc(128*128*2);
  float*  b3_lbf  = (float*)alloc(128*4);
  unsigned short* b3_wwP = (unsigned short*)alloc(128*128*2);
  unsigned short* b3_w1P = (unsigned short*)alloc(128*128*2);
  float*  b3_w1bf = (float*)alloc(128*4);
  float*  g1wT    = (float*)alloc(32*64*4);
  float*  g1bf    = (float*)alloc(32*4);
  float*  g2wT    = (float*)alloc(32*64*4);
  float*  g2bf    = (float*)alloc(32*4);

  if(ws_size < off){
    hipMemsetAsync(d_out, 0x41, (size_t)out_size*2, stream);
    return;
  }

  k_detect<<<1,256,0,stream>>>((const unsigned short*)in[0], flag);
  k_canary<<<(out_size+255)/256,256,0,stream>>>(d_out, out_size, flag);

  auto cvt = [&](const void* src, float* dst, int n){
    k_cvt<<<(n+255)/256,256,0,stream>>>(src, dst, n, flag);
  };
  auto cvtT = [&](const void* src, float* dst, int rows, int cols){
    k_cvtT<<<(rows*cols+255)/256,256,0,stream>>>(src, dst, rows, cols, flag);
  };
  auto packB = [&](const void* src, unsigned short* dst, int ND, int KD, int trans){
    k_packB<<<(ND*KD+255)/256,256,0,stream>>>(src, dst, ND, KD, trans, flag);
  };
  // lw buffers are K-major [CIN][COUT] -> trans=1; ww/w1w/dw are [N][K] -> trans=0
  packB(in[5],  b1_lwP, 64, 64, 1);     cvt(in[6],  b1_lbf,  64);
  packB(in[12], b1_wwP, 64, 64, 0);     packB(in[13], b1_w1P, 64, 64, 0);
  cvt (in[14], b1_w1bf, 64);
  packB(in[15], b2_lwP, 128, 64, 1);    cvt(in[16], b2_lbf,  128);
  packB(in[22], b2_wwP, 128, 128, 0);   packB(in[23], b2_w1P, 128, 128, 0);
  cvt (in[24], b2_w1bf, 128);
  packB(in[25], b2_dwP, 128, 64, 0);    cvt(in[26], b2_dbf,  128);
  packB(in[29], b3_lwP, 128, 128, 1);   cvt(in[30], b3_lbf,  128);
  packB(in[36], b3_wwP, 128, 128, 0);   packB(in[37], b3_w1P, 128, 128, 0);
  cvt (in[38], b3_w1bf, 128);
  cvtT(in[1],  g1wT,    32, 64);        cvt(in[2],  g1bf,    32);
  cvtT(in[3],  g2wT,    32, 64);        cvt(in[4],  g2bf,    32);

  k_tanhp1<<<5,256,0,stream>>>(in[7],  fmv1, 1216, flag);
  k_tanhp1<<<5,256,0,stream>>>(in[17], fmv2, 1216, flag);
  k_tanhp1<<<10,256,0,stream>>>(in[31], fmv3, 2432, flag);
  k_gspa<<<NT,256,0,stream>>>(in[0], g1wT, g1bf, g2wT, g2bf, gmat, flag);

  // ---- Block 1 (64 -> 64, identity residual) ----
  k_stage1<64,64,false,false><<<NT,256,0,stream>>>(in[0], nullptr, nullptr, fmv1,
                                                   b1_lwP, b1_lbf, zA,
                                                   nullptr, nullptr, nullptr, flag);
  k_zero<<<19,256,0,stream>>>(s1, 2*2432);
  k_colstats<<<dim3(5,64),256,0,stream>>>(zA, 1216, s1, s2);
  k_fin1<64><<<5,256,0,stream>>>(s1, s2, in[8], in[9], A1, B1, flag);
  k_stage2<64,64,false,false><<<NT,256,0,stream>>>(in[0], nullptr, nullptr, zA, A1, B1,
                                                   gmat, b1_wwP, b1_w1P, b1_w1bf,
                                                   nullptr, nullptr, nullptr, nullptr, flag);
  k_zero<<<19,256,0,stream>>>(s1, 2*2432);
  k_colstats<<<dim3(5,64),256,0,stream>>>(zA, 1216, s1, s2);
  k_fin2<64><<<1,64,0,stream>>>(s1, s2, in[10], in[11], A2b1, B2b1, flag);

  // ---- Block 2 (64 -> 128, down path) ----
  k_zero<<<64,256,0,stream>>>(dpart, 64*256);
  k_stage1<64,128,true,true><<<NT,256,0,stream>>>(zA, A2b1, B2b1, fmv2,
                                                  b2_lwP, b2_lbf, zB,
                                                  b2_dwP, b2_dbf, dpart, flag);
  k_dfin<<<1,256,0,stream>>>(dpart, in[27], in[28], A2d, B2d, flag);
  k_zero<<<19,256,0,stream>>>(s1, 2*2432);
  k_colstats<<<dim3(10,64),256,0,stream>>>(zB, 2432, s1, s2);
  k_fin1<128><<<10,256,0,stream>>>(s1, s2, in[18], in[19], A1, B1, flag);
  k_stage2<64,128,true,true><<<NT,256,0,stream>>>(zA, A2b1, B2b1, zB, A1, B1,
                                                  gmat, b2_wwP, b2_w1P, b2_w1bf,
                                                  b2_dwP, b2_dbf, A2d, B2d, flag);
  k_zero<<<19,256,0,stream>>>(s1, 2*2432);
  k_colstats<<<dim3(10,64),256,0,stream>>>(zB, 2432, s1, s2);
  k_fin2<128><<<1,128,0,stream>>>(s1, s2, in[20], in[21], A2b2, B2b2, flag);

  // ---- Block 3 (128 -> 128, identity) ----
  k_stage1<128,128,false,true><<<NT,256,0,stream>>>(zB, A2b2, B2b2, fmv3,
                                                    b3_lwP, b3_lbf, zA,
                                                    nullptr, nullptr, nullptr, flag);
  k_zero<<<19,256,0,stream>>>(s1, 2*2432);
  k_colstats<<<dim3(10,64),256,0,stream>>>(zA, 2432, s1, s2);
  k_fin1<128><<<10,256,0,stream>>>(s1, s2, in[32], in[33], A1, B1, flag);
  k_stage2<128,128,false,true><<<NT,256,0,stream>>>(zB, A2b2, B2b2, zA, A1, B1,
                                                    gmat, b3_wwP, b3_w1P, b3_w1bf,
                                                    nullptr, nullptr, nullptr, nullptr, flag);
  k_zero<<<19,256,0,stream>>>(s1, 2*2432);
  k_colstats<<<dim3(10,64),256,0,stream>>>(zA, 2432, s1, s2);
  k_fin2<128><<<1,128,0,stream>>>(s1, s2, in[34], in[35], A2b3, B2b3, flag);
  k_stage3<128><<<NT,256,0,stream>>>(zA, A2b3, B2b3, d_out, flag);
}